// Round 3
// baseline (9473.260 us; speedup 1.0000x reference)
//
#include <hip/hip_runtime.h>

typedef unsigned short ushort_t;
typedef unsigned long long u64;
typedef __attribute__((ext_vector_type(8))) short short8;
typedef __attribute__((ext_vector_type(4))) float f32x4;

#define SEQ 512
#define HID 1024
#define GCOLS 4096           // 4*HID
#define HSEQ_ELEMS 16777216  // SEQ*BATCH*HID
#define NWG 64
#define COLS 16              // hidden cols per WG

__device__ __forceinline__ ushort_t f2bf(float f) {
    unsigned u = __float_as_uint(f);
    unsigned r = (u + 0x7FFFu + ((u >> 16) & 1u)) >> 16;
    return (ushort_t)r;
}
__device__ __forceinline__ float bf2f(ushort_t u) {
    return __uint_as_float(((unsigned)u) << 16);
}
__device__ __forceinline__ float sigmoidf_(float x) { return 1.f / (1.f + __expf(-x)); }
__device__ __forceinline__ float tanhs_(float x) {
    float ax = fabsf(x);
    float e  = __expf(-2.f * ax);
    float t  = (1.f - e) / (1.f + e);
    return copysignf(t, x);
}

// ---------------- convert x (fp32 -> bf16) ----------------
__global__ __launch_bounds__(256) void k_convert_x(const float* __restrict__ x, ushort_t* __restrict__ xbf) {
    size_t i = ((size_t)blockIdx.x * 256 + threadIdx.x) * 8;
    float4 a = *(const float4*)(x + i);
    float4 b = *(const float4*)(x + i + 4);
    short8 v;
    v[0] = (short)f2bf(a.x); v[1] = (short)f2bf(a.y); v[2] = (short)f2bf(a.z); v[3] = (short)f2bf(a.w);
    v[4] = (short)f2bf(b.x); v[5] = (short)f2bf(b.y); v[6] = (short)f2bf(b.z); v[7] = (short)f2bf(b.w);
    *(short8*)(xbf + i) = v;
}

// ---------------- transpose-convert 8 square matrices ----------------
__global__ __launch_bounds__(256) void k_transpose8(
    const float* __restrict__ u0, const float* __restrict__ u1, const float* __restrict__ u2, const float* __restrict__ u3,
    const float* __restrict__ v0, const float* __restrict__ v1, const float* __restrict__ v2, const float* __restrict__ v3,
    ushort_t* __restrict__ UT, ushort_t* __restrict__ VT) {
    __shared__ float tile[32][33];
    int m  = blockIdx.x >> 10;    // matrix 0..7
    int tl = blockIdx.x & 1023;
    int tr = tl >> 5, tc = tl & 31;
    const float* src = (m == 0) ? u0 : (m == 1) ? u1 : (m == 2) ? u2 : (m == 3) ? u3
                      : (m == 4) ? v0 : (m == 5) ? v1 : (m == 6) ? v2 : v3;
    int r = threadIdx.x >> 5, c = threadIdx.x & 31;
    int k0 = tr * 32, n0 = tc * 32;
#pragma unroll
    for (int i = 0; i < 4; ++i)
        tile[r + 8 * i][c] = src[(size_t)(k0 + r + 8 * i) * HID + n0 + c];
    __syncthreads();
    ushort_t* dst = (m < 4) ? (UT + (size_t)m * HID * HID) : (VT + (size_t)(m - 4) * HID * HID);
#pragma unroll
    for (int i = 0; i < 4; ++i) {
        int row = r + 8 * i;
        dst[(size_t)(n0 + row) * HID + k0 + c] = f2bf(tile[c][row]);
    }
}

// ---------------- phase-1 GEMM: gates_pre = x_bf @ U + bias (bf16 out) ----------------
__global__ __launch_bounds__(256) void k_gemm(
    const ushort_t* __restrict__ A, const ushort_t* __restrict__ Bt,
    const float* __restrict__ pbi, const float* __restrict__ pbf,
    const float* __restrict__ pbc, const float* __restrict__ pbo,
    ushort_t* __restrict__ gates) {
    __shared__ ushort_t As[128 * 64];
    __shared__ ushort_t Bs[128 * 64];
    const int tid = threadIdx.x, lane = tid & 63, wv = tid >> 6;
    const int bm = blockIdx.x & 127, bn = blockIdx.x >> 7;
    const size_t m0 = (size_t)bm * 128;
    const size_t n0 = (size_t)bn * 128;
    const int wm = wv >> 1, wn = wv & 1;
    f32x4 acc[4][4] = {};
    const int srow = tid >> 1, skof = (tid & 1) * 32;
    const ushort_t* ap = A + (m0 + srow) * 1024 + skof;
    const ushort_t* bp = Bt + (n0 + srow) * 1024 + skof;

    for (int kt = 0; kt < 16; ++kt) {
        int k0 = kt * 64;
#pragma unroll
        for (int i = 0; i < 4; ++i) {
            *(short8*)(&As[srow * 64 + skof + i * 8]) = *(const short8*)(ap + k0 + i * 8);
            *(short8*)(&Bs[srow * 64 + skof + i * 8]) = *(const short8*)(bp + k0 + i * 8);
        }
        __syncthreads();
#pragma unroll
        for (int kk = 0; kk < 64; kk += 32) {
            short8 af[4], bfr[4];
            int ko = kk + (lane >> 4) * 8;
#pragma unroll
            for (int mi = 0; mi < 4; ++mi) af[mi] = *(const short8*)(&As[(wm * 64 + mi * 16 + (lane & 15)) * 64 + ko]);
#pragma unroll
            for (int ni = 0; ni < 4; ++ni) bfr[ni] = *(const short8*)(&Bs[(wn * 64 + ni * 16 + (lane & 15)) * 64 + ko]);
#pragma unroll
            for (int mi = 0; mi < 4; ++mi)
#pragma unroll
                for (int ni = 0; ni < 4; ++ni)
                    acc[mi][ni] = __builtin_amdgcn_mfma_f32_16x16x32_bf16(af[mi], bfr[ni], acc[mi][ni], 0, 0, 0);
        }
        __syncthreads();
    }
    const int g = (int)(n0 >> 10);
    const float* bias = (g == 0) ? pbi : (g == 1) ? pbf : (g == 2) ? pbc : pbo;
#pragma unroll
    for (int ni = 0; ni < 4; ++ni) {
        int col = (int)n0 + wn * 64 + ni * 16 + (lane & 15);
        float bv = bias[col & 1023];
#pragma unroll
        for (int mi = 0; mi < 4; ++mi) {
            int row0 = (int)m0 + wm * 64 + mi * 16 + ((lane >> 4) << 2);
#pragma unroll
            for (int r = 0; r < 4; ++r)
                gates[(size_t)(row0 + r) * GCOLS + col] = f2bf(acc[mi][ni][r] + bv);
        }
    }
}

// ---------------- persistent scan: 64 WGs x 256 threads ----------------
// WG w owns 16 hidden cols (x4 gates = 64 output cols). V slice (128KB) swizzled in LDS.
// K split across 4 waves; cross-wave reduce via ds_add_f32 into double-buffered pre[].
// Cross-WG h + flags via agent-scope relaxed atomics (L3). Gates prefetched 1 step ahead.
__global__ __launch_bounds__(256) void k_scan(
    const ushort_t* __restrict__ gates, const ushort_t* __restrict__ VT,
    ushort_t* hbuf, unsigned* flags, float* __restrict__ out) {
    __shared__ ushort_t Vs[64 * 1024];   // 128KB, XOR-swizzled rows
    __shared__ float pre[2][2048];       // 16KB double-buffered partial sums
    __shared__ ushort_t hsh[512];        // 1KB  h slice staging [b][c]
    const int tid = threadIdx.x, w = blockIdx.x;
    const int lane = tid & 63, wv = tid >> 6;
    const int n0 = w * COLS;
    const int arow = lane & 15;
    const int ksub = (lane >> 4) * 8;
    const int kb = wv * 256;             // K quarter per wave

    // ---- stage V slice into LDS (swizzled): 64 rows (jj=g*16+c) x 1024 k ----
    {
        int jj = tid >> 2, part = tid & 3;
        int g = jj >> 4, c = jj & 15;
        const ushort_t* src = VT + ((size_t)(g * 1024 + n0 + c)) * 1024 + part * 256;
        char* dst = (char*)Vs + jj * 2048;
        int swz = (jj & 7) << 4;
#pragma unroll
        for (int i = 0; i < 32; ++i) {
            short8 v = *(const short8*)(src + i * 8);
            int koff = (part * 256 + i * 8) * 2;
            *(short8*)(dst + (koff ^ swz)) = v;
        }
    }
    // zero both pre buffers
    {
        float* pz = &pre[0][0];
#pragma unroll
        for (int i = 0; i < 16; ++i) pz[tid + i * 256] = 0.f;
    }
    // zero h buffer 0 slice (wave 0 only; 32 rows x 16 cols)
    if (wv == 0) {
#pragma unroll
        for (int m = 0; m < 2; ++m) {
            int ch = lane + m * 64;
            int b = ch >> 2, part = ch & 3;
            __hip_atomic_store((u64*)(hbuf + b * 1024 + n0 + part * 4), (u64)0,
                               __ATOMIC_RELAXED, __HIP_MEMORY_SCOPE_AGENT);
        }
    }
    // prefetch gates for t=0
    float cur[8];
    {
        int q0 = tid, q1 = tid + 256;
        int b0 = q0 >> 4, c0 = q0 & 15, b1 = q1 >> 4, c1 = q1 & 15;
        size_t r0 = (size_t)b0 * GCOLS + n0, r1 = (size_t)b1 * GCOLS + n0;
#pragma unroll
        for (int g = 0; g < 4; ++g) {
            cur[g]     = bf2f(gates[r0 + g * 1024 + c0]);
            cur[4 + g] = bf2f(gates[r1 + g * 1024 + c1]);
        }
    }
    // initial barrier (h0 visible)
    if (wv == 0) {
        asm volatile("s_waitcnt vmcnt(0)" ::: "memory");
        if (lane == 0)
            __hip_atomic_store(&flags[w], 1u, __ATOMIC_RELAXED, __HIP_MEMORY_SCOPE_AGENT);
        for (;;) {
            unsigned f = __hip_atomic_load(&flags[lane], __ATOMIC_RELAXED, __HIP_MEMORY_SCOPE_AGENT);
            if (__all(f >= 1u)) break;
        }
    }
    __syncthreads();

    float c0r = 0.f, c1r = 0.f;
    for (int t = 0; t < SEQ; ++t) {
        const ushort_t* hc = hbuf + (t & 1) * 32768;

        // ---- h fragments: 32 x 8B agent-scope loads per lane ----
        short8 a0[8], a1[8];
#pragma unroll
        for (int ks = 0; ks < 8; ++ks) {
            const ushort_t* hp = hc + arow * 1024 + kb + ks * 32 + ksub;
            union { u64 q[2]; short8 s; } u0l, u1l;
            u0l.q[0] = __hip_atomic_load((u64*)hp, __ATOMIC_RELAXED, __HIP_MEMORY_SCOPE_AGENT);
            u0l.q[1] = __hip_atomic_load((u64*)(hp + 4), __ATOMIC_RELAXED, __HIP_MEMORY_SCOPE_AGENT);
            u1l.q[0] = __hip_atomic_load((u64*)(hp + 16 * 1024), __ATOMIC_RELAXED, __HIP_MEMORY_SCOPE_AGENT);
            u1l.q[1] = __hip_atomic_load((u64*)(hp + 16 * 1024 + 4), __ATOMIC_RELAXED, __HIP_MEMORY_SCOPE_AGENT);
            a0[ks] = u0l.s;
            a1[ks] = u1l.s;
        }

        // ---- prefetch gates for step t+1 (consumed after next barrier) ----
        ushort_t pf[8];
        {
            int tn = (t + 1 < SEQ) ? t + 1 : 0;
            int q0 = tid, q1 = tid + 256;
            int b0 = q0 >> 4, c0 = q0 & 15, b1 = q1 >> 4, c1 = q1 & 15;
            size_t r0 = (size_t)(tn * 32 + b0) * GCOLS + n0;
            size_t r1 = (size_t)(tn * 32 + b1) * GCOLS + n0;
#pragma unroll
            for (int g = 0; g < 4; ++g) {
                pf[g]     = gates[r0 + g * 1024 + c0];
                pf[4 + g] = gates[r1 + g * 1024 + c1];
            }
        }

        // ---- GEMM quarter-K: acc[mi][nb] over 8 k-steps ----
        f32x4 acc[2][4] = {};
        const int swz = (arow & 7) << 4;
#pragma unroll
        for (int ks = 0; ks < 8; ++ks) {
            int koff = (kb + ks * 32 + ksub) * 2;
#pragma unroll
            for (int nb = 0; nb < 4; ++nb) {
                int jj = nb * 16 + arow;
                short8 bfr = *(const short8*)((const char*)Vs + jj * 2048 + (koff ^ swz));
                acc[0][nb] = __builtin_amdgcn_mfma_f32_16x16x32_bf16(a0[ks], bfr, acc[0][nb], 0, 0, 0);
                acc[1][nb] = __builtin_amdgcn_mfma_f32_16x16x32_bf16(a1[ks], bfr, acc[1][nb], 0, 0, 0);
            }
        }

        // ---- cross-wave reduce: ds_add_f32 into pre[t&1] ----
        float* pb = &pre[t & 1][0];
#pragma unroll
        for (int mi = 0; mi < 2; ++mi)
#pragma unroll
            for (int nb = 0; nb < 4; ++nb) {
                int jj = nb * 16 + (lane & 15);
#pragma unroll
                for (int r = 0; r < 4; ++r) {
                    int b = mi * 16 + (lane >> 4) * 4 + r;
                    __hip_atomic_fetch_add(&pb[b * 64 + jj], acc[mi][nb][r],
                                           __ATOMIC_RELAXED, __HIP_MEMORY_SCOPE_WORKGROUP);
                }
            }
        __syncthreads();

        // ---- elementwise: 2 (b,c) pairs per thread ----
        {
            int q0 = tid, q1 = tid + 256;
            int b0 = q0 >> 4, c0 = q0 & 15, b1 = q1 >> 4, c1 = q1 & 15;
            float si0 = pb[b0 * 64 + c0]      + cur[0];
            float sf0 = pb[b0 * 64 + 16 + c0] + cur[1];
            float sc0 = pb[b0 * 64 + 32 + c0] + cur[2];
            float so0 = pb[b0 * 64 + 48 + c0] + cur[3];
            float si1 = pb[b1 * 64 + c1]      + cur[4];
            float sf1 = pb[b1 * 64 + 16 + c1] + cur[5];
            float sc1v= pb[b1 * 64 + 32 + c1] + cur[6];
            float so1 = pb[b1 * 64 + 48 + c1] + cur[7];
            c0r = sigmoidf_(sf0) * c0r + sigmoidf_(si0) * tanhs_(sc0);
            c1r = sigmoidf_(sf1) * c1r + sigmoidf_(si1) * tanhs_(sc1v);
            float h0 = sigmoidf_(so0) * tanhs_(c0r);
            float h1 = sigmoidf_(so1) * tanhs_(c1r);
            out[(size_t)t * 32768 + b0 * 1024 + n0 + c0] = h0;
            out[(size_t)t * 32768 + b1 * 1024 + n0 + c1] = h1;
            hsh[q0] = f2bf(h0);
            hsh[q1] = f2bf(h1);
            if (t == SEQ - 1) {
                out[HSEQ_ELEMS + b0 * 1024 + n0 + c0] = h0;
                out[HSEQ_ELEMS + b1 * 1024 + n0 + c1] = h1;
                out[HSEQ_ELEMS + 32768 + b0 * 1024 + n0 + c0] = c0r;
                out[HSEQ_ELEMS + 32768 + b1 * 1024 + n0 + c1] = c1r;
            }
        }
        // zero the other pre buffer (used by step t+1)
        {
            float* pz = &pre[(t + 1) & 1][0];
#pragma unroll
            for (int i = 0; i < 8; ++i) pz[tid + i * 256] = 0.f;
        }
        // rotate prefetched gates into cur
#pragma unroll
        for (int i = 0; i < 8; ++i) cur[i] = bf2f(pf[i]);

        if (t == SEQ - 1) break;  // no publish/poll needed after last step

        __syncthreads();  // hsh + pz ready
        // ---- publish h slice + barrier (wave 0) ----
        if (wv == 0) {
            ushort_t* hn = hbuf + ((t & 1) ^ 1) * 32768;
#pragma unroll
            for (int m = 0; m < 2; ++m) {
                int ch = lane + m * 64;
                int b = ch >> 2, part = ch & 3;
                u64 v = *(const u64*)&hsh[b * 16 + part * 4];
                __hip_atomic_store((u64*)(hn + b * 1024 + n0 + part * 4), v,
                                   __ATOMIC_RELAXED, __HIP_MEMORY_SCOPE_AGENT);
            }
            unsigned val = (unsigned)(t + 2);
            asm volatile("s_waitcnt vmcnt(0)" ::: "memory");
            if (lane == 0)
                __hip_atomic_store(&flags[w], val, __ATOMIC_RELAXED, __HIP_MEMORY_SCOPE_AGENT);
            for (;;) {
                unsigned f = __hip_atomic_load(&flags[lane], __ATOMIC_RELAXED, __HIP_MEMORY_SCOPE_AGENT);
                if (__all(f >= val)) break;
            }
        }
        __syncthreads();
    }
}

extern "C" void kernel_launch(void* const* d_in, const int* in_sizes, int n_in,
                              void* d_out, int out_size, void* d_ws, size_t ws_size,
                              hipStream_t stream) {
    const float* x  = (const float*)d_in[0];
    const float* Ui = (const float*)d_in[1];
    const float* Vi = (const float*)d_in[2];
    const float* bi = (const float*)d_in[3];
    const float* Uf = (const float*)d_in[4];
    const float* Vf = (const float*)d_in[5];
    const float* bfp= (const float*)d_in[6];
    const float* Uc = (const float*)d_in[7];
    const float* Vc = (const float*)d_in[8];
    const float* bc = (const float*)d_in[9];
    const float* Uo = (const float*)d_in[10];
    const float* Vo = (const float*)d_in[11];
    const float* bo = (const float*)d_in[12];

    char* ws = (char*)d_ws;
    unsigned* flags = (unsigned*)ws;                          // 4096 B
    ushort_t* hbuf  = (ushort_t*)(ws + 4096);                 // 131072 B (2 x 32x1024 bf16)
    ushort_t* xbf   = (ushort_t*)(ws + 135168);               // 33554432 B
    ushort_t* UT    = (ushort_t*)(ws + 33689600);             // 8388608 B
    ushort_t* VT    = (ushort_t*)(ws + 42078208);             // 8388608 B
    ushort_t* gates = (ushort_t*)(ws + 50466816);             // 134217728 B

    hipMemsetAsync(flags, 0, 4096, stream);
    hipLaunchKernelGGL(k_convert_x, dim3(8192), dim3(256), 0, stream, x, xbf);
    hipLaunchKernelGGL(k_transpose8, dim3(8192), dim3(256), 0, stream,
                       Ui, Uf, Uc, Uo, Vi, Vf, Vc, Vo, UT, VT);
    hipLaunchKernelGGL(k_gemm, dim3(4096), dim3(256), 0, stream,
                       xbf, UT, bi, bfp, bc, bo, gates);
    hipLaunchKernelGGL(k_scan, dim3(NWG), dim3(256), 0, stream,
                       gates, VT, hbuf, flags, (float*)d_out);
}

// Round 4
// 4210.299 us; speedup vs baseline: 2.2500x; 2.2500x over previous
//
#include <hip/hip_runtime.h>

typedef unsigned short ushort_t;
typedef unsigned long long u64;
typedef __attribute__((ext_vector_type(8))) short short8;
typedef __attribute__((ext_vector_type(4))) float f32x4;

#define SEQ 512
#define HID 1024
#define GCOLS 4096           // 4*HID
#define HSEQ_ELEMS 16777216  // SEQ*BATCH*HID
#define NWG 128
#define COLS 8               // hidden cols per WG

__device__ __forceinline__ ushort_t f2bf(float f) {
    unsigned u = __float_as_uint(f);
    unsigned r = (u + 0x7FFFu + ((u >> 16) & 1u)) >> 16;
    return (ushort_t)r;
}
__device__ __forceinline__ float bf2f(ushort_t u) {
    return __uint_as_float(((unsigned)u) << 16);
}
__device__ __forceinline__ float sigmoidf_(float x) { return 1.f / (1.f + __expf(-x)); }
__device__ __forceinline__ float tanhs_(float x) {
    float ax = fabsf(x);
    float e  = __expf(-2.f * ax);
    float t  = (1.f - e) / (1.f + e);
    return copysignf(t, x);
}

// ---------------- convert x (fp32 -> bf16) ----------------
__global__ __launch_bounds__(256) void k_convert_x(const float* __restrict__ x, ushort_t* __restrict__ xbf) {
    size_t i = ((size_t)blockIdx.x * 256 + threadIdx.x) * 8;
    float4 a = *(const float4*)(x + i);
    float4 b = *(const float4*)(x + i + 4);
    short8 v;
    v[0] = (short)f2bf(a.x); v[1] = (short)f2bf(a.y); v[2] = (short)f2bf(a.z); v[3] = (short)f2bf(a.w);
    v[4] = (short)f2bf(b.x); v[5] = (short)f2bf(b.y); v[6] = (short)f2bf(b.z); v[7] = (short)f2bf(b.w);
    *(short8*)(xbf + i) = v;
}

// ---------------- transpose-convert 8 square matrices ----------------
__global__ __launch_bounds__(256) void k_transpose8(
    const float* __restrict__ u0, const float* __restrict__ u1, const float* __restrict__ u2, const float* __restrict__ u3,
    const float* __restrict__ v0, const float* __restrict__ v1, const float* __restrict__ v2, const float* __restrict__ v3,
    ushort_t* __restrict__ UT, ushort_t* __restrict__ VT) {
    __shared__ float tile[32][33];
    int m  = blockIdx.x >> 10;    // matrix 0..7
    int tl = blockIdx.x & 1023;
    int tr = tl >> 5, tc = tl & 31;
    const float* src = (m == 0) ? u0 : (m == 1) ? u1 : (m == 2) ? u2 : (m == 3) ? u3
                      : (m == 4) ? v0 : (m == 5) ? v1 : (m == 6) ? v2 : v3;
    int r = threadIdx.x >> 5, c = threadIdx.x & 31;
    int k0 = tr * 32, n0 = tc * 32;
#pragma unroll
    for (int i = 0; i < 4; ++i)
        tile[r + 8 * i][c] = src[(size_t)(k0 + r + 8 * i) * HID + n0 + c];
    __syncthreads();
    ushort_t* dst = (m < 4) ? (UT + (size_t)m * HID * HID) : (VT + (size_t)(m - 4) * HID * HID);
#pragma unroll
    for (int i = 0; i < 4; ++i) {
        int row = r + 8 * i;
        dst[(size_t)(n0 + row) * HID + k0 + c] = f2bf(tile[c][row]);
    }
}

// ---------------- phase-1 GEMM: gates_pre = x_bf @ U + bias (bf16 out) ----------------
__global__ __launch_bounds__(256) void k_gemm(
    const ushort_t* __restrict__ A, const ushort_t* __restrict__ Bt,
    const float* __restrict__ pbi, const float* __restrict__ pbf,
    const float* __restrict__ pbc, const float* __restrict__ pbo,
    ushort_t* __restrict__ gates) {
    __shared__ ushort_t As[128 * 64];
    __shared__ ushort_t Bs[128 * 64];
    const int tid = threadIdx.x, lane = tid & 63, wv = tid >> 6;
    const int bm = blockIdx.x & 127, bn = blockIdx.x >> 7;
    const size_t m0 = (size_t)bm * 128;
    const size_t n0 = (size_t)bn * 128;
    const int wm = wv >> 1, wn = wv & 1;
    f32x4 acc[4][4] = {};
    const int srow = tid >> 1, skof = (tid & 1) * 32;
    const ushort_t* ap = A + (m0 + srow) * 1024 + skof;
    const ushort_t* bp = Bt + (n0 + srow) * 1024 + skof;

    for (int kt = 0; kt < 16; ++kt) {
        int k0 = kt * 64;
#pragma unroll
        for (int i = 0; i < 4; ++i) {
            *(short8*)(&As[srow * 64 + skof + i * 8]) = *(const short8*)(ap + k0 + i * 8);
            *(short8*)(&Bs[srow * 64 + skof + i * 8]) = *(const short8*)(bp + k0 + i * 8);
        }
        __syncthreads();
#pragma unroll
        for (int kk = 0; kk < 64; kk += 32) {
            short8 af[4], bfr[4];
            int ko = kk + (lane >> 4) * 8;
#pragma unroll
            for (int mi = 0; mi < 4; ++mi) af[mi] = *(const short8*)(&As[(wm * 64 + mi * 16 + (lane & 15)) * 64 + ko]);
#pragma unroll
            for (int ni = 0; ni < 4; ++ni) bfr[ni] = *(const short8*)(&Bs[(wn * 64 + ni * 16 + (lane & 15)) * 64 + ko]);
#pragma unroll
            for (int mi = 0; mi < 4; ++mi)
#pragma unroll
                for (int ni = 0; ni < 4; ++ni)
                    acc[mi][ni] = __builtin_amdgcn_mfma_f32_16x16x32_bf16(af[mi], bfr[ni], acc[mi][ni], 0, 0, 0);
        }
        __syncthreads();
    }
    const int g = (int)(n0 >> 10);
    const float* bias = (g == 0) ? pbi : (g == 1) ? pbf : (g == 2) ? pbc : pbo;
#pragma unroll
    for (int ni = 0; ni < 4; ++ni) {
        int col = (int)n0 + wn * 64 + ni * 16 + (lane & 15);
        float bv = bias[col & 1023];
#pragma unroll
        for (int mi = 0; mi < 4; ++mi) {
            int row0 = (int)m0 + wm * 64 + mi * 16 + ((lane >> 4) << 2);
#pragma unroll
            for (int r = 0; r < 4; ++r)
                gates[(size_t)(row0 + r) * GCOLS + col] = f2bf(acc[mi][ni][r] + bv);
        }
    }
}

// ---------------- single-root tree barrier ----------------
// Producers: u16 flag store (2 cachelines total). Root (WG0 wave0): polls all 128
// flags as 64 dwords, then writes GO (own cacheline). Others: poll GO (read-mostly).
__device__ __forceinline__ void xbar(unsigned short* flags, unsigned* go,
                                     int w, int wv, int lane, unsigned val) {
    if (wv == 0) {
        asm volatile("s_waitcnt vmcnt(0)" ::: "memory");
        if (lane == 0)
            __hip_atomic_store(&flags[w], (unsigned short)val, __ATOMIC_RELAXED, __HIP_MEMORY_SCOPE_AGENT);
        if (w == 0) {
            const unsigned* fp = (const unsigned*)flags;
            for (;;) {
                unsigned fl = __hip_atomic_load(&fp[lane], __ATOMIC_RELAXED, __HIP_MEMORY_SCOPE_AGENT);
                if (__all((fl & 0xFFFFu) >= val && (fl >> 16) >= val)) break;
            }
            if (lane == 0)
                __hip_atomic_store(go, val, __ATOMIC_RELAXED, __HIP_MEMORY_SCOPE_AGENT);
        } else {
            for (;;) {
                unsigned g = __hip_atomic_load(go, __ATOMIC_RELAXED, __HIP_MEMORY_SCOPE_AGENT);
                if (g >= val) break;
                __builtin_amdgcn_s_sleep(1);
            }
        }
    }
    __syncthreads();
}

// ---------------- persistent scan: 128 WGs x 256 threads ----------------
// WG w owns 8 hidden cols (x4 gates = 32 out cols). V fragments in registers (64 VGPR).
// K split across 4 waves; reduce via rotated red[] layout (2-way = conflict-free).
// Cross-WG h + flags via agent-scope relaxed atomics (L3). Gates prefetched 1 step ahead.
__global__ __launch_bounds__(256) void k_scan(
    const ushort_t* __restrict__ gates, const ushort_t* __restrict__ VT,
    ushort_t* hbuf, unsigned short* flags, unsigned* go, float* __restrict__ out) {
    __shared__ float red[4 * 1024];   // 16KB
    __shared__ float pre[1024];       // 4KB
    __shared__ ushort_t hsh[256];
    const int tid = threadIdx.x, w = blockIdx.x;
    const int lane = tid & 63, wv = tid >> 6;
    const int q = lane >> 4;
    const int n0 = w * COLS;
    const int arow = lane & 15;
    const int ksub = q * 8;
    const int kb = wv * 256;             // K quarter per wave

    // V fragments: 2 N-tiles x 8 k-steps resident in 64 VGPRs (V constant all scan)
    short8 bv[2][8];
#pragma unroll
    for (int nt = 0; nt < 2; ++nt) {
        int j = nt * 16 + arow, g = j >> 3, c = j & 7;
        const ushort_t* vrow = VT + ((size_t)(g * 1024 + n0 + c)) * 1024 + kb + ksub;
#pragma unroll
        for (int ks = 0; ks < 8; ++ks) bv[nt][ks] = *(const short8*)(vrow + ks * 32);
    }

    const int b = tid >> 3, c = tid & 7;  // this thread's (batch, col) output element
    float c_reg = 0.f;

    // zero h buffer 0 slice (wave 0: 32 rows x 8 cols, 8B per lane)
    if (wv == 0) {
        int row = lane >> 1, part = lane & 1;
        __hip_atomic_store((u64*)(hbuf + row * 1024 + n0 + part * 4), (u64)0,
                           __ATOMIC_RELAXED, __HIP_MEMORY_SCOPE_AGENT);
    }
    // prefetch gates t=0
    float cur[4];
    {
        size_t r0 = (size_t)b * GCOLS + n0 + c;
#pragma unroll
        for (int g = 0; g < 4; ++g) cur[g] = bf2f(gates[r0 + g * 1024]);
    }
    xbar(flags, go, w, wv, lane, 1u);

    for (int t = 0; t < SEQ; ++t) {
        const ushort_t* hc = hbuf + (t & 1) * 32768;

        // ---- h fragments: 32 x 8B agent-scope loads per lane, all pipelined ----
        short8 a0[8], a1[8];
#pragma unroll
        for (int ks = 0; ks < 8; ++ks) {
            const ushort_t* hp = hc + arow * 1024 + kb + ks * 32 + ksub;
            union { u64 qd[2]; short8 s; } u0l, u1l;
            u0l.qd[0] = __hip_atomic_load((u64*)hp, __ATOMIC_RELAXED, __HIP_MEMORY_SCOPE_AGENT);
            u0l.qd[1] = __hip_atomic_load((u64*)(hp + 4), __ATOMIC_RELAXED, __HIP_MEMORY_SCOPE_AGENT);
            u1l.qd[0] = __hip_atomic_load((u64*)(hp + 16 * 1024), __ATOMIC_RELAXED, __HIP_MEMORY_SCOPE_AGENT);
            u1l.qd[1] = __hip_atomic_load((u64*)(hp + 16 * 1024 + 4), __ATOMIC_RELAXED, __HIP_MEMORY_SCOPE_AGENT);
            a0[ks] = u0l.s;
            a1[ks] = u1l.s;
        }

        // ---- prefetch gates for t+1 (plain cached loads) ----
        ushort_t pf[4];
        {
            int tn = (t + 1 < SEQ) ? t + 1 : 0;
            size_t r0 = (size_t)(tn * 32 + b) * GCOLS + n0 + c;
#pragma unroll
            for (int g = 0; g < 4; ++g) pf[g] = gates[r0 + g * 1024];
        }

        // ---- MFMA quarter-K: 2 batch-tiles x 2 col-tiles ----
        f32x4 acc[2][2] = {};
#pragma unroll
        for (int ks = 0; ks < 8; ++ks) {
            acc[0][0] = __builtin_amdgcn_mfma_f32_16x16x32_bf16(a0[ks], bv[0][ks], acc[0][0], 0, 0, 0);
            acc[0][1] = __builtin_amdgcn_mfma_f32_16x16x32_bf16(a0[ks], bv[1][ks], acc[0][1], 0, 0, 0);
            acc[1][0] = __builtin_amdgcn_mfma_f32_16x16x32_bf16(a1[ks], bv[0][ks], acc[1][0], 0, 0, 0);
            acc[1][1] = __builtin_amdgcn_mfma_f32_16x16x32_bf16(a1[ks], bv[1][ks], acc[1][1], 0, 0, 0);
        }

        // ---- red stores, quadrant-rotated columns: 2-way bank aliasing = free ----
        {
            float* rp = red + wv * 1024;
#pragma unroll
            for (int m = 0; m < 2; ++m)
#pragma unroll
                for (int n = 0; n < 2; ++n)
#pragma unroll
                    for (int r = 0; r < 4; ++r) {
                        int bb = m * 16 + q * 4 + r;
                        int col = (n * 16 + arow + q * 8) & 31;
                        rp[bb * 32 + col] = acc[m][n][r];
                    }
        }
        __syncthreads();
        // ---- cross-wave sum into pre[] (logical layout, rotation undone) ----
#pragma unroll
        for (int i = 0; i < 4; ++i) {
            int idx = tid + i * 256;
            int bb = idx >> 5, jj = idx & 31;
            int col = (jj + ((bb >> 2) & 3) * 8) & 31;
            int o = bb * 32 + col;
            pre[idx] = red[o] + red[1024 + o] + red[2048 + o] + red[3072 + o];
        }
        __syncthreads();

        // ---- elementwise: exactly 1 (b,c) per thread ----
        {
            float si = pre[b * 32 + c]      + cur[0];
            float sf = pre[b * 32 + 8 + c]  + cur[1];
            float sc = pre[b * 32 + 16 + c] + cur[2];
            float so = pre[b * 32 + 24 + c] + cur[3];
            c_reg = sigmoidf_(sf) * c_reg + sigmoidf_(si) * tanhs_(sc);
            float h = sigmoidf_(so) * tanhs_(c_reg);
            out[(size_t)t * 32768 + b * 1024 + n0 + c] = h;
            hsh[tid] = f2bf(h);
            if (t == SEQ - 1) {
                out[HSEQ_ELEMS + b * 1024 + n0 + c] = h;
                out[HSEQ_ELEMS + 32768 + b * 1024 + n0 + c] = c_reg;
                break;
            }
        }
#pragma unroll
        for (int g = 0; g < 4; ++g) cur[g] = bf2f(pf[g]);

        __syncthreads();  // hsh ready
        // ---- publish h slice (wave 0) + tree barrier ----
        if (wv == 0) {
            ushort_t* hn = hbuf + ((t & 1) ^ 1) * 32768;
            int row = lane >> 1, part = lane & 1;
            u64 v = *(const u64*)&hsh[row * 8 + part * 4];
            __hip_atomic_store((u64*)(hn + row * 1024 + n0 + part * 4), v,
                               __ATOMIC_RELAXED, __HIP_MEMORY_SCOPE_AGENT);
        }
        xbar(flags, go, w, wv, lane, (unsigned)(t + 2));
    }
}

extern "C" void kernel_launch(void* const* d_in, const int* in_sizes, int n_in,
                              void* d_out, int out_size, void* d_ws, size_t ws_size,
                              hipStream_t stream) {
    const float* x  = (const float*)d_in[0];
    const float* Ui = (const float*)d_in[1];
    const float* Vi = (const float*)d_in[2];
    const float* bi = (const float*)d_in[3];
    const float* Uf = (const float*)d_in[4];
    const float* Vf = (const float*)d_in[5];
    const float* bfp= (const float*)d_in[6];
    const float* Uc = (const float*)d_in[7];
    const float* Vc = (const float*)d_in[8];
    const float* bc = (const float*)d_in[9];
    const float* Uo = (const float*)d_in[10];
    const float* Vo = (const float*)d_in[11];
    const float* bo = (const float*)d_in[12];

    char* ws = (char*)d_ws;
    unsigned short* flags = (unsigned short*)ws;              // 256 B (128 u16)
    unsigned* go    = (unsigned*)(ws + 512);                  // own cacheline
    ushort_t* hbuf  = (ushort_t*)(ws + 4096);                 // 131072 B (2 x 32x1024 bf16)
    ushort_t* xbf   = (ushort_t*)(ws + 135168);               // 33554432 B
    ushort_t* UT    = (ushort_t*)(ws + 33689600);             // 8388608 B
    ushort_t* VT    = (ushort_t*)(ws + 42078208);             // 8388608 B
    ushort_t* gates = (ushort_t*)(ws + 50466816);             // 134217728 B

    hipMemsetAsync(ws, 0, 4096, stream);
    hipLaunchKernelGGL(k_convert_x, dim3(8192), dim3(256), 0, stream, x, xbf);
    hipLaunchKernelGGL(k_transpose8, dim3(8192), dim3(256), 0, stream,
                       Ui, Uf, Uc, Uo, Vi, Vf, Vc, Vo, UT, VT);
    hipLaunchKernelGGL(k_gemm, dim3(4096), dim3(256), 0, stream,
                       xbf, UT, bi, bfp, bc, bo, gates);
    hipLaunchKernelGGL(k_scan, dim3(NWG), dim3(256), 0, stream,
                       gates, VT, hbuf, flags, go, (float*)d_out);
}

// Round 5
// 2885.534 us; speedup vs baseline: 3.2830x; 1.4591x over previous
//
#include <hip/hip_runtime.h>

typedef unsigned short ushort_t;
typedef unsigned long long u64;
typedef __attribute__((ext_vector_type(8))) short short8;
typedef __attribute__((ext_vector_type(4))) float f32x4;
typedef __attribute__((ext_vector_type(4))) int i32x4;

#define SEQ 512
#define HID 1024
#define GCOLS 4096           // 4*HID
#define HSEQ_ELEMS 16777216  // SEQ*BATCH*HID
#define NWG 128
#define COLS 8               // hidden cols per WG

__device__ __forceinline__ ushort_t f2bf(float f) {
    unsigned u = __float_as_uint(f);
    unsigned r = (u + 0x7FFFu + ((u >> 16) & 1u)) >> 16;
    return (ushort_t)r;
}
__device__ __forceinline__ float bf2f(ushort_t u) {
    return __uint_as_float(((unsigned)u) << 16);
}
__device__ __forceinline__ float sigmoidf_(float x) { return 1.f / (1.f + __expf(-x)); }
__device__ __forceinline__ float tanhs_(float x) {
    float ax = fabsf(x);
    float e  = __expf(-2.f * ax);
    float t  = (1.f - e) / (1.f + e);
    return copysignf(t, x);
}

// 16B coherent (device-scope) load/store: bypass L1/L2, served at L3 coherence point.
__device__ __forceinline__ void ld_h16(i32x4* dst, const ushort_t* p) {
    asm volatile("global_load_dwordx4 %0, %1, off sc0 sc1"
                 : "=&v"(*dst) : "v"(p) : "memory");
}
__device__ __forceinline__ void st_h16(ushort_t* p, i32x4 v) {
    asm volatile("global_store_dwordx4 %0, %1, off sc0 sc1"
                 :: "v"(p), "v"(v) : "memory");
}

// ---------------- convert x (fp32 -> bf16) ----------------
__global__ __launch_bounds__(256) void k_convert_x(const float* __restrict__ x, ushort_t* __restrict__ xbf) {
    size_t i = ((size_t)blockIdx.x * 256 + threadIdx.x) * 8;
    float4 a = *(const float4*)(x + i);
    float4 b = *(const float4*)(x + i + 4);
    short8 v;
    v[0] = (short)f2bf(a.x); v[1] = (short)f2bf(a.y); v[2] = (short)f2bf(a.z); v[3] = (short)f2bf(a.w);
    v[4] = (short)f2bf(b.x); v[5] = (short)f2bf(b.y); v[6] = (short)f2bf(b.z); v[7] = (short)f2bf(b.w);
    *(short8*)(xbf + i) = v;
}

// ---------------- transpose-convert 8 square matrices ----------------
__global__ __launch_bounds__(256) void k_transpose8(
    const float* __restrict__ u0, const float* __restrict__ u1, const float* __restrict__ u2, const float* __restrict__ u3,
    const float* __restrict__ v0, const float* __restrict__ v1, const float* __restrict__ v2, const float* __restrict__ v3,
    ushort_t* __restrict__ UT, ushort_t* __restrict__ VT) {
    __shared__ float tile[32][33];
    int m  = blockIdx.x >> 10;    // matrix 0..7
    int tl = blockIdx.x & 1023;
    int tr = tl >> 5, tc = tl & 31;
    const float* src = (m == 0) ? u0 : (m == 1) ? u1 : (m == 2) ? u2 : (m == 3) ? u3
                      : (m == 4) ? v0 : (m == 5) ? v1 : (m == 6) ? v2 : v3;
    int r = threadIdx.x >> 5, c = threadIdx.x & 31;
    int k0 = tr * 32, n0 = tc * 32;
#pragma unroll
    for (int i = 0; i < 4; ++i)
        tile[r + 8 * i][c] = src[(size_t)(k0 + r + 8 * i) * HID + n0 + c];
    __syncthreads();
    ushort_t* dst = (m < 4) ? (UT + (size_t)m * HID * HID) : (VT + (size_t)(m - 4) * HID * HID);
#pragma unroll
    for (int i = 0; i < 4; ++i) {
        int row = r + 8 * i;
        dst[(size_t)(n0 + row) * HID + k0 + c] = f2bf(tile[c][row]);
    }
}

// ---------------- phase-1 GEMM: gates_pre = x_bf @ U + bias (bf16 out, NT stores) ----------------
__global__ __launch_bounds__(256) void k_gemm(
    const ushort_t* __restrict__ A, const ushort_t* __restrict__ Bt,
    const float* __restrict__ pbi, const float* __restrict__ pbf,
    const float* __restrict__ pbc, const float* __restrict__ pbo,
    ushort_t* __restrict__ gates) {
    __shared__ ushort_t As[128 * 64];
    __shared__ ushort_t Bs[128 * 64];
    const int tid = threadIdx.x, lane = tid & 63, wv = tid >> 6;
    const int bm = blockIdx.x & 127, bn = blockIdx.x >> 7;
    const size_t m0 = (size_t)bm * 128;
    const size_t n0 = (size_t)bn * 128;
    const int wm = wv >> 1, wn = wv & 1;
    f32x4 acc[4][4] = {};
    const int srow = tid >> 1, skof = (tid & 1) * 32;
    const ushort_t* ap = A + (m0 + srow) * 1024 + skof;
    const ushort_t* bp = Bt + (n0 + srow) * 1024 + skof;

    for (int kt = 0; kt < 16; ++kt) {
        int k0 = kt * 64;
#pragma unroll
        for (int i = 0; i < 4; ++i) {
            *(short8*)(&As[srow * 64 + skof + i * 8]) = *(const short8*)(ap + k0 + i * 8);
            *(short8*)(&Bs[srow * 64 + skof + i * 8]) = *(const short8*)(bp + k0 + i * 8);
        }
        __syncthreads();
#pragma unroll
        for (int kk = 0; kk < 64; kk += 32) {
            short8 af[4], bfr[4];
            int ko = kk + (lane >> 4) * 8;
#pragma unroll
            for (int mi = 0; mi < 4; ++mi) af[mi] = *(const short8*)(&As[(wm * 64 + mi * 16 + (lane & 15)) * 64 + ko]);
#pragma unroll
            for (int ni = 0; ni < 4; ++ni) bfr[ni] = *(const short8*)(&Bs[(wn * 64 + ni * 16 + (lane & 15)) * 64 + ko]);
#pragma unroll
            for (int mi = 0; mi < 4; ++mi)
#pragma unroll
                for (int ni = 0; ni < 4; ++ni)
                    acc[mi][ni] = __builtin_amdgcn_mfma_f32_16x16x32_bf16(af[mi], bfr[ni], acc[mi][ni], 0, 0, 0);
        }
        __syncthreads();
    }
    const int g = (int)(n0 >> 10);
    const float* bias = (g == 0) ? pbi : (g == 1) ? pbf : (g == 2) ? pbc : pbo;
#pragma unroll
    for (int ni = 0; ni < 4; ++ni) {
        int col = (int)n0 + wn * 64 + ni * 16 + (lane & 15);
        float bv = bias[col & 1023];
#pragma unroll
        for (int mi = 0; mi < 4; ++mi) {
            int row0 = (int)m0 + wm * 64 + mi * 16 + ((lane >> 4) << 2);
#pragma unroll
            for (int r = 0; r < 4; ++r)
                __builtin_nontemporal_store(f2bf(acc[mi][ni][r] + bv),
                                            &gates[(size_t)(row0 + r) * GCOLS + col]);
        }
    }
}

// ---------------- single-root tree barrier (u16 flags, root aggregates, GO broadcast) ----
__device__ __forceinline__ void xbar(unsigned short* flags, unsigned* go,
                                     int w, int wv, int lane, unsigned val) {
    if (wv == 0) {
        asm volatile("s_waitcnt vmcnt(0)" ::: "memory");
        if (lane == 0)
            __hip_atomic_store(&flags[w], (unsigned short)val, __ATOMIC_RELAXED, __HIP_MEMORY_SCOPE_AGENT);
        if (w == 0) {
            const unsigned* fp = (const unsigned*)flags;
            for (;;) {
                unsigned fl = __hip_atomic_load(&fp[lane], __ATOMIC_RELAXED, __HIP_MEMORY_SCOPE_AGENT);
                if (__all((fl & 0xFFFFu) >= val && (fl >> 16) >= val)) break;
            }
            if (lane == 0)
                __hip_atomic_store(go, val, __ATOMIC_RELAXED, __HIP_MEMORY_SCOPE_AGENT);
        } else {
            for (;;) {
                unsigned g = __hip_atomic_load(go, __ATOMIC_RELAXED, __HIP_MEMORY_SCOPE_AGENT);
                if (g >= val) break;
                __builtin_amdgcn_s_sleep(1);
            }
        }
    }
    __syncthreads();
}

// ---------------- persistent scan: 128 WGs x 256 threads ----------------
// h stored BLOCKED: hblk[kblk=0..127][batch=0..31][8 elems] bf16 (64KB per buffer).
// A-fragment loads are lane-contiguous 16B coherent loads; publish is one 16B store.
// V fragments pinned in 64 VGPRs. Gates streamed nontemporal.
__global__ __launch_bounds__(256, 1) void k_scan(
    const ushort_t* __restrict__ gates, const ushort_t* __restrict__ VT,
    ushort_t* hbuf, unsigned short* flags, unsigned* go, float* __restrict__ out) {
    __shared__ float red[4 * 1024];   // 16KB
    __shared__ float pre[1024];       // 4KB
    __shared__ ushort_t hsh[256] __attribute__((aligned(16)));
    const int tid = threadIdx.x, w = blockIdx.x;
    const int lane = tid & 63, wv = tid >> 6;
    const int q = lane >> 4;
    const int n0 = w * COLS;
    const int arow = lane & 15;
    const int ksub = q * 8;
    const int kb = wv * 256;             // K quarter per wave

    // V fragments: 2 N-tiles x 8 k-steps resident in 64 VGPRs, PINNED via asm barrier
    short8 bv0[8], bv1[8];
#pragma unroll
    for (int nt = 0; nt < 2; ++nt) {
        int j = nt * 16 + arow, g = j >> 3, c = j & 7;
        const ushort_t* vrow = VT + ((size_t)(g * 1024 + n0 + c)) * 1024 + kb + ksub;
#pragma unroll
        for (int ks = 0; ks < 8; ++ks) {
            short8 v = *(const short8*)(vrow + ks * 32);
            if (nt == 0) bv0[ks] = v; else bv1[ks] = v;
        }
    }
#pragma unroll
    for (int ks = 0; ks < 8; ++ks) {
        asm volatile("" : "+v"(*(i32x4*)&bv0[ks]));
        asm volatile("" : "+v"(*(i32x4*)&bv1[ks]));
    }

    const int b = tid >> 3, c = tid & 7;  // this thread's (batch, col) output element

    // zero h buffer 0 slice: this WG's contiguous 512B block (blocked layout)
    if (wv == 0 && lane < 32) {
        i32x4 z = {};
        st_h16(hbuf + w * 256 + lane * 8, z);
    }
    // prefetch gates t=0 (nontemporal)
    float cur[4];
    {
        size_t r0 = (size_t)b * GCOLS + n0 + c;
#pragma unroll
        for (int g = 0; g < 4; ++g) cur[g] = bf2f(__builtin_nontemporal_load(&gates[r0 + g * 1024]));
    }
    xbar(flags, go, w, wv, lane, 1u);

    float c_reg = 0.f;
    for (int t = 0; t < SEQ; ++t) {
        const ushort_t* hc = hbuf + (t & 1) * 32768;

        // ---- h A-fragments: 16 x 16B coherent, lane-contiguous loads ----
        i32x4 af0[8], af1[8];
#pragma unroll
        for (int ks = 0; ks < 8; ++ks) {
            int kblk = wv * 32 + ks * 4 + q;
            const ushort_t* base = hc + ((kblk * 32 + arow) << 3);
            ld_h16(&af0[ks], base);
            ld_h16(&af1[ks], base + 128);   // rows 16..31
        }

        // ---- prefetch gates for t+1 (nontemporal) ----
        ushort_t pf[4];
        {
            int tn = (t + 1 < SEQ) ? t + 1 : 0;
            size_t r0 = (size_t)(tn * 32 + b) * GCOLS + n0 + c;
#pragma unroll
            for (int g = 0; g < 4; ++g) pf[g] = __builtin_nontemporal_load(&gates[r0 + g * 1024]);
        }

        asm volatile("s_waitcnt vmcnt(0)" ::: "memory");
        __builtin_amdgcn_sched_barrier(0);

        // ---- MFMA quarter-K: 2 batch-tiles x 2 col-tiles ----
        f32x4 acc[2][2] = {};
#pragma unroll
        for (int ks = 0; ks < 8; ++ks) {
            short8 A0 = __builtin_bit_cast(short8, af0[ks]);
            short8 A1 = __builtin_bit_cast(short8, af1[ks]);
            acc[0][0] = __builtin_amdgcn_mfma_f32_16x16x32_bf16(A0, bv0[ks], acc[0][0], 0, 0, 0);
            acc[0][1] = __builtin_amdgcn_mfma_f32_16x16x32_bf16(A0, bv1[ks], acc[0][1], 0, 0, 0);
            acc[1][0] = __builtin_amdgcn_mfma_f32_16x16x32_bf16(A1, bv0[ks], acc[1][0], 0, 0, 0);
            acc[1][1] = __builtin_amdgcn_mfma_f32_16x16x32_bf16(A1, bv1[ks], acc[1][1], 0, 0, 0);
        }

        // ---- red stores, quadrant-rotated columns (2-way aliasing = free) ----
        {
            float* rp = red + wv * 1024;
#pragma unroll
            for (int m = 0; m < 2; ++m)
#pragma unroll
                for (int n = 0; n < 2; ++n)
#pragma unroll
                    for (int r = 0; r < 4; ++r) {
                        int bb = m * 16 + q * 4 + r;
                        int col = (n * 16 + arow + q * 8) & 31;
                        rp[bb * 32 + col] = acc[m][n][r];
                    }
        }
        __syncthreads();
        // ---- cross-wave sum into pre[] (rotation undone) ----
#pragma unroll
        for (int i = 0; i < 4; ++i) {
            int idx = tid + i * 256;
            int bb = idx >> 5, jj = idx & 31;
            int col = (jj + ((bb >> 2) & 3) * 8) & 31;
            int o = bb * 32 + col;
            pre[idx] = red[o] + red[1024 + o] + red[2048 + o] + red[3072 + o];
        }
        __syncthreads();

        // ---- elementwise: 1 (b,c) per thread ----
        {
            float si = pre[b * 32 + c]      + cur[0];
            float sf = pre[b * 32 + 8 + c]  + cur[1];
            float sc = pre[b * 32 + 16 + c] + cur[2];
            float so = pre[b * 32 + 24 + c] + cur[3];
            c_reg = sigmoidf_(sf) * c_reg + sigmoidf_(si) * tanhs_(sc);
            float h = sigmoidf_(so) * tanhs_(c_reg);
            __builtin_nontemporal_store(h, &out[(size_t)t * 32768 + b * 1024 + n0 + c]);
            hsh[tid] = f2bf(h);
            if (t == SEQ - 1) {
                out[HSEQ_ELEMS + b * 1024 + n0 + c] = h;
                out[HSEQ_ELEMS + 32768 + b * 1024 + n0 + c] = c_reg;
                break;
            }
        }
#pragma unroll
        for (int g = 0; g < 4; ++g) cur[g] = bf2f(pf[g]);

        __syncthreads();  // hsh ready
        // ---- publish: WG's 512B slice is contiguous in blocked layout -> 1 store inst ----
        if (wv == 0 && lane < 32) {
            ushort_t* hn = hbuf + ((t & 1) ^ 1) * 32768;
            i32x4 v = *(const i32x4*)&hsh[lane * 8];
            st_h16(hn + w * 256 + lane * 8, v);
        }
        xbar(flags, go, w, wv, lane, (unsigned)(t + 2));
    }
}

extern "C" void kernel_launch(void* const* d_in, const int* in_sizes, int n_in,
                              void* d_out, int out_size, void* d_ws, size_t ws_size,
                              hipStream_t stream) {
    const float* x  = (const float*)d_in[0];
    const float* Ui = (const float*)d_in[1];
    const float* Vi = (const float*)d_in[2];
    const float* bi = (const float*)d_in[3];
    const float* Uf = (const float*)d_in[4];
    const float* Vf = (const float*)d_in[5];
    const float* bfp= (const float*)d_in[6];
    const float* Uc = (const float*)d_in[7];
    const float* Vc = (const float*)d_in[8];
    const float* bc = (const float*)d_in[9];
    const float* Uo = (const float*)d_in[10];
    const float* Vo = (const float*)d_in[11];
    const float* bo = (const float*)d_in[12];

    char* ws = (char*)d_ws;
    unsigned short* flags = (unsigned short*)ws;              // 256 B (128 u16)
    unsigned* go    = (unsigned*)(ws + 512);                  // own cacheline
    ushort_t* hbuf  = (ushort_t*)(ws + 4096);                 // 131072 B (2 x blocked 32x1024 bf16)
    ushort_t* xbf   = (ushort_t*)(ws + 135168);               // 33554432 B
    ushort_t* UT    = (ushort_t*)(ws + 33689600);             // 8388608 B
    ushort_t* VT    = (ushort_t*)(ws + 42078208);             // 8388608 B
    ushort_t* gates = (ushort_t*)(ws + 50466816);             // 134217728 B

    hipMemsetAsync(ws, 0, 4096, stream);
    hipLaunchKernelGGL(k_convert_x, dim3(8192), dim3(256), 0, stream, x, xbf);
    hipLaunchKernelGGL(k_transpose8, dim3(8192), dim3(256), 0, stream,
                       Ui, Uf, Uc, Uo, Vi, Vf, Vc, Vo, UT, VT);
    hipLaunchKernelGGL(k_gemm, dim3(4096), dim3(256), 0, stream,
                       xbf, UT, bi, bfp, bc, bo, gates);
    hipLaunchKernelGGL(k_scan, dim3(NWG), dim3(256), 0, stream,
                       gates, VT, hbuf, flags, go, (float*)d_out);
}

// Round 6
// 2727.867 us; speedup vs baseline: 3.4728x; 1.0578x over previous
//
#include <hip/hip_runtime.h>

typedef unsigned short ushort_t;
typedef unsigned long long u64;
typedef __attribute__((ext_vector_type(8))) short short8;
typedef __attribute__((ext_vector_type(4))) float f32x4;
typedef __attribute__((ext_vector_type(4))) int i32x4;

#define SEQ 512
#define HID 1024
#define GCOLS 4096           // 4*HID
#define HSEQ_ELEMS 16777216  // SEQ*BATCH*HID
#define NWG 128              // 64 col-groups x 2 batch-halves

__device__ __forceinline__ ushort_t f2bf(float f) {
    unsigned u = __float_as_uint(f);
    unsigned r = (u + 0x7FFFu + ((u >> 16) & 1u)) >> 16;
    return (ushort_t)r;
}
__device__ __forceinline__ float bf2f(ushort_t u) {
    return __uint_as_float(((unsigned)u) << 16);
}
__device__ __forceinline__ float sigmoidf_(float x) { return 1.f / (1.f + __expf(-x)); }
__device__ __forceinline__ float tanhs_(float x) {
    float ax = fabsf(x);
    float e  = __expf(-2.f * ax);
    float t  = (1.f - e) / (1.f + e);
    return copysignf(t, x);
}

// 16B coherent (device-scope) load/store at the L3 coherence point.
__device__ __forceinline__ void ld_h16(i32x4* dst, const ushort_t* p) {
    asm volatile("global_load_dwordx4 %0, %1, off sc0 sc1"
                 : "=&v"(*dst) : "v"(p) : "memory");
}
__device__ __forceinline__ void st_h16(ushort_t* p, i32x4 v) {
    asm volatile("global_store_dwordx4 %0, %1, off sc0 sc1"
                 :: "v"(p), "v"(v) : "memory");
}

// ---------------- convert x (fp32 -> bf16) ----------------
__global__ __launch_bounds__(256) void k_convert_x(const float* __restrict__ x, ushort_t* __restrict__ xbf) {
    size_t i = ((size_t)blockIdx.x * 256 + threadIdx.x) * 8;
    float4 a = *(const float4*)(x + i);
    float4 b = *(const float4*)(x + i + 4);
    short8 v;
    v[0] = (short)f2bf(a.x); v[1] = (short)f2bf(a.y); v[2] = (short)f2bf(a.z); v[3] = (short)f2bf(a.w);
    v[4] = (short)f2bf(b.x); v[5] = (short)f2bf(b.y); v[6] = (short)f2bf(b.z); v[7] = (short)f2bf(b.w);
    *(short8*)(xbf + i) = v;
}

// ---------------- transpose-convert 8 square matrices ----------------
__global__ __launch_bounds__(256) void k_transpose8(
    const float* __restrict__ u0, const float* __restrict__ u1, const float* __restrict__ u2, const float* __restrict__ u3,
    const float* __restrict__ v0, const float* __restrict__ v1, const float* __restrict__ v2, const float* __restrict__ v3,
    ushort_t* __restrict__ UT, ushort_t* __restrict__ VT) {
    __shared__ float tile[32][33];
    int m  = blockIdx.x >> 10;    // matrix 0..7
    int tl = blockIdx.x & 1023;
    int tr = tl >> 5, tc = tl & 31;
    const float* src = (m == 0) ? u0 : (m == 1) ? u1 : (m == 2) ? u2 : (m == 3) ? u3
                      : (m == 4) ? v0 : (m == 5) ? v1 : (m == 6) ? v2 : v3;
    int r = threadIdx.x >> 5, c = threadIdx.x & 31;
    int k0 = tr * 32, n0 = tc * 32;
#pragma unroll
    for (int i = 0; i < 4; ++i)
        tile[r + 8 * i][c] = src[(size_t)(k0 + r + 8 * i) * HID + n0 + c];
    __syncthreads();
    ushort_t* dst = (m < 4) ? (UT + (size_t)m * HID * HID) : (VT + (size_t)(m - 4) * HID * HID);
#pragma unroll
    for (int i = 0; i < 4; ++i) {
        int row = r + 8 * i;
        dst[(size_t)(n0 + row) * HID + k0 + c] = f2bf(tile[c][row]);
    }
}

// ---------------- phase-1 GEMM: gates_pre = x_bf @ U + bias (bf16 out, NT stores) ----------------
__global__ __launch_bounds__(256) void k_gemm(
    const ushort_t* __restrict__ A, const ushort_t* __restrict__ Bt,
    const float* __restrict__ pbi, const float* __restrict__ pbf,
    const float* __restrict__ pbc, const float* __restrict__ pbo,
    ushort_t* __restrict__ gates) {
    __shared__ ushort_t As[128 * 64];
    __shared__ ushort_t Bs[128 * 64];
    const int tid = threadIdx.x, lane = tid & 63, wv = tid >> 6;
    const int bm = blockIdx.x & 127, bn = blockIdx.x >> 7;
    const size_t m0 = (size_t)bm * 128;
    const size_t n0 = (size_t)bn * 128;
    const int wm = wv >> 1, wn = wv & 1;
    f32x4 acc[4][4] = {};
    const int srow = tid >> 1, skof = (tid & 1) * 32;
    const ushort_t* ap = A + (m0 + srow) * 1024 + skof;
    const ushort_t* bp = Bt + (n0 + srow) * 1024 + skof;

    for (int kt = 0; kt < 16; ++kt) {
        int k0 = kt * 64;
#pragma unroll
        for (int i = 0; i < 4; ++i) {
            *(short8*)(&As[srow * 64 + skof + i * 8]) = *(const short8*)(ap + k0 + i * 8);
            *(short8*)(&Bs[srow * 64 + skof + i * 8]) = *(const short8*)(bp + k0 + i * 8);
        }
        __syncthreads();
#pragma unroll
        for (int kk = 0; kk < 64; kk += 32) {
            short8 af[4], bfr[4];
            int ko = kk + (lane >> 4) * 8;
#pragma unroll
            for (int mi = 0; mi < 4; ++mi) af[mi] = *(const short8*)(&As[(wm * 64 + mi * 16 + (lane & 15)) * 64 + ko]);
#pragma unroll
            for (int ni = 0; ni < 4; ++ni) bfr[ni] = *(const short8*)(&Bs[(wn * 64 + ni * 16 + (lane & 15)) * 64 + ko]);
#pragma unroll
            for (int mi = 0; mi < 4; ++mi)
#pragma unroll
                for (int ni = 0; ni < 4; ++ni)
                    acc[mi][ni] = __builtin_amdgcn_mfma_f32_16x16x32_bf16(af[mi], bfr[ni], acc[mi][ni], 0, 0, 0);
        }
        __syncthreads();
    }
    const int g = (int)(n0 >> 10);
    const float* bias = (g == 0) ? pbi : (g == 1) ? pbf : (g == 2) ? pbc : pbo;
#pragma unroll
    for (int ni = 0; ni < 4; ++ni) {
        int col = (int)n0 + wn * 64 + ni * 16 + (lane & 15);
        float bv = bias[col & 1023];
#pragma unroll
        for (int mi = 0; mi < 4; ++mi) {
            int row0 = (int)m0 + wm * 64 + mi * 16 + ((lane >> 4) << 2);
#pragma unroll
            for (int r = 0; r < 4; ++r)
                __builtin_nontemporal_store(f2bf(acc[mi][ni][r] + bv),
                                            &gates[(size_t)(row0 + r) * GCOLS + col]);
        }
    }
}

// ---------------- single-root tree barrier (u16 flags, root aggregates, GO broadcast) ----
__device__ __forceinline__ void xbar(unsigned short* flags, unsigned* go,
                                     int w, int wv, int lane, unsigned val) {
    if (wv == 0) {
        asm volatile("s_waitcnt vmcnt(0)" ::: "memory");
        if (lane == 0)
            __hip_atomic_store(&flags[w], (unsigned short)val, __ATOMIC_RELAXED, __HIP_MEMORY_SCOPE_AGENT);
        if (w == 0) {
            const unsigned* fp = (const unsigned*)flags;
            for (;;) {
                unsigned fl = __hip_atomic_load(&fp[lane], __ATOMIC_RELAXED, __HIP_MEMORY_SCOPE_AGENT);
                if (__all((fl & 0xFFFFu) >= val && (fl >> 16) >= val)) break;
            }
            if (lane == 0)
                __hip_atomic_store(go, val, __ATOMIC_RELAXED, __HIP_MEMORY_SCOPE_AGENT);
        } else {
            for (;;) {
                unsigned g = __hip_atomic_load(go, __ATOMIC_RELAXED, __HIP_MEMORY_SCOPE_AGENT);
                if (g >= val) break;
                __builtin_amdgcn_s_sleep(1);
            }
        }
    }
    __syncthreads();
}

// ---------------- persistent scan: 128 WGs (64 colgroups x 2 batch-halves) x 256 thr ----
// WG owns 16 hidden cols x 16 batch. Reads only its 16-batch half of h: 32KB/step
// (broadcast total 4MB/step, half of R5). V = 64 outcols x K/4 per wave, pinned in
// 128 VGPRs. K split across 4 waves; red-array reduce; gather fused into elementwise.
// h blocked [colchunk 0..127][batch 0..31][8 cols] bf16; all cross-WG traffic sc0sc1.
__global__ __launch_bounds__(256, 1) void k_scan(
    const ushort_t* __restrict__ gates, const ushort_t* __restrict__ VT,
    ushort_t* hbuf, unsigned short* flags, unsigned* go, float* __restrict__ out) {
    __shared__ float red[4 * 1024];                              // 16KB
    __shared__ ushort_t hsh[256] __attribute__((aligned(16)));   // 512B pack buffer
    const int tid = threadIdx.x, w = blockIdx.x;
    const int lane = tid & 63, wv = tid >> 6;
    const int q = lane >> 4;          // k-sub selector
    const int arow = lane & 15;       // batch row within half / V row within n-tile
    const int cg = w >> 1;            // col-group 0..63 (16 hidden cols)
    const int bh = w & 1;             // batch half

    // ---- V fragments: 4 gates x 8 k-steps, pinned in 128 VGPRs ----
    short8 bv[4][8];
#pragma unroll
    for (int g = 0; g < 4; ++g) {
        const ushort_t* vrow = VT + ((size_t)(g * 1024 + cg * 16 + arow)) * 1024 + wv * 256 + q * 8;
#pragma unroll
        for (int ks = 0; ks < 8; ++ks)
            bv[g][ks] = *(const short8*)(vrow + ks * 32);
    }
#pragma unroll
    for (int g = 0; g < 4; ++g)
#pragma unroll
        for (int ks = 0; ks < 8; ++ks)
            asm volatile("" : "+v"(*(i32x4*)&bv[g][ks]));

    const int bl = tid >> 4, hcl = tid & 15;          // thread's (batch_local, col_local)
    const int batch_g = bh * 16 + bl;
    const int col_g = cg * 16 + hcl;

    // zero h buffer 0: this WG's 2 half-blocks (2 x 256B)
    if (wv == 0 && lane < 32) {
        i32x4 z = {};
        st_h16(hbuf + ((cg * 2 + (lane >> 4)) * 32 + bh * 16 + (lane & 15)) * 8, z);
    }
    // prefetch gates t=0 (nontemporal)
    float cur[4];
    {
        size_t r0 = (size_t)batch_g * GCOLS + col_g;
#pragma unroll
        for (int g = 0; g < 4; ++g) cur[g] = bf2f(__builtin_nontemporal_load(&gates[r0 + g * 1024]));
    }
    xbar(flags, go, w, wv, lane, 1u);

    float c_reg = 0.f;
    for (int t = 0; t < SEQ; ++t) {
        const ushort_t* hc = hbuf + (t & 1) * 32768;

        // ---- h A-fragments: 8 x 16B coherent loads (own batch-half, K quarter) ----
        i32x4 hl[8];
#pragma unroll
        for (int ks = 0; ks < 8; ++ks) {
            int cchunk = wv * 32 + ks * 4 + q;
            ld_h16(&hl[ks], hc + (cchunk * 32 + bh * 16 + arow) * 8);
        }

        // ---- prefetch gates for t+1 (nontemporal) ----
        ushort_t pf[4];
        {
            int tn = (t + 1 < SEQ) ? t + 1 : 0;
            size_t r0 = (size_t)(tn * 32 + batch_g) * GCOLS + col_g;
#pragma unroll
            for (int g = 0; g < 4; ++g) pf[g] = __builtin_nontemporal_load(&gates[r0 + g * 1024]);
        }

        asm volatile("s_waitcnt vmcnt(0)" ::: "memory");
        __builtin_amdgcn_sched_barrier(0);

        // ---- MFMA: 8 k-steps x 4 gate-tiles (n-tile g = gate g) ----
        f32x4 acc[4] = {};
#pragma unroll
        for (int ks = 0; ks < 8; ++ks) {
            short8 A = __builtin_bit_cast(short8, hl[ks]);
            acc[0] = __builtin_amdgcn_mfma_f32_16x16x32_bf16(A, bv[0][ks], acc[0], 0, 0, 0);
            acc[1] = __builtin_amdgcn_mfma_f32_16x16x32_bf16(A, bv[1][ks], acc[1], 0, 0, 0);
            acc[2] = __builtin_amdgcn_mfma_f32_16x16x32_bf16(A, bv[2][ks], acc[2], 0, 0, 0);
            acc[3] = __builtin_amdgcn_mfma_f32_16x16x32_bf16(A, bv[3][ks], acc[3], 0, 0, 0);
        }

        // ---- red stores, rotated cols (2-way aliasing = free) ----
        {
            float* rp = red + wv * 1024;
#pragma unroll
            for (int g = 0; g < 4; ++g)
#pragma unroll
                for (int r = 0; r < 4; ++r) {
                    int bb = q * 4 + r;
                    int colrot = (g * 16 + arow + 16 * q) & 63;
                    rp[bb * 64 + colrot] = acc[g][r];
                }
        }
        __syncthreads();

        // ---- gather own 4 gate sums (fused cross-wave reduce) + elementwise ----
        {
            float s[4];
            int rotbase = 16 * (bl >> 2);
#pragma unroll
            for (int g = 0; g < 4; ++g) {
                int o = bl * 64 + ((g * 16 + hcl + rotbase) & 63);
                s[g] = red[o] + red[1024 + o] + red[2048 + o] + red[3072 + o] + cur[g];
            }
            c_reg = sigmoidf_(s[1]) * c_reg + sigmoidf_(s[0]) * tanhs_(s[2]);
            float h = sigmoidf_(s[3]) * tanhs_(c_reg);
            __builtin_nontemporal_store(h, &out[(size_t)t * 32768 + batch_g * 1024 + col_g]);
            hsh[(hcl >> 3) * 128 + bl * 8 + (hcl & 7)] = f2bf(h);
            if (t == SEQ - 1) {
                out[HSEQ_ELEMS + batch_g * 1024 + col_g] = h;
                out[HSEQ_ELEMS + 32768 + batch_g * 1024 + col_g] = c_reg;
                break;
            }
        }
#pragma unroll
        for (int g = 0; g < 4; ++g) cur[g] = bf2f(pf[g]);

        __syncthreads();  // hsh ready
        // ---- publish: 2 x 256B contiguous half-blocks (wave 0) ----
        if (wv == 0 && lane < 32) {
            ushort_t* hn = hbuf + ((t & 1) ^ 1) * 32768;
            int cc = lane >> 4, b2 = lane & 15;
            i32x4 v = *(const i32x4*)&hsh[cc * 128 + b2 * 8];
            st_h16(hn + ((cg * 2 + cc) * 32 + bh * 16 + b2) * 8, v);
        }
        xbar(flags, go, w, wv, lane, (unsigned)(t + 2));
    }
}

extern "C" void kernel_launch(void* const* d_in, const int* in_sizes, int n_in,
                              void* d_out, int out_size, void* d_ws, size_t ws_size,
                              hipStream_t stream) {
    const float* x  = (const float*)d_in[0];
    const float* Ui = (const float*)d_in[1];
    const float* Vi = (const float*)d_in[2];
    const float* bi = (const float*)d_in[3];
    const float* Uf = (const float*)d_in[4];
    const float* Vf = (const float*)d_in[5];
    const float* bfp= (const float*)d_in[6];
    const float* Uc = (const float*)d_in[7];
    const float* Vc = (const float*)d_in[8];
    const float* bc = (const float*)d_in[9];
    const float* Uo = (const float*)d_in[10];
    const float* Vo = (const float*)d_in[11];
    const float* bo = (const float*)d_in[12];

    char* ws = (char*)d_ws;
    unsigned short* flags = (unsigned short*)ws;              // 256 B (128 u16)
    unsigned* go    = (unsigned*)(ws + 512);                  // own cacheline
    ushort_t* hbuf  = (ushort_t*)(ws + 4096);                 // 131072 B (2 x blocked 32x1024 bf16)
    ushort_t* xbf   = (ushort_t*)(ws + 135168);               // 33554432 B
    ushort_t* UT    = (ushort_t*)(ws + 33689600);             // 8388608 B
    ushort_t* VT    = (ushort_t*)(ws + 42078208);             // 8388608 B
    ushort_t* gates = (ushort_t*)(ws + 50466816);             // 134217728 B

    hipMemsetAsync(ws, 0, 4096, stream);
    hipLaunchKernelGGL(k_convert_x, dim3(8192), dim3(256), 0, stream, x, xbf);
    hipLaunchKernelGGL(k_transpose8, dim3(8192), dim3(256), 0, stream,
                       Ui, Uf, Uc, Uo, Vi, Vf, Vc, Vo, UT, VT);
    hipLaunchKernelGGL(k_gemm, dim3(4096), dim3(256), 0, stream,
                       xbf, UT, bi, bfp, bc, bo, gates);
    hipLaunchKernelGGL(k_scan, dim3(NWG), dim3(256), 0, stream,
                       gates, VT, hbuf, flags, go, (float*)d_out);
}

// Round 7
// 2596.966 us; speedup vs baseline: 3.6478x; 1.0504x over previous
//
#include <hip/hip_runtime.h>

typedef unsigned short ushort_t;
typedef unsigned long long u64;
typedef __attribute__((ext_vector_type(8))) short short8;
typedef __attribute__((ext_vector_type(4))) float f32x4;
typedef __attribute__((ext_vector_type(4))) int i32x4;

#define SEQ 512
#define HID 1024
#define GCOLS 4096           // 4*HID
#define HSEQ_ELEMS 16777216  // SEQ*BATCH*HID
#define NWG 128              // 64 col-groups x 2 batch-halves

__device__ __forceinline__ ushort_t f2bf(float f) {
    unsigned u = __float_as_uint(f);
    unsigned r = (u + 0x7FFFu + ((u >> 16) & 1u)) >> 16;
    return (ushort_t)r;
}
__device__ __forceinline__ float bf2f(ushort_t u) {
    return __uint_as_float(((unsigned)u) << 16);
}
__device__ __forceinline__ float sigmoidf_(float x) { return 1.f / (1.f + __expf(-x)); }
__device__ __forceinline__ float tanhs_(float x) {
    float ax = fabsf(x);
    float e  = __expf(-2.f * ax);
    float t  = (1.f - e) / (1.f + e);
    return copysignf(t, x);
}

// 16B coherent (device-scope) load/store at the L3 coherence point.
__device__ __forceinline__ void ld_h16(i32x4* dst, const ushort_t* p) {
    asm volatile("global_load_dwordx4 %0, %1, off sc0 sc1"
                 : "=&v"(*dst) : "v"(p) : "memory");
}
__device__ __forceinline__ void st_h16(ushort_t* p, i32x4 v) {
    asm volatile("global_store_dwordx4 %0, %1, off sc0 sc1"
                 :: "v"(p), "v"(v) : "memory");
}

// async global->LDS, 16B per lane (dest = wave-uniform base + lane*16)
__device__ __forceinline__ void gload_lds16(const ushort_t* g, ushort_t* l) {
    __builtin_amdgcn_global_load_lds(
        (const __attribute__((address_space(1))) unsigned*)g,
        (__attribute__((address_space(3))) unsigned*)l, 16, 0, 0);
}

// ---------------- convert x (fp32 -> bf16) ----------------
__global__ __launch_bounds__(256) void k_convert_x(const float* __restrict__ x, ushort_t* __restrict__ xbf) {
    size_t i = ((size_t)blockIdx.x * 256 + threadIdx.x) * 8;
    float4 a = *(const float4*)(x + i);
    float4 b = *(const float4*)(x + i + 4);
    short8 v;
    v[0] = (short)f2bf(a.x); v[1] = (short)f2bf(a.y); v[2] = (short)f2bf(a.z); v[3] = (short)f2bf(a.w);
    v[4] = (short)f2bf(b.x); v[5] = (short)f2bf(b.y); v[6] = (short)f2bf(b.z); v[7] = (short)f2bf(b.w);
    *(short8*)(xbf + i) = v;
}

// ---------------- transpose-convert 8 square matrices ----------------
__global__ __launch_bounds__(256) void k_transpose8(
    const float* __restrict__ u0, const float* __restrict__ u1, const float* __restrict__ u2, const float* __restrict__ u3,
    const float* __restrict__ v0, const float* __restrict__ v1, const float* __restrict__ v2, const float* __restrict__ v3,
    ushort_t* __restrict__ UT, ushort_t* __restrict__ VT) {
    __shared__ float tile[32][33];
    int m  = blockIdx.x >> 10;    // matrix 0..7
    int tl = blockIdx.x & 1023;
    int tr = tl >> 5, tc = tl & 31;
    const float* src = (m == 0) ? u0 : (m == 1) ? u1 : (m == 2) ? u2 : (m == 3) ? u3
                      : (m == 4) ? v0 : (m == 5) ? v1 : (m == 6) ? v2 : v3;
    int r = threadIdx.x >> 5, c = threadIdx.x & 31;
    int k0 = tr * 32, n0 = tc * 32;
#pragma unroll
    for (int i = 0; i < 4; ++i)
        tile[r + 8 * i][c] = src[(size_t)(k0 + r + 8 * i) * HID + n0 + c];
    __syncthreads();
    ushort_t* dst = (m < 4) ? (UT + (size_t)m * HID * HID) : (VT + (size_t)(m - 4) * HID * HID);
#pragma unroll
    for (int i = 0; i < 4; ++i) {
        int row = r + 8 * i;
        dst[(size_t)(n0 + row) * HID + k0 + c] = f2bf(tile[c][row]);
    }
}

// ---------------- phase-1 GEMM: gates_pre = x_bf @ U + bias ----------------
// m97 structure: global_load_lds width=16 staging, 128x128 tile, BK=64, 2-barrier loop.
__global__ __launch_bounds__(256) void k_gemm(
    const ushort_t* __restrict__ A, const ushort_t* __restrict__ Bt,
    const float* __restrict__ pbi, const float* __restrict__ pbf,
    const float* __restrict__ pbc, const float* __restrict__ pbo,
    ushort_t* __restrict__ gates) {
    __shared__ ushort_t As[128 * 64];
    __shared__ ushort_t Bs[128 * 64];
    const int tid = threadIdx.x, lane = tid & 63, wv = tid >> 6;
    const int bm = blockIdx.x & 127, bn = blockIdx.x >> 7;
    const size_t m0 = (size_t)bm * 128;
    const size_t n0 = (size_t)bn * 128;
    const int wm = wv >> 1, wn = wv & 1;
    f32x4 acc[4][4] = {};
    const int rsub = lane >> 3;        // 0..7 row within 8-row chunk
    const int koff = (lane & 7) * 8;   // k element offset

    for (int kt = 0; kt < 16; ++kt) {
        int k0 = kt * 64;
#pragma unroll
        for (int j = 0; j < 4; ++j) {
            int row = wv * 32 + j * 8 + rsub;
            gload_lds16(A  + (m0 + row) * 1024 + k0 + koff, &As[wv * 2048 + j * 512]);
            gload_lds16(Bt + (n0 + row) * 1024 + k0 + koff, &Bs[wv * 2048 + j * 512]);
        }
        __syncthreads();   // compiler drains vmcnt before s_barrier
#pragma unroll
        for (int kk = 0; kk < 64; kk += 32) {
            short8 af[4], bfr[4];
            int ko = kk + (lane >> 4) * 8;
#pragma unroll
            for (int mi = 0; mi < 4; ++mi) af[mi] = *(const short8*)(&As[(wm * 64 + mi * 16 + (lane & 15)) * 64 + ko]);
#pragma unroll
            for (int ni = 0; ni < 4; ++ni) bfr[ni] = *(const short8*)(&Bs[(wn * 64 + ni * 16 + (lane & 15)) * 64 + ko]);
#pragma unroll
            for (int mi = 0; mi < 4; ++mi)
#pragma unroll
                for (int ni = 0; ni < 4; ++ni)
                    acc[mi][ni] = __builtin_amdgcn_mfma_f32_16x16x32_bf16(af[mi], bfr[ni], acc[mi][ni], 0, 0, 0);
        }
        __syncthreads();
    }
    const int g = (int)(n0 >> 10);
    const float* bias = (g == 0) ? pbi : (g == 1) ? pbf : (g == 2) ? pbc : pbo;
#pragma unroll
    for (int ni = 0; ni < 4; ++ni) {
        int col = (int)n0 + wn * 64 + ni * 16 + (lane & 15);
        float bv = bias[col & 1023];
#pragma unroll
        for (int mi = 0; mi < 4; ++mi) {
            int row0 = (int)m0 + wm * 64 + mi * 16 + ((lane >> 4) << 2);
#pragma unroll
            for (int r = 0; r < 4; ++r)
                __builtin_nontemporal_store(f2bf(acc[mi][ni][r] + bv),
                                            &gates[(size_t)(row0 + r) * GCOLS + col]);
        }
    }
}

// ---------------- flat group barrier: 64 u32 flags, consumers poll directly ----------------
// One group = the 64 WGs of one batch-half (dependency-closed). No root, no GO:
// wave0's 64 lanes each poll one flag; s_sleep backoff prevents L3 port storm.
__device__ __forceinline__ void gbar2(unsigned* gflags, int cg, int wv, int lane, unsigned val) {
    if (wv == 0) {
        asm volatile("s_waitcnt vmcnt(0)" ::: "memory");
        if (lane == 0)
            __hip_atomic_store(&gflags[cg], val, __ATOMIC_RELAXED, __HIP_MEMORY_SCOPE_AGENT);
        for (;;) {
            unsigned f = __hip_atomic_load(&gflags[lane], __ATOMIC_RELAXED, __HIP_MEMORY_SCOPE_AGENT);
            if (__all(f >= val)) break;
            __builtin_amdgcn_s_sleep(1);
        }
    }
    __syncthreads();
}

// ---------------- persistent scan: 128 WGs (64 colgroups x 2 batch-halves) x 256 thr ----
// WG owns 16 hidden cols x 16 batch. V pinned in 128 VGPRs. K split across 4 waves;
// red-array reduce fused into elementwise. h blocked [colchunk][batch][8] bf16, sc0sc1.
__global__ __launch_bounds__(256, 1) void k_scan(
    const ushort_t* __restrict__ gates, const ushort_t* __restrict__ VT,
    ushort_t* hbuf, unsigned* flags, float* __restrict__ out) {
    __shared__ float red[4 * 1024];                              // 16KB
    __shared__ ushort_t hsh[256] __attribute__((aligned(16)));   // 512B pack buffer
    const int tid = threadIdx.x, w = blockIdx.x;
    const int lane = tid & 63, wv = tid >> 6;
    const int q = lane >> 4;          // k-sub selector
    const int arow = lane & 15;       // batch row within half / V row within n-tile
    const int cg = w >> 1;            // col-group 0..63 (16 hidden cols)
    const int bh = w & 1;             // batch half
    unsigned* gflags = flags + bh * 64;

    // ---- V fragments: 4 gates x 8 k-steps, pinned in 128 VGPRs ----
    short8 bv[4][8];
#pragma unroll
    for (int g = 0; g < 4; ++g) {
        const ushort_t* vrow = VT + ((size_t)(g * 1024 + cg * 16 + arow)) * 1024 + wv * 256 + q * 8;
#pragma unroll
        for (int ks = 0; ks < 8; ++ks)
            bv[g][ks] = *(const short8*)(vrow + ks * 32);
    }
#pragma unroll
    for (int g = 0; g < 4; ++g)
#pragma unroll
        for (int ks = 0; ks < 8; ++ks)
            asm volatile("" : "+v"(*(i32x4*)&bv[g][ks]));

    const int bl = tid >> 4, hcl = tid & 15;          // thread's (batch_local, col_local)
    const int batch_g = bh * 16 + bl;
    const int col_g = cg * 16 + hcl;

    // zero h buffer 0: this WG's 2 half-blocks (2 x 256B)
    if (wv == 0 && lane < 32) {
        i32x4 z = {};
        st_h16(hbuf + ((cg * 2 + (lane >> 4)) * 32 + bh * 16 + (lane & 15)) * 8, z);
    }
    // prefetch gates t=0 (nontemporal)
    float cur[4];
    {
        size_t r0 = (size_t)batch_g * GCOLS + col_g;
#pragma unroll
        for (int g = 0; g < 4; ++g) cur[g] = bf2f(__builtin_nontemporal_load(&gates[r0 + g * 1024]));
    }
    gbar2(gflags, cg, wv, lane, 1u);

    float c_reg = 0.f;
    for (int t = 0; t < SEQ; ++t) {
        const ushort_t* hc = hbuf + (t & 1) * 32768;

        // ---- h A-fragments: 8 x 16B coherent loads (own batch-half, K quarter) ----
        i32x4 hl[8];
#pragma unroll
        for (int ks = 0; ks < 8; ++ks) {
            int cchunk = wv * 32 + ks * 4 + q;
            ld_h16(&hl[ks], hc + (cchunk * 32 + bh * 16 + arow) * 8);
        }

        // ---- prefetch gates for t+1 (nontemporal) ----
        ushort_t pf[4];
        {
            int tn = (t + 1 < SEQ) ? t + 1 : 0;
            size_t r0 = (size_t)(tn * 32 + batch_g) * GCOLS + col_g;
#pragma unroll
            for (int g = 0; g < 4; ++g) pf[g] = __builtin_nontemporal_load(&gates[r0 + g * 1024]);
        }

        asm volatile("s_waitcnt vmcnt(0)" ::: "memory");
        __builtin_amdgcn_sched_barrier(0);

        // ---- MFMA: 8 k-steps x 4 gate-tiles ----
        f32x4 acc[4] = {};
#pragma unroll
        for (int ks = 0; ks < 8; ++ks) {
            short8 A = __builtin_bit_cast(short8, hl[ks]);
            acc[0] = __builtin_amdgcn_mfma_f32_16x16x32_bf16(A, bv[0][ks], acc[0], 0, 0, 0);
            acc[1] = __builtin_amdgcn_mfma_f32_16x16x32_bf16(A, bv[1][ks], acc[1], 0, 0, 0);
            acc[2] = __builtin_amdgcn_mfma_f32_16x16x32_bf16(A, bv[2][ks], acc[2], 0, 0, 0);
            acc[3] = __builtin_amdgcn_mfma_f32_16x16x32_bf16(A, bv[3][ks], acc[3], 0, 0, 0);
        }

        // ---- red stores, rotated cols (2-way aliasing = free) ----
        {
            float* rp = red + wv * 1024;
#pragma unroll
            for (int g = 0; g < 4; ++g)
#pragma unroll
                for (int r = 0; r < 4; ++r) {
                    int bb = q * 4 + r;
                    int colrot = (g * 16 + arow + 16 * q) & 63;
                    rp[bb * 64 + colrot] = acc[g][r];
                }
        }
        __syncthreads();

        // ---- gather own 4 gate sums (fused cross-wave reduce) + elementwise ----
        {
            float s[4];
            int rotbase = 16 * (bl >> 2);
#pragma unroll
            for (int g = 0; g < 4; ++g) {
                int o = bl * 64 + ((g * 16 + hcl + rotbase) & 63);
                s[g] = red[o] + red[1024 + o] + red[2048 + o] + red[3072 + o] + cur[g];
            }
            c_reg = sigmoidf_(s[1]) * c_reg + sigmoidf_(s[0]) * tanhs_(s[2]);
            float h = sigmoidf_(s[3]) * tanhs_(c_reg);
            __builtin_nontemporal_store(h, &out[(size_t)t * 32768 + batch_g * 1024 + col_g]);
            hsh[(hcl >> 3) * 128 + bl * 8 + (hcl & 7)] = f2bf(h);
            if (t == SEQ - 1) {
                out[HSEQ_ELEMS + batch_g * 1024 + col_g] = h;
                out[HSEQ_ELEMS + 32768 + batch_g * 1024 + col_g] = c_reg;
                break;
            }
        }
#pragma unroll
        for (int g = 0; g < 4; ++g) cur[g] = bf2f(pf[g]);

        __syncthreads();  // hsh ready
        // ---- publish: 2 x 256B contiguous half-blocks (wave 0) ----
        if (wv == 0 && lane < 32) {
            ushort_t* hn = hbuf + ((t & 1) ^ 1) * 32768;
            int cc = lane >> 4, b2 = lane & 15;
            i32x4 v = *(const i32x4*)&hsh[cc * 128 + b2 * 8];
            st_h16(hn + ((cg * 2 + cc) * 32 + bh * 16 + b2) * 8, v);
        }
        gbar2(gflags, cg, wv, lane, (unsigned)(t + 2));
    }
}

extern "C" void kernel_launch(void* const* d_in, const int* in_sizes, int n_in,
                              void* d_out, int out_size, void* d_ws, size_t ws_size,
                              hipStream_t stream) {
    const float* x  = (const float*)d_in[0];
    const float* Ui = (const float*)d_in[1];
    const float* Vi = (const float*)d_in[2];
    const float* bi = (const float*)d_in[3];
    const float* Uf = (const float*)d_in[4];
    const float* Vf = (const float*)d_in[5];
    const float* bfp= (const float*)d_in[6];
    const float* Uc = (const float*)d_in[7];
    const float* Vc = (const float*)d_in[8];
    const float* bc = (const float*)d_in[9];
    const float* Uo = (const float*)d_in[10];
    const float* Vo = (const float*)d_in[11];
    const float* bo = (const float*)d_in[12];

    char* ws = (char*)d_ws;
    unsigned* flags = (unsigned*)ws;                          // 512 B (2 groups x 64 u32)
    ushort_t* hbuf  = (ushort_t*)(ws + 4096);                 // 131072 B (2 x blocked 32x1024 bf16)
    ushort_t* xbf   = (ushort_t*)(ws + 135168);               // 33554432 B
    ushort_t* UT    = (ushort_t*)(ws + 33689600);             // 8388608 B
    ushort_t* VT    = (ushort_t*)(ws + 42078208);             // 8388608 B
    ushort_t* gates = (ushort_t*)(ws + 50466816);             // 134217728 B

    hipMemsetAsync(ws, 0, 4096, stream);
    hipLaunchKernelGGL(k_convert_x, dim3(8192), dim3(256), 0, stream, x, xbf);
    hipLaunchKernelGGL(k_transpose8, dim3(8192), dim3(256), 0, stream,
                       Ui, Uf, Uc, Uo, Vi, Vf, Vc, Vo, UT, VT);
    hipLaunchKernelGGL(k_gemm, dim3(4096), dim3(256), 0, stream,
                       xbf, UT, bi, bfp, bc, bo, gates);
    hipLaunchKernelGGL(k_scan, dim3(NWG), dim3(256), 0, stream,
                       gates, VT, hbuf, flags, (float*)d_out);
}

// Round 8
// 2257.135 us; speedup vs baseline: 4.1970x; 1.1506x over previous
//
#include <hip/hip_runtime.h>

typedef unsigned short ushort_t;
typedef unsigned long long u64;
typedef __attribute__((ext_vector_type(8))) short short8;
typedef __attribute__((ext_vector_type(4))) float f32x4;
typedef __attribute__((ext_vector_type(4))) int i32x4;

#define SEQ 512
#define HID 1024
#define GCOLS 4096           // 4*HID
#define HSEQ_ELEMS 16777216  // SEQ*BATCH*HID
#define NWG 128              // 64 col-groups x 2 batch-halves

__device__ __forceinline__ ushort_t f2bf(float f) {
    unsigned u = __float_as_uint(f);
    unsigned r = (u + 0x7FFFu + ((u >> 16) & 1u)) >> 16;
    return (ushort_t)r;
}
__device__ __forceinline__ float bf2f(ushort_t u) {
    return __uint_as_float(((unsigned)u) << 16);
}
__device__ __forceinline__ float sigmoidf_(float x) { return 1.f / (1.f + __expf(-x)); }
__device__ __forceinline__ float tanhs_(float x) {
    float ax = fabsf(x);
    float e  = __expf(-2.f * ax);
    float t  = (1.f - e) / (1.f + e);
    return copysignf(t, x);
}
// pack two f32 -> two bf16 in one dword (dst.lo = src0, dst.hi = src1)
__device__ __forceinline__ unsigned cvtpk(float lo, float hi) {
    unsigned r;
    asm volatile("v_cvt_pk_bf16_f32 %0, %1, %2" : "=v"(r) : "v"(lo), "v"(hi));
    return r;
}

// 16B coherent (device-scope) load/store at the L3 coherence point.
__device__ __forceinline__ void ld_h16f(i32x4* dst, const float* p) {
    asm volatile("global_load_dwordx4 %0, %1, off sc0 sc1"
                 : "=&v"(*dst) : "v"(p) : "memory");
}
__device__ __forceinline__ void st_h16f(float* p, i32x4 v) {
    asm volatile("global_store_dwordx4 %0, %1, off sc0 sc1"
                 :: "v"(p), "v"(v) : "memory");
}

// async global->LDS, 16B per lane (dest = wave-uniform base + lane*16)
__device__ __forceinline__ void gload_lds16(const ushort_t* g, ushort_t* l) {
    __builtin_amdgcn_global_load_lds(
        (const __attribute__((address_space(1))) unsigned*)g,
        (__attribute__((address_space(3))) unsigned*)l, 16, 0, 0);
}

// ---------------- convert x (fp32 -> bf16) ----------------
__global__ __launch_bounds__(256) void k_convert_x(const float* __restrict__ x, ushort_t* __restrict__ xbf) {
    size_t i = ((size_t)blockIdx.x * 256 + threadIdx.x) * 8;
    float4 a = *(const float4*)(x + i);
    float4 b = *(const float4*)(x + i + 4);
    short8 v;
    v[0] = (short)f2bf(a.x); v[1] = (short)f2bf(a.y); v[2] = (short)f2bf(a.z); v[3] = (short)f2bf(a.w);
    v[4] = (short)f2bf(b.x); v[5] = (short)f2bf(b.y); v[6] = (short)f2bf(b.z); v[7] = (short)f2bf(b.w);
    *(short8*)(xbf + i) = v;
}

// ---------------- transpose-convert 8 square matrices ----------------
__global__ __launch_bounds__(256) void k_transpose8(
    const float* __restrict__ u0, const float* __restrict__ u1, const float* __restrict__ u2, const float* __restrict__ u3,
    const float* __restrict__ v0, const float* __restrict__ v1, const float* __restrict__ v2, const float* __restrict__ v3,
    ushort_t* __restrict__ UT, ushort_t* __restrict__ VT) {
    __shared__ float tile[32][33];
    int m  = blockIdx.x >> 10;    // matrix 0..7
    int tl = blockIdx.x & 1023;
    int tr = tl >> 5, tc = tl & 31;
    const float* src = (m == 0) ? u0 : (m == 1) ? u1 : (m == 2) ? u2 : (m == 3) ? u3
                      : (m == 4) ? v0 : (m == 5) ? v1 : (m == 6) ? v2 : v3;
    int r = threadIdx.x >> 5, c = threadIdx.x & 31;
    int k0 = tr * 32, n0 = tc * 32;
#pragma unroll
    for (int i = 0; i < 4; ++i)
        tile[r + 8 * i][c] = src[(size_t)(k0 + r + 8 * i) * HID + n0 + c];
    __syncthreads();
    ushort_t* dst = (m < 4) ? (UT + (size_t)m * HID * HID) : (VT + (size_t)(m - 4) * HID * HID);
#pragma unroll
    for (int i = 0; i < 4; ++i) {
        int row = r + 8 * i;
        dst[(size_t)(n0 + row) * HID + k0 + c] = f2bf(tile[c][row]);
    }
}

// ---------------- phase-1 GEMM: gates_pre = x_bf @ U + bias ----------------
// m97 structure: global_load_lds width=16 staging, 128x128 tile, BK=64, 2-barrier loop.
__global__ __launch_bounds__(256) void k_gemm(
    const ushort_t* __restrict__ A, const ushort_t* __restrict__ Bt,
    const float* __restrict__ pbi, const float* __restrict__ pbf,
    const float* __restrict__ pbc, const float* __restrict__ pbo,
    ushort_t* __restrict__ gates) {
    __shared__ ushort_t As[128 * 64];
    __shared__ ushort_t Bs[128 * 64];
    const int tid = threadIdx.x, lane = tid & 63, wv = tid >> 6;
    const int bm = blockIdx.x & 127, bn = blockIdx.x >> 7;
    const size_t m0 = (size_t)bm * 128;
    const size_t n0 = (size_t)bn * 128;
    const int wm = wv >> 1, wn = wv & 1;
    f32x4 acc[4][4] = {};
    const int rsub = lane >> 3;        // 0..7 row within 8-row chunk
    const int koff = (lane & 7) * 8;   // k element offset

    for (int kt = 0; kt < 16; ++kt) {
        int k0 = kt * 64;
#pragma unroll
        for (int j = 0; j < 4; ++j) {
            int row = wv * 32 + j * 8 + rsub;
            gload_lds16(A  + (m0 + row) * 1024 + k0 + koff, &As[wv * 2048 + j * 512]);
            gload_lds16(Bt + (n0 + row) * 1024 + k0 + koff, &Bs[wv * 2048 + j * 512]);
        }
        __syncthreads();   // compiler drains vmcnt before s_barrier
#pragma unroll
        for (int kk = 0; kk < 64; kk += 32) {
            short8 af[4], bfr[4];
            int ko = kk + (lane >> 4) * 8;
#pragma unroll
            for (int mi = 0; mi < 4; ++mi) af[mi] = *(const short8*)(&As[(wm * 64 + mi * 16 + (lane & 15)) * 64 + ko]);
#pragma unroll
            for (int ni = 0; ni < 4; ++ni) bfr[ni] = *(const short8*)(&Bs[(wn * 64 + ni * 16 + (lane & 15)) * 64 + ko]);
#pragma unroll
            for (int mi = 0; mi < 4; ++mi)
#pragma unroll
                for (int ni = 0; ni < 4; ++ni)
                    acc[mi][ni] = __builtin_amdgcn_mfma_f32_16x16x32_bf16(af[mi], bfr[ni], acc[mi][ni], 0, 0, 0);
        }
        __syncthreads();
    }
    const int g = (int)(n0 >> 10);
    const float* bias = (g == 0) ? pbi : (g == 1) ? pbf : (g == 2) ? pbc : pbo;
#pragma unroll
    for (int ni = 0; ni < 4; ++ni) {
        int col = (int)n0 + wn * 64 + ni * 16 + (lane & 15);
        float bv = bias[col & 1023];
#pragma unroll
        for (int mi = 0; mi < 4; ++mi) {
            int row0 = (int)m0 + wm * 64 + mi * 16 + ((lane >> 4) << 2);
#pragma unroll
            for (int r = 0; r < 4; ++r)
                __builtin_nontemporal_store(f2bf(acc[mi][ni][r] + bv),
                                            &gates[(size_t)(row0 + r) * GCOLS + col]);
        }
    }
}

// ---------------- persistent scan: 128 WGs (64 colgroups x 2 batch-halves) x 256 thr ----
// BARRIER-FREE dataflow: h published as f32 with a 2-bit step tag in the low mantissa
// bits of every dword. Consumers poll the data blocks directly and retry stale ones.
// Backpressure is structural (2-deep buffer + dependency chain). No flags, no fences,
// no vmcnt(0) on the publish path. h layout: [kchunk(256)][batch(32)][4 f32] per buffer.
__global__ __launch_bounds__(256, 1) void k_scan(
    const ushort_t* __restrict__ gates, const ushort_t* __restrict__ VT,
    float* hbuf, float* __restrict__ out) {
    __shared__ float red[4 * 1024];                            // 16KB
    __shared__ float hshF[256] __attribute__((aligned(16)));   // 1KB pack buffer (f32)
    const int tid = threadIdx.x, w = blockIdx.x;
    const int lane = tid & 63, wv = tid >> 6;
    const int q = lane >> 4;          // k-sub selector
    const int arow = lane & 15;       // batch row within half / V row within n-tile
    const int cg = w >> 1;            // col-group 0..63 (16 hidden cols)
    const int bh = w & 1;             // batch half

    // ---- V fragments: 4 gates x 8 k-steps, pinned in 128 VGPRs ----
    short8 bv[4][8];
#pragma unroll
    for (int g = 0; g < 4; ++g) {
        const ushort_t* vrow = VT + ((size_t)(g * 1024 + cg * 16 + arow)) * 1024 + wv * 256 + q * 8;
#pragma unroll
        for (int ks = 0; ks < 8; ++ks)
            bv[g][ks] = *(const short8*)(vrow + ks * 32);
    }

    const int bl = tid >> 4, hcl = tid & 15;          // thread's (batch_local, col_local)
    const int batch_g = bh * 16 + bl;
    const int col_g = cg * 16 + hcl;

    // prefetch gates t=0 (nontemporal)
    float cur[4];
    {
        size_t r0 = (size_t)batch_g * GCOLS + col_g;
#pragma unroll
        for (int g = 0; g < 4; ++g) cur[g] = bf2f(__builtin_nontemporal_load(&gates[r0 + g * 1024]));
    }

    float c_reg = 0.f;
    for (int t = 0; t < SEQ; ++t) {
        // re-pin V each iteration: forces residency (compiler may not sink loads into loop)
#pragma unroll
        for (int g = 0; g < 4; ++g)
#pragma unroll
            for (int ks = 0; ks < 8; ++ks)
                asm volatile("" : "+v"(*(i32x4*)&bv[g][ks]));

        const float* hc = hbuf + (t & 1) * 32768;

        // ---- prefetch gates for t+1 (nontemporal, off critical path) ----
        ushort_t pf[4];
        {
            int tn = (t + 1 < SEQ) ? t + 1 : 0;
            size_t r0 = (size_t)(tn * 32 + batch_g) * GCOLS + col_g;
#pragma unroll
            for (int g = 0; g < 4; ++g) pf[g] = __builtin_nontemporal_load(&gates[r0 + g * 1024]);
        }

        f32x4 acc[4] = {};
        if (t > 0) {
            // ---- poll-load h: 16 x 16B blocks, validate 2-bit tag per dword, retry stale ----
            i32x4 hb[16];
            const unsigned p = (unsigned)(t & 3);
            const float* hbase = hc + ((wv * 64 + q * 2) * 32 + bh * 16 + arow) * 4;
            unsigned stale = 0xFFFFu;
            for (;;) {
#pragma unroll
                for (int bx = 0; bx < 16; ++bx)
                    if (stale & (1u << bx))
                        ld_h16f(&hb[bx], hbase + (bx >> 1) * 1024 + (bx & 1) * 128);
                asm volatile("s_waitcnt vmcnt(0)" ::: "memory");
                unsigned ns = 0;
#pragma unroll
                for (int bx = 0; bx < 16; ++bx)
                    if (stale & (1u << bx)) {
                        unsigned m = ((((unsigned)hb[bx][0]) ^ p) | (((unsigned)hb[bx][1]) ^ p) |
                                      (((unsigned)hb[bx][2]) ^ p) | (((unsigned)hb[bx][3]) ^ p)) & 3u;
                        if (m) ns |= 1u << bx;
                    }
                stale = ns;
                if (__all(stale == 0)) break;
            }
            __builtin_amdgcn_sched_barrier(0);

            // ---- convert f32->bf16 (cvt_pk) and MFMA: 8 k-steps x 4 gate-tiles ----
#pragma unroll
            for (int ks = 0; ks < 8; ++ks) {
                const float* fA = (const float*)&hb[2 * ks];
                const float* fB = (const float*)&hb[2 * ks + 1];
                union { unsigned d[4]; short8 s; } A;
                A.d[0] = cvtpk(fA[0], fA[1]);
                A.d[1] = cvtpk(fA[2], fA[3]);
                A.d[2] = cvtpk(fB[0], fB[1]);
                A.d[3] = cvtpk(fB[2], fB[3]);
                acc[0] = __builtin_amdgcn_mfma_f32_16x16x32_bf16(A.s, bv[0][ks], acc[0], 0, 0, 0);
                acc[1] = __builtin_amdgcn_mfma_f32_16x16x32_bf16(A.s, bv[1][ks], acc[1], 0, 0, 0);
                acc[2] = __builtin_amdgcn_mfma_f32_16x16x32_bf16(A.s, bv[2][ks], acc[2], 0, 0, 0);
                acc[3] = __builtin_amdgcn_mfma_f32_16x16x32_bf16(A.s, bv[3][ks], acc[3], 0, 0, 0);
            }
        }

        // ---- red stores, rotated cols (2-way aliasing = free) ----
        {
            float* rp = red + wv * 1024;
#pragma unroll
            for (int g = 0; g < 4; ++g)
#pragma unroll
                for (int r = 0; r < 4; ++r) {
                    int bb = q * 4 + r;
                    int colrot = (g * 16 + arow + 16 * q) & 63;
                    rp[bb * 64 + colrot] = acc[g][r];
                }
        }
        __syncthreads();

        // ---- gather own 4 gate sums (fused cross-wave reduce) + elementwise ----
        float h;
        {
            float s[4];
            int rotbase = 16 * (bl >> 2);
#pragma unroll
            for (int g = 0; g < 4; ++g) {
                int o = bl * 64 + ((g * 16 + hcl + rotbase) & 63);
                s[g] = red[o] + red[1024 + o] + red[2048 + o] + red[3072 + o] + cur[g];
            }
            c_reg = sigmoidf_(s[1]) * c_reg + sigmoidf_(s[0]) * tanhs_(s[2]);
            h = sigmoidf_(s[3]) * tanhs_(c_reg);
            __builtin_nontemporal_store(h, &out[(size_t)t * 32768 + batch_g * 1024 + col_g]);
            if (t == SEQ - 1) {
                out[HSEQ_ELEMS + batch_g * 1024 + col_g] = h;
                out[HSEQ_ELEMS + 32768 + batch_g * 1024 + col_g] = c_reg;
                break;
            }
        }
        // tag h with (t+1)&3 in the low 2 mantissa bits, pack into LDS
        {
            unsigned hv = (__float_as_uint(h) & ~3u) | (unsigned)((t + 1) & 3);
            hshF[(hcl >> 2) * 64 + bl * 4 + (hcl & 3)] = __uint_as_float(hv);
        }
#pragma unroll
        for (int g = 0; g < 4; ++g) cur[g] = bf2f(pf[g]);

        __syncthreads();  // hshF ready; also orders red gather vs next red stores
        // ---- publish: wave0, 64 x 16B coherent stores, NO drain, NO flag ----
        if (wv == 0) {
            float* hn = hbuf + ((t & 1) ^ 1) * 32768;
            int kbl = lane >> 4, b2 = lane & 15;
            i32x4 v = *(const i32x4*)&hshF[kbl * 64 + b2 * 4];
            st_h16f(hn + ((cg * 4 + kbl) * 32 + bh * 16 + b2) * 4, v);
        }
    }
}

extern "C" void kernel_launch(void* const* d_in, const int* in_sizes, int n_in,
                              void* d_out, int out_size, void* d_ws, size_t ws_size,
                              hipStream_t stream) {
    const float* x  = (const float*)d_in[0];
    const float* Ui = (const float*)d_in[1];
    const float* Vi = (const float*)d_in[2];
    const float* bi = (const float*)d_in[3];
    const float* Uf = (const float*)d_in[4];
    const float* Vf = (const float*)d_in[5];
    const float* bfp= (const float*)d_in[6];
    const float* Uc = (const float*)d_in[7];
    const float* Vc = (const float*)d_in[8];
    const float* bc = (const float*)d_in[9];
    const float* Uo = (const float*)d_in[10];
    const float* Vo = (const float*)d_in[11];
    const float* bo = (const float*)d_in[12];

    char* ws = (char*)d_ws;
    float* hbufF    = (float*)(ws + 4096);                    // 262144 B (2 x [256][32][4] f32)
    ushort_t* xbf   = (ushort_t*)(ws + 266240);               // 33554432 B
    ushort_t* UT    = (ushort_t*)(ws + 33820672);             // 8388608 B
    ushort_t* VT    = (ushort_t*)(ws + 42209280);             // 8388608 B
    ushort_t* gates = (ushort_t*)(ws + 50597888);             // 134217728 B -> end ~184.8MB

    // poison h buffers with INVALID tags for their parity:
    // buf0 (even steps, tags {0,2}): 0x01010101 -> tag 1.  buf1 (odd, {1,3}): 0x02020202 -> tag 2.
    hipMemsetAsync(ws + 4096, 0x01, 131072, stream);
    hipMemsetAsync(ws + 4096 + 131072, 0x02, 131072, stream);
    hipLaunchKernelGGL(k_convert_x, dim3(8192), dim3(256), 0, stream, x, xbf);
    hipLaunchKernelGGL(k_transpose8, dim3(8192), dim3(256), 0, stream,
                       Ui, Uf, Uc, Uo, Vi, Vf, Vc, Vo, UT, VT);
    hipLaunchKernelGGL(k_gemm, dim3(4096), dim3(256), 0, stream,
                       xbf, UT, bi, bfp, bc, bo, gates);
    hipLaunchKernelGGL(k_scan, dim3(NWG), dim3(256), 0, stream,
                       gates, VT, hbufF, (float*)d_out);
}

// Round 10
// 2098.646 us; speedup vs baseline: 4.5140x; 1.0755x over previous
//
#include <hip/hip_runtime.h>

typedef unsigned short ushort_t;
typedef unsigned long long u64;
typedef __attribute__((ext_vector_type(8))) short short8;
typedef __attribute__((ext_vector_type(4))) float f32x4;
typedef __attribute__((ext_vector_type(4))) int i32x4;

#define SEQ 512
#define HID 1024
#define GCOLS 4096           // 4*HID
#define HSEQ_ELEMS 16777216  // SEQ*BATCH*HID
#define NWG 128              // 64 col-groups x 2 batch-halves

__device__ __forceinline__ ushort_t f2bf(float f) {
    unsigned u = __float_as_uint(f);
    unsigned r = (u + 0x7FFFu + ((u >> 16) & 1u)) >> 16;
    return (ushort_t)r;
}
__device__ __forceinline__ float bf2f(ushort_t u) {
    return __uint_as_float(((unsigned)u) << 16);
}
__device__ __forceinline__ float sigmoidf_(float x) { return 1.f / (1.f + __expf(-x)); }
__device__ __forceinline__ float tanhs_(float x) {
    float ax = fabsf(x);
    float e  = __expf(-2.f * ax);
    float t  = (1.f - e) / (1.f + e);
    return copysignf(t, x);
}
// pack two f32 -> two bf16 in one dword (dst.lo = src0, dst.hi = src1)
__device__ __forceinline__ unsigned cvtpk(float lo, float hi) {
    unsigned r;
    asm volatile("v_cvt_pk_bf16_f32 %0, %1, %2" : "=v"(r) : "v"(lo), "v"(hi));
    return r;
}

// 16B coherent (device-scope) load/store at the L3 coherence point.
__device__ __forceinline__ void ld_h16f(i32x4* dst, const float* p) {
    asm volatile("global_load_dwordx4 %0, %1, off sc0 sc1"
                 : "=&v"(*dst) : "v"(p) : "memory");
}
__device__ __forceinline__ void st_h16f(float* p, i32x4 v) {
    asm volatile("global_store_dwordx4 %0, %1, off sc0 sc1"
                 :: "v"(p), "v"(v) : "memory");
}

// async global->LDS, 16B per lane (dest = wave-uniform base + lane*16)
__device__ __forceinline__ void gload_lds16(const ushort_t* g, ushort_t* l) {
    __builtin_amdgcn_global_load_lds(
        (const __attribute__((address_space(1))) unsigned*)g,
        (__attribute__((address_space(3))) unsigned*)l, 16, 0, 0);
}

// ---------------- convert x (fp32 -> bf16) ----------------
__global__ __launch_bounds__(256) void k_convert_x(const float* __restrict__ x, ushort_t* __restrict__ xbf) {
    size_t i = ((size_t)blockIdx.x * 256 + threadIdx.x) * 8;
    float4 a = *(const float4*)(x + i);
    float4 b = *(const float4*)(x + i + 4);
    short8 v;
    v[0] = (short)f2bf(a.x); v[1] = (short)f2bf(a.y); v[2] = (short)f2bf(a.z); v[3] = (short)f2bf(a.w);
    v[4] = (short)f2bf(b.x); v[5] = (short)f2bf(b.y); v[6] = (short)f2bf(b.z); v[7] = (short)f2bf(b.w);
    *(short8*)(xbf + i) = v;
}

// ---------------- transpose-convert 8 square matrices ----------------
__global__ __launch_bounds__(256) void k_transpose8(
    const float* __restrict__ u0, const float* __restrict__ u1, const float* __restrict__ u2, const float* __restrict__ u3,
    const float* __restrict__ v0, const float* __restrict__ v1, const float* __restrict__ v2, const float* __restrict__ v3,
    ushort_t* __restrict__ UT, ushort_t* __restrict__ VT) {
    __shared__ float tile[32][33];
    int m  = blockIdx.x >> 10;    // matrix 0..7
    int tl = blockIdx.x & 1023;
    int tr = tl >> 5, tc = tl & 31;
    const float* src = (m == 0) ? u0 : (m == 1) ? u1 : (m == 2) ? u2 : (m == 3) ? u3
                      : (m == 4) ? v0 : (m == 5) ? v1 : (m == 6) ? v2 : v3;
    int r = threadIdx.x >> 5, c = threadIdx.x & 31;
    int k0 = tr * 32, n0 = tc * 32;
#pragma unroll
    for (int i = 0; i < 4; ++i)
        tile[r + 8 * i][c] = src[(size_t)(k0 + r + 8 * i) * HID + n0 + c];
    __syncthreads();
    ushort_t* dst = (m < 4) ? (UT + (size_t)m * HID * HID) : (VT + (size_t)(m - 4) * HID * HID);
#pragma unroll
    for (int i = 0; i < 4; ++i) {
        int row = r + 8 * i;
        dst[(size_t)(n0 + row) * HID + k0 + c] = f2bf(tile[c][row]);
    }
}

// ---------------- phase-1 GEMM: gates_pre = x_bf @ U + bias ----------------
// m97 structure: global_load_lds width=16 staging, 128x128 tile, BK=64, 2-barrier loop.
__global__ __launch_bounds__(256) void k_gemm(
    const ushort_t* __restrict__ A, const ushort_t* __restrict__ Bt,
    const float* __restrict__ pbi, const float* __restrict__ pbf,
    const float* __restrict__ pbc, const float* __restrict__ pbo,
    ushort_t* __restrict__ gates) {
    __shared__ ushort_t As[128 * 64];
    __shared__ ushort_t Bs[128 * 64];
    const int tid = threadIdx.x, lane = tid & 63, wv = tid >> 6;
    const int bm = blockIdx.x & 127, bn = blockIdx.x >> 7;
    const size_t m0 = (size_t)bm * 128;
    const size_t n0 = (size_t)bn * 128;
    const int wm = wv >> 1, wn = wv & 1;
    f32x4 acc[4][4] = {};
    const int rsub = lane >> 3;        // 0..7 row within 8-row chunk
    const int koff = (lane & 7) * 8;   // k element offset

    for (int kt = 0; kt < 16; ++kt) {
        int k0 = kt * 64;
#pragma unroll
        for (int j = 0; j < 4; ++j) {
            int row = wv * 32 + j * 8 + rsub;
            gload_lds16(A  + (m0 + row) * 1024 + k0 + koff, &As[wv * 2048 + j * 512]);
            gload_lds16(Bt + (n0 + row) * 1024 + k0 + koff, &Bs[wv * 2048 + j * 512]);
        }
        __syncthreads();   // compiler drains vmcnt before s_barrier
#pragma unroll
        for (int kk = 0; kk < 64; kk += 32) {
            short8 af[4], bfr[4];
            int ko = kk + (lane >> 4) * 8;
#pragma unroll
            for (int mi = 0; mi < 4; ++mi) af[mi] = *(const short8*)(&As[(wm * 64 + mi * 16 + (lane & 15)) * 64 + ko]);
#pragma unroll
            for (int ni = 0; ni < 4; ++ni) bfr[ni] = *(const short8*)(&Bs[(wn * 64 + ni * 16 + (lane & 15)) * 64 + ko]);
#pragma unroll
            for (int mi = 0; mi < 4; ++mi)
#pragma unroll
                for (int ni = 0; ni < 4; ++ni)
                    acc[mi][ni] = __builtin_amdgcn_mfma_f32_16x16x32_bf16(af[mi], bfr[ni], acc[mi][ni], 0, 0, 0);
        }
        __syncthreads();
    }
    const int g = (int)(n0 >> 10);
    const float* bias = (g == 0) ? pbi : (g == 1) ? pbf : (g == 2) ? pbc : pbo;
#pragma unroll
    for (int ni = 0; ni < 4; ++ni) {
        int col = (int)n0 + wn * 64 + ni * 16 + (lane & 15);
        float bv = bias[col & 1023];
#pragma unroll
        for (int mi = 0; mi < 4; ++mi) {
            int row0 = (int)m0 + wm * 64 + mi * 16 + ((lane >> 4) << 2);
#pragma unroll
            for (int r = 0; r < 4; ++r)
                __builtin_nontemporal_store(f2bf(acc[mi][ni][r] + bv),
                                            &gates[(size_t)(row0 + r) * GCOLS + col]);
        }
    }
}

// ---------------- persistent scan: 128 WGs (64 colgroups x 2 batch-halves) x 256 thr ----
// BARRIER-FREE dataflow (R8 skeleton): h published as f32 with a 2-bit step tag in the
// low mantissa bits of every dword; consumers poll the data itself and retry stale
// blocks. ONE change vs R8: the gates prefetch is issued AFTER h-detection (plain
// nontemporal loads, compiler-managed waitcnt at the use ~1us later) so the poll's
// vmcnt(0) no longer drains an HBM load on the critical path.
__global__ __launch_bounds__(256, 1) void k_scan(
    const ushort_t* __restrict__ gates, const ushort_t* __restrict__ VT,
    float* hbuf, float* __restrict__ out) {
    __shared__ float red[4 * 1024];                            // 16KB
    __shared__ float hshF[256] __attribute__((aligned(16)));   // 1KB pack buffer (f32)
    const int tid = threadIdx.x, w = blockIdx.x;
    const int lane = tid & 63, wv = tid >> 6;
    const int q = lane >> 4;          // k-sub selector
    const int arow = lane & 15;       // batch row within half / V row within n-tile
    const int cg = w >> 1;            // col-group 0..63 (16 hidden cols)
    const int bh = w & 1;             // batch half

    // ---- V fragments: 4 gates x 8 k-steps, pinned in 128 VGPRs ----
    short8 bv[4][8];
#pragma unroll
    for (int g = 0; g < 4; ++g) {
        const ushort_t* vrow = VT + ((size_t)(g * 1024 + cg * 16 + arow)) * 1024 + wv * 256 + q * 8;
#pragma unroll
        for (int ks = 0; ks < 8; ++ks)
            bv[g][ks] = *(const short8*)(vrow + ks * 32);
    }

    const int bl = tid >> 4, hcl = tid & 15;          // thread's (batch_local, col_local)
    const int batch_g = bh * 16 + bl;
    const int col_g = cg * 16 + hcl;

    // prefetch gates t=0 (nontemporal)
    float cur[4];
    {
        size_t r0 = (size_t)batch_g * GCOLS + col_g;
#pragma unroll
        for (int g = 0; g < 4; ++g) cur[g] = bf2f(__builtin_nontemporal_load(&gates[r0 + g * 1024]));
    }

    float c_reg = 0.f;
    for (int t = 0; t < SEQ; ++t) {
        // re-pin V each iteration: forces residency (compiler may not sink loads into loop)
#pragma unroll
        for (int g = 0; g < 4; ++g)
#pragma unroll
            for (int ks = 0; ks < 8; ++ks)
                asm volatile("" : "+v"(*(i32x4*)&bv[g][ks]));

        const float* hc = hbuf + (t & 1) * 32768;

        f32x4 acc[4] = {};
        i32x4 hb[16];
        if (t > 0) {
            // ---- poll-load h: 16 x 16B blocks, validate 2-bit tag per dword, retry stale ----
            const unsigned p = (unsigned)(t & 3);
            const float* hbase = hc + ((wv * 64 + q * 2) * 32 + bh * 16 + arow) * 4;
            unsigned stale = 0xFFFFu;
            for (;;) {
#pragma unroll
                for (int bx = 0; bx < 16; ++bx)
                    if (stale & (1u << bx))
                        ld_h16f(&hb[bx], hbase + (bx >> 1) * 1024 + (bx & 1) * 128);
                asm volatile("s_waitcnt vmcnt(0)" ::: "memory");
                unsigned ns = 0;
#pragma unroll
                for (int bx = 0; bx < 16; ++bx)
                    if (stale & (1u << bx)) {
                        unsigned m = ((((unsigned)hb[bx][0]) ^ p) | (((unsigned)hb[bx][1]) ^ p) |
                                      (((unsigned)hb[bx][2]) ^ p) | (((unsigned)hb[bx][3]) ^ p)) & 3u;
                        if (m) ns |= 1u << bx;
                    }
                stale = ns;
                if (__all(stale == 0)) break;
            }
            __builtin_amdgcn_sched_barrier(0);
        }

        // ---- prefetch gates for t+1: AFTER detection (cannot hoist above the
        //      "memory"-clobbered poll asm); plain NT loads, waitcnt lands at use ----
        ushort_t pf[4];
        {
            int tn = (t + 1 < SEQ) ? t + 1 : 0;
            size_t r0 = (size_t)(tn * 32 + batch_g) * GCOLS + col_g;
#pragma unroll
            for (int g = 0; g < 4; ++g) pf[g] = __builtin_nontemporal_load(&gates[r0 + g * 1024]);
        }

        if (t > 0) {
            // ---- convert f32->bf16 (cvt_pk) and MFMA: 8 k-steps x 4 gate-tiles ----
#pragma unroll
            for (int ks = 0; ks < 8; ++ks) {
                const float* fA = (const float*)&hb[2 * ks];
                const float* fB = (const float*)&hb[2 * ks + 1];
                union { unsigned d[4]; short8 s; } A;
                A.d[0] = cvtpk(fA[0], fA[1]);
                A.d[1] = cvtpk(fA[2], fA[3]);
                A.d[2] = cvtpk(fB[0], fB[1]);
                A.d[3] = cvtpk(fB[2], fB[3]);
                acc[0] = __builtin_amdgcn_mfma_f32_16x16x32_bf16(A.s, bv[0][ks], acc[0], 0, 0, 0);
                acc[1] = __builtin_amdgcn_mfma_f32_16x16x32_bf16(A.s, bv[1][ks], acc[1], 0, 0, 0);
                acc[2] = __builtin_amdgcn_mfma_f32_16x16x32_bf16(A.s, bv[2][ks], acc[2], 0, 0, 0);
                acc[3] = __builtin_amdgcn_mfma_f32_16x16x32_bf16(A.s, bv[3][ks], acc[3], 0, 0, 0);
            }
        }

        // ---- red stores, rotated cols (2-way aliasing = free) ----
        {
            float* rp = red + wv * 1024;
#pragma unroll
            for (int g = 0; g < 4; ++g)
#pragma unroll
                for (int r = 0; r < 4; ++r) {
                    int bb = q * 4 + r;
                    int colrot = (g * 16 + arow + 16 * q) & 63;
                    rp[bb * 64 + colrot] = acc[g][r];
                }
        }
        __syncthreads();

        // ---- gather own 4 gate sums (fused cross-wave reduce) + elementwise ----
        float h;
        {
            float s[4];
            int rotbase = 16 * (bl >> 2);
#pragma unroll
            for (int g = 0; g < 4; ++g) {
                int o = bl * 64 + ((g * 16 + hcl + rotbase) & 63);
                s[g] = red[o] + red[1024 + o] + red[2048 + o] + red[3072 + o] + cur[g];
            }
            c_reg = sigmoidf_(s[1]) * c_reg + sigmoidf_(s[0]) * tanhs_(s[2]);
            h = sigmoidf_(s[3]) * tanhs_(c_reg);
            __builtin_nontemporal_store(h, &out[(size_t)t * 32768 + batch_g * 1024 + col_g]);
            if (t == SEQ - 1) {
                out[HSEQ_ELEMS + batch_g * 1024 + col_g] = h;
                out[HSEQ_ELEMS + 32768 + batch_g * 1024 + col_g] = c_reg;
                break;
            }
        }
        // tag h with (t+1)&3 in the low 2 mantissa bits, pack into LDS
        {
            unsigned hv = (__float_as_uint(h) & ~3u) | (unsigned)((t + 1) & 3);
            hshF[(hcl >> 2) * 64 + bl * 4 + (hcl & 3)] = __uint_as_float(hv);
        }
#pragma unroll
        for (int g = 0; g < 4; ++g) cur[g] = bf2f(pf[g]);

        __syncthreads();  // hshF ready; also orders red gather vs next red stores
        // ---- publish: wave0, 64 x 16B coherent stores, NO drain, NO flag ----
        if (wv == 0) {
            float* hn = hbuf + ((t & 1) ^ 1) * 32768;
            int kbl = lane >> 4, b2 = lane & 15;
            i32x4 v = *(const i32x4*)&hshF[kbl * 64 + b2 * 4];
            st_h16f(hn + ((cg * 4 + kbl) * 32 + bh * 16 + b2) * 4, v);
        }
    }
}

extern "C" void kernel_launch(void* const* d_in, const int* in_sizes, int n_in,
                              void* d_out, int out_size, void* d_ws, size_t ws_size,
                              hipStream_t stream) {
    const float* x  = (const float*)d_in[0];
    const float* Ui = (const float*)d_in[1];
    const float* Vi = (const float*)d_in[2];
    const float* bi = (const float*)d_in[3];
    const float* Uf = (const float*)d_in[4];
    const float* Vf = (const float*)d_in[5];
    const float* bfp= (const float*)d_in[6];
    const float* Uc = (const float*)d_in[7];
    const float* Vc = (const float*)d_in[8];
    const float* bc = (const float*)d_in[9];
    const float* Uo = (const float*)d_in[10];
    const float* Vo = (const float*)d_in[11];
    const float* bo = (const float*)d_in[12];

    char* ws = (char*)d_ws;
    float* hbufF    = (float*)(ws + 4096);                    // 262144 B (2 x [256][32][4] f32)
    ushort_t* xbf   = (ushort_t*)(ws + 266240);               // 33554432 B
    ushort_t* UT    = (ushort_t*)(ws + 33820672);             // 8388608 B
    ushort_t* VT    = (ushort_t*)(ws + 42209280);             // 8388608 B
    ushort_t* gates = (ushort_t*)(ws + 50597888);             // 134217728 B

    // poison h buffers with INVALID tags for their parity:
    // buf0 (even steps, tags {0,2}): 0x01 -> tag 1.  buf1 (odd, {1,3}): 0x02 -> tag 2.
    hipMemsetAsync(ws + 4096, 0x01, 131072, stream);
    hipMemsetAsync(ws + 4096 + 131072, 0x02, 131072, stream);
    hipLaunchKernelGGL(k_convert_x, dim3(8192), dim3(256), 0, stream, x, xbf);
    hipLaunchKernelGGL(k_transpose8, dim3(8192), dim3(256), 0, stream,
                       Ui, Uf, Uc, Uo, Vi, Vf, Vc, Vo, UT, VT);
    hipLaunchKernelGGL(k_gemm, dim3(4096), dim3(256), 0, stream,
                       xbf, UT, bi, bfp, bc, bo, gates);
    hipLaunchKernelGGL(k_scan, dim3(NWG), dim3(256), 0, stream,
                       gates, VT, hbufF, (float*)d_out);
}

// Round 11
// 2069.354 us; speedup vs baseline: 4.5779x; 1.0142x over previous
//
#include <hip/hip_runtime.h>

typedef unsigned short ushort_t;
typedef unsigned long long u64;
typedef __attribute__((ext_vector_type(8))) short short8;
typedef __attribute__((ext_vector_type(4))) float f32x4;
typedef __attribute__((ext_vector_type(4))) int i32x4;

#define SEQ 512
#define HID 1024
#define GCOLS 4096           // 4*HID
#define HSEQ_ELEMS 16777216  // SEQ*BATCH*HID
#define NWG 128              // 64 col-groups x 2 batch-halves

__device__ __forceinline__ ushort_t f2bf(float f) {
    unsigned u = __float_as_uint(f);
    unsigned r = (u + 0x7FFFu + ((u >> 16) & 1u)) >> 16;
    return (ushort_t)r;
}
__device__ __forceinline__ float bf2f(ushort_t u) {
    return __uint_as_float(((unsigned)u) << 16);
}
__device__ __forceinline__ float sigmoidf_(float x) { return 1.f / (1.f + __expf(-x)); }
__device__ __forceinline__ float tanhs_(float x) {
    float ax = fabsf(x);
    float e  = __expf(-2.f * ax);
    float t  = (1.f - e) / (1.f + e);
    return copysignf(t, x);
}
// pack two f32 -> two bf16 in one dword (dst.lo = src0, dst.hi = src1)
__device__ __forceinline__ unsigned cvtpk(float lo, float hi) {
    unsigned r;
    asm volatile("v_cvt_pk_bf16_f32 %0, %1, %2" : "=v"(r) : "v"(lo), "v"(hi));
    return r;
}

// 16B coherent (device-scope) load at the L3 coherence point.
__device__ __forceinline__ void ld_h16f(i32x4* dst, const float* p) {
    asm volatile("global_load_dwordx4 %0, %1, off sc0 sc1"
                 : "=&v"(*dst) : "v"(p) : "memory");
}
// 4B coherent tagged publish store
__device__ __forceinline__ void st_h4f(float* p, unsigned v) {
    asm volatile("global_store_dword %0, %1, off sc0 sc1"
                 :: "v"(p), "v"(v) : "memory");
}

// async global->LDS, 16B per lane (dest = wave-uniform base + lane*16)
__device__ __forceinline__ void gload_lds16(const ushort_t* g, ushort_t* l) {
    __builtin_amdgcn_global_load_lds(
        (const __attribute__((address_space(1))) unsigned*)g,
        (__attribute__((address_space(3))) unsigned*)l, 16, 0, 0);
}

// ---------------- convert x (fp32 -> bf16) ----------------
__global__ __launch_bounds__(256) void k_convert_x(const float* __restrict__ x, ushort_t* __restrict__ xbf) {
    size_t i = ((size_t)blockIdx.x * 256 + threadIdx.x) * 8;
    float4 a = *(const float4*)(x + i);
    float4 b = *(const float4*)(x + i + 4);
    short8 v;
    v[0] = (short)f2bf(a.x); v[1] = (short)f2bf(a.y); v[2] = (short)f2bf(a.z); v[3] = (short)f2bf(a.w);
    v[4] = (short)f2bf(b.x); v[5] = (short)f2bf(b.y); v[6] = (short)f2bf(b.z); v[7] = (short)f2bf(b.w);
    *(short8*)(xbf + i) = v;
}

// ---------------- transpose-convert 8 square matrices ----------------
__global__ __launch_bounds__(256) void k_transpose8(
    const float* __restrict__ u0, const float* __restrict__ u1, const float* __restrict__ u2, const float* __restrict__ u3,
    const float* __restrict__ v0, const float* __restrict__ v1, const float* __restrict__ v2, const float* __restrict__ v3,
    ushort_t* __restrict__ UT, ushort_t* __restrict__ VT) {
    __shared__ float tile[32][33];
    int m  = blockIdx.x >> 10;    // matrix 0..7
    int tl = blockIdx.x & 1023;
    int tr = tl >> 5, tc = tl & 31;
    const float* src = (m == 0) ? u0 : (m == 1) ? u1 : (m == 2) ? u2 : (m == 3) ? u3
                      : (m == 4) ? v0 : (m == 5) ? v1 : (m == 6) ? v2 : v3;
    int r = threadIdx.x >> 5, c = threadIdx.x & 31;
    int k0 = tr * 32, n0 = tc * 32;
#pragma unroll
    for (int i = 0; i < 4; ++i)
        tile[r + 8 * i][c] = src[(size_t)(k0 + r + 8 * i) * HID + n0 + c];
    __syncthreads();
    ushort_t* dst = (m < 4) ? (UT + (size_t)m * HID * HID) : (VT + (size_t)(m - 4) * HID * HID);
#pragma unroll
    for (int i = 0; i < 4; ++i) {
        int row = r + 8 * i;
        dst[(size_t)(n0 + row) * HID + k0 + c] = f2bf(tile[c][row]);
    }
}

// ---------------- phase-1 GEMM: gates_pre = x_bf @ U + bias ----------------
// m97 structure: global_load_lds width=16 staging, 128x128 tile, BK=64, 2-barrier loop.
__global__ __launch_bounds__(256) void k_gemm(
    const ushort_t* __restrict__ A, const ushort_t* __restrict__ Bt,
    const float* __restrict__ pbi, const float* __restrict__ pbf,
    const float* __restrict__ pbc, const float* __restrict__ pbo,
    ushort_t* __restrict__ gates) {
    __shared__ ushort_t As[128 * 64];
    __shared__ ushort_t Bs[128 * 64];
    const int tid = threadIdx.x, lane = tid & 63, wv = tid >> 6;
    const int bm = blockIdx.x & 127, bn = blockIdx.x >> 7;
    const size_t m0 = (size_t)bm * 128;
    const size_t n0 = (size_t)bn * 128;
    const int wm = wv >> 1, wn = wv & 1;
    f32x4 acc[4][4] = {};
    const int rsub = lane >> 3;        // 0..7 row within 8-row chunk
    const int koff = (lane & 7) * 8;   // k element offset

    for (int kt = 0; kt < 16; ++kt) {
        int k0 = kt * 64;
#pragma unroll
        for (int j = 0; j < 4; ++j) {
            int row = wv * 32 + j * 8 + rsub;
            gload_lds16(A  + (m0 + row) * 1024 + k0 + koff, &As[wv * 2048 + j * 512]);
            gload_lds16(Bt + (n0 + row) * 1024 + k0 + koff, &Bs[wv * 2048 + j * 512]);
        }
        __syncthreads();   // compiler drains vmcnt before s_barrier
#pragma unroll
        for (int kk = 0; kk < 64; kk += 32) {
            short8 af[4], bfr[4];
            int ko = kk + (lane >> 4) * 8;
#pragma unroll
            for (int mi = 0; mi < 4; ++mi) af[mi] = *(const short8*)(&As[(wm * 64 + mi * 16 + (lane & 15)) * 64 + ko]);
#pragma unroll
            for (int ni = 0; ni < 4; ++ni) bfr[ni] = *(const short8*)(&Bs[(wn * 64 + ni * 16 + (lane & 15)) * 64 + ko]);
#pragma unroll
            for (int mi = 0; mi < 4; ++mi)
#pragma unroll
                for (int ni = 0; ni < 4; ++ni)
                    acc[mi][ni] = __builtin_amdgcn_mfma_f32_16x16x32_bf16(af[mi], bfr[ni], acc[mi][ni], 0, 0, 0);
        }
        __syncthreads();
    }
    const int g = (int)(n0 >> 10);
    const float* bias = (g == 0) ? pbi : (g == 1) ? pbf : (g == 2) ? pbc : pbo;
#pragma unroll
    for (int ni = 0; ni < 4; ++ni) {
        int col = (int)n0 + wn * 64 + ni * 16 + (lane & 15);
        float bv = bias[col & 1023];
#pragma unroll
        for (int mi = 0; mi < 4; ++mi) {
            int row0 = (int)m0 + wm * 64 + mi * 16 + ((lane >> 4) << 2);
#pragma unroll
            for (int r = 0; r < 4; ++r)
                __builtin_nontemporal_store(f2bf(acc[mi][ni][r] + bv),
                                            &gates[(size_t)(row0 + r) * GCOLS + col]);
        }
    }
}

// ---------------- persistent scan: 128 WGs (64 colgroups x 2 batch-halves) x 256 thr ----
// BARRIER-FREE dataflow: h published as f32 with a 2-bit step tag in the low mantissa
// bits of every dword; consumers poll the data itself and retry stale blocks.
// ONE change vs R10: per-thread 4B tagged publish right after elementwise (deletes the
// hshF LDS pack and the 2nd __syncthreads); red[] double-buffered so the single
// remaining sync per step is sufficient (buffer alternation separates WAR reuse).
__global__ __launch_bounds__(256, 1) void k_scan(
    const ushort_t* __restrict__ gates, const ushort_t* __restrict__ VT,
    float* hbuf, float* __restrict__ out) {
    __shared__ float red[2][4 * 1024];                         // 2 x 16KB
    const int tid = threadIdx.x, w = blockIdx.x;
    const int lane = tid & 63, wv = tid >> 6;
    const int q = lane >> 4;          // k-sub selector
    const int arow = lane & 15;       // batch row within half / V row within n-tile
    const int cg = w >> 1;            // col-group 0..63 (16 hidden cols)
    const int bh = w & 1;             // batch half

    // ---- V fragments: 4 gates x 8 k-steps, pinned in 128 VGPRs ----
    short8 bv[4][8];
#pragma unroll
    for (int g = 0; g < 4; ++g) {
        const ushort_t* vrow = VT + ((size_t)(g * 1024 + cg * 16 + arow)) * 1024 + wv * 256 + q * 8;
#pragma unroll
        for (int ks = 0; ks < 8; ++ks)
            bv[g][ks] = *(const short8*)(vrow + ks * 32);
    }

    const int bl = tid >> 4, hcl = tid & 15;          // thread's (batch_local, col_local)
    const int batch_g = bh * 16 + bl;
    const int col_g = cg * 16 + hcl;
    // this thread's publish slot in the blocked layout [kchunk(256)][batch(32)][4 f32]
    const int pub_idx = (((cg * 4 + (hcl >> 2)) * 32 + batch_g) << 2) + (hcl & 3);

    // prefetch gates t=0 (nontemporal)
    float cur[4];
    {
        size_t r0 = (size_t)batch_g * GCOLS + col_g;
#pragma unroll
        for (int g = 0; g < 4; ++g) cur[g] = bf2f(__builtin_nontemporal_load(&gates[r0 + g * 1024]));
    }

    float c_reg = 0.f;
    for (int t = 0; t < SEQ; ++t) {
        // re-pin V each iteration: forces residency (compiler may not sink loads into loop)
#pragma unroll
        for (int g = 0; g < 4; ++g)
#pragma unroll
            for (int ks = 0; ks < 8; ++ks)
                asm volatile("" : "+v"(*(i32x4*)&bv[g][ks]));

        const float* hc = hbuf + (t & 1) * 32768;

        f32x4 acc[4] = {};
        i32x4 hb[16];
        if (t > 0) {
            // ---- poll-load h: 16 x 16B blocks, validate 2-bit tag per dword, retry stale ----
            const unsigned p = (unsigned)(t & 3);
            const float* hbase = hc + ((wv * 64 + q * 2) * 32 + bh * 16 + arow) * 4;
            unsigned stale = 0xFFFFu;
            for (;;) {
#pragma unroll
                for (int bx = 0; bx < 16; ++bx)
                    if (stale & (1u << bx))
                        ld_h16f(&hb[bx], hbase + (bx >> 1) * 1024 + (bx & 1) * 128);
                asm volatile("s_waitcnt vmcnt(0)" ::: "memory");
                unsigned ns = 0;
#pragma unroll
                for (int bx = 0; bx < 16; ++bx)
                    if (stale & (1u << bx)) {
                        unsigned m = ((((unsigned)hb[bx][0]) ^ p) | (((unsigned)hb[bx][1]) ^ p) |
                                      (((unsigned)hb[bx][2]) ^ p) | (((unsigned)hb[bx][3]) ^ p)) & 3u;
                        if (m) ns |= 1u << bx;
                    }
                stale = ns;
                if (__all(stale == 0)) break;
            }
            __builtin_amdgcn_sched_barrier(0);
        }

        // ---- prefetch gates for t+1: AFTER detection (cannot hoist above the
        //      "memory"-clobbered poll asm); plain NT loads, waitcnt lands at use ----
        ushort_t pf[4];
        {
            int tn = (t + 1 < SEQ) ? t + 1 : 0;
            size_t r0 = (size_t)(tn * 32 + batch_g) * GCOLS + col_g;
#pragma unroll
            for (int g = 0; g < 4; ++g) pf[g] = __builtin_nontemporal_load(&gates[r0 + g * 1024]);
        }

        if (t > 0) {
            // ---- convert f32->bf16 (cvt_pk) and MFMA: 8 k-steps x 4 gate-tiles ----
#pragma unroll
            for (int ks = 0; ks < 8; ++ks) {
                const float* fA = (const float*)&hb[2 * ks];
                const float* fB = (const float*)&hb[2 * ks + 1];
                union { unsigned d[4]; short8 s; } A;
                A.d[0] = cvtpk(fA[0], fA[1]);
                A.d[1] = cvtpk(fA[2], fA[3]);
                A.d[2] = cvtpk(fB[0], fB[1]);
                A.d[3] = cvtpk(fB[2], fB[3]);
                acc[0] = __builtin_amdgcn_mfma_f32_16x16x32_bf16(A.s, bv[0][ks], acc[0], 0, 0, 0);
                acc[1] = __builtin_amdgcn_mfma_f32_16x16x32_bf16(A.s, bv[1][ks], acc[1], 0, 0, 0);
                acc[2] = __builtin_amdgcn_mfma_f32_16x16x32_bf16(A.s, bv[2][ks], acc[2], 0, 0, 0);
                acc[3] = __builtin_amdgcn_mfma_f32_16x16x32_bf16(A.s, bv[3][ks], acc[3], 0, 0, 0);
            }
        }

        // ---- red stores into buffer t&1, rotated cols (2-way aliasing = free) ----
        {
            float* rp = &red[t & 1][wv * 1024];
#pragma unroll
            for (int g = 0; g < 4; ++g)
#pragma unroll
                for (int r = 0; r < 4; ++r) {
                    int bb = q * 4 + r;
                    int colrot = (g * 16 + arow + 16 * q) & 63;
                    rp[bb * 64 + colrot] = acc[g][r];
                }
        }
        __syncthreads();   // the ONLY sync per step

        // ---- gather own 4 gate sums (fused cross-wave reduce) + elementwise + publish ----
        {
            const float* rb = &red[t & 1][0];
            float s[4];
            int rotbase = 16 * (bl >> 2);
#pragma unroll
            for (int g = 0; g < 4; ++g) {
                int o = bl * 64 + ((g * 16 + hcl + rotbase) & 63);
                s[g] = rb[o] + rb[1024 + o] + rb[2048 + o] + rb[3072 + o] + cur[g];
            }
            c_reg = sigmoidf_(s[1]) * c_reg + sigmoidf_(s[0]) * tanhs_(s[2]);
            float h = sigmoidf_(s[3]) * tanhs_(c_reg);
            __builtin_nontemporal_store(h, &out[(size_t)t * 32768 + batch_g * 1024 + col_g]);
            if (t == SEQ - 1) {
                out[HSEQ_ELEMS + batch_g * 1024 + col_g] = h;
                out[HSEQ_ELEMS + 32768 + batch_g * 1024 + col_g] = c_reg;
                break;
            }
            // per-thread tagged publish: tag (t+1)&3 in low 2 mantissa bits
            unsigned hv = (__float_as_uint(h) & ~3u) | (unsigned)((t + 1) & 3);
            float* hn = hbuf + (((t & 1) ^ 1) * 32768);
            st_h4f(hn + pub_idx, hv);
        }
#pragma unroll
        for (int g = 0; g < 4; ++g) cur[g] = bf2f(pf[g]);
    }
}

extern "C" void kernel_launch(void* const* d_in, const int* in_sizes, int n_in,
                              void* d_out, int out_size, void* d_ws, size_t ws_size,
                              hipStream_t stream) {
    const float* x  = (const float*)d_in[0];
    const float* Ui = (const float*)d_in[1];
    const float* Vi = (const float*)d_in[2];
    const float* bi = (const float*)d_in[3];
    const float* Uf = (const float*)d_in[4];
    const float* Vf = (const float*)d_in[5];
    const float* bfp= (const float*)d_in[6];
    const float* Uc = (const float*)d_in[7];
    const float* Vc = (const float*)d_in[8];
    const float* bc = (const float*)d_in[9];
    const float* Uo = (const float*)d_in[10];
    const float* Vo = (const float*)d_in[11];
    const float* bo = (const float*)d_in[12];

    char* ws = (char*)d_ws;
    float* hbufF    = (float*)(ws + 4096);                    // 262144 B (2 x [256][32][4] f32)
    ushort_t* xbf   = (ushort_t*)(ws + 266240);               // 33554432 B
    ushort_t* UT    = (ushort_t*)(ws + 33820672);             // 8388608 B
    ushort_t* VT    = (ushort_t*)(ws + 42209280);             // 8388608 B
    ushort_t* gates = (ushort_t*)(ws + 50597888);             // 134217728 B

    // poison h buffers with INVALID tags for their parity:
    // buf0 (even steps, tags {0,2}): 0x01 -> tag 1.  buf1 (odd, {1,3}): 0x02 -> tag 2.
    hipMemsetAsync(ws + 4096, 0x01, 131072, stream);
    hipMemsetAsync(ws + 4096 + 131072, 0x02, 131072, stream);
    hipLaunchKernelGGL(k_convert_x, dim3(8192), dim3(256), 0, stream, x, xbf);
    hipLaunchKernelGGL(k_transpose8, dim3(8192), dim3(256), 0, stream,
                       Ui, Uf, Uc, Uo, Vi, Vf, Vc, Vo, UT, VT);
    hipLaunchKernelGGL(k_gemm, dim3(4096), dim3(256), 0, stream,
                       xbf, UT, bi, bfp, bc, bo, gates);
    hipLaunchKernelGGL(k_scan, dim3(NWG), dim3(256), 0, stream,
                       gates, VT, hbufF, (float*)d_out);
}

// Round 12
// 1793.316 us; speedup vs baseline: 5.2825x; 1.1539x over previous
//
#include <hip/hip_runtime.h>

typedef unsigned short ushort_t;
typedef unsigned long long u64;
typedef __attribute__((ext_vector_type(8))) short short8;
typedef __attribute__((ext_vector_type(4))) float f32x4;
typedef __attribute__((ext_vector_type(4))) int i32x4;

#define SEQ 512
#define HID 1024
#define GCOLS 4096           // 4*HID
#define HSEQ_ELEMS 16777216  // SEQ*BATCH*HID
#define NWG 128              // 64 col-groups x 2 batch-halves

__device__ __forceinline__ ushort_t f2bf(float f) {
    unsigned u = __float_as_uint(f);
    unsigned r = (u + 0x7FFFu + ((u >> 16) & 1u)) >> 16;
    return (ushort_t)r;
}
__device__ __forceinline__ float bf2f(ushort_t u) {
    return __uint_as_float(((unsigned)u) << 16);
}
__device__ __forceinline__ float sigmoidf_(float x) { return 1.f / (1.f + __expf(-x)); }
__device__ __forceinline__ float tanhs_(float x) {
    float ax = fabsf(x);
    float e  = __expf(-2.f * ax);
    float t  = (1.f - e) / (1.f + e);
    return copysignf(t, x);
}

// 16B coherent (device-scope) load at the L3 coherence point.
__device__ __forceinline__ void ld_h16(i32x4* dst, const ushort_t* p) {
    asm volatile("global_load_dwordx4 %0, %1, off sc0 sc1"
                 : "=&v"(*dst) : "v"(p) : "memory");
}
// 2B coherent tagged publish store (byte-enable merge at L3; no tearing across threads)
__device__ __forceinline__ void st_h2(ushort_t* p, unsigned v) {
    asm volatile("global_store_short %0, %1, off sc0 sc1"
                 :: "v"(p), "v"(v) : "memory");
}

// async global->LDS, 16B per lane (dest = wave-uniform base + lane*16)
__device__ __forceinline__ void gload_lds16(const ushort_t* g, ushort_t* l) {
    __builtin_amdgcn_global_load_lds(
        (const __attribute__((address_space(1))) unsigned*)g,
        (__attribute__((address_space(3))) unsigned*)l, 16, 0, 0);
}

// ---------------- convert x (fp32 -> bf16) ----------------
__global__ __launch_bounds__(256) void k_convert_x(const float* __restrict__ x, ushort_t* __restrict__ xbf) {
    size_t i = ((size_t)blockIdx.x * 256 + threadIdx.x) * 8;
    float4 a = *(const float4*)(x + i);
    float4 b = *(const float4*)(x + i + 4);
    short8 v;
    v[0] = (short)f2bf(a.x); v[1] = (short)f2bf(a.y); v[2] = (short)f2bf(a.z); v[3] = (short)f2bf(a.w);
    v[4] = (short)f2bf(b.x); v[5] = (short)f2bf(b.y); v[6] = (short)f2bf(b.z); v[7] = (short)f2bf(b.w);
    *(short8*)(xbf + i) = v;
}

// ---------------- transpose-convert 8 square matrices ----------------
__global__ __launch_bounds__(256) void k_transpose8(
    const float* __restrict__ u0, const float* __restrict__ u1, const float* __restrict__ u2, const float* __restrict__ u3,
    const float* __restrict__ v0, const float* __restrict__ v1, const float* __restrict__ v2, const float* __restrict__ v3,
    ushort_t* __restrict__ UT, ushort_t* __restrict__ VT) {
    __shared__ float tile[32][33];
    int m  = blockIdx.x >> 10;    // matrix 0..7
    int tl = blockIdx.x & 1023;
    int tr = tl >> 5, tc = tl & 31;
    const float* src = (m == 0) ? u0 : (m == 1) ? u1 : (m == 2) ? u2 : (m == 3) ? u3
                      : (m == 4) ? v0 : (m == 5) ? v1 : (m == 6) ? v2 : v3;
    int r = threadIdx.x >> 5, c = threadIdx.x & 31;
    int k0 = tr * 32, n0 = tc * 32;
#pragma unroll
    for (int i = 0; i < 4; ++i)
        tile[r + 8 * i][c] = src[(size_t)(k0 + r + 8 * i) * HID + n0 + c];
    __syncthreads();
    ushort_t* dst = (m < 4) ? (UT + (size_t)m * HID * HID) : (VT + (size_t)(m - 4) * HID * HID);
#pragma unroll
    for (int i = 0; i < 4; ++i) {
        int row = r + 8 * i;
        dst[(size_t)(n0 + row) * HID + k0 + c] = f2bf(tile[c][row]);
    }
}

// ---------------- phase-1 GEMM: gates_pre = x_bf @ U + bias ----------------
// m97 structure: global_load_lds width=16 staging, 128x128 tile, BK=64, 2-barrier loop.
__global__ __launch_bounds__(256) void k_gemm(
    const ushort_t* __restrict__ A, const ushort_t* __restrict__ Bt,
    const float* __restrict__ pbi, const float* __restrict__ pbf,
    const float* __restrict__ pbc, const float* __restrict__ pbo,
    ushort_t* __restrict__ gates) {
    __shared__ ushort_t As[128 * 64];
    __shared__ ushort_t Bs[128 * 64];
    const int tid = threadIdx.x, lane = tid & 63, wv = tid >> 6;
    const int bm = blockIdx.x & 127, bn = blockIdx.x >> 7;
    const size_t m0 = (size_t)bm * 128;
    const size_t n0 = (size_t)bn * 128;
    const int wm = wv >> 1, wn = wv & 1;
    f32x4 acc[4][4] = {};
    const int rsub = lane >> 3;        // 0..7 row within 8-row chunk
    const int koff = (lane & 7) * 8;   // k element offset

    for (int kt = 0; kt < 16; ++kt) {
        int k0 = kt * 64;
#pragma unroll
        for (int j = 0; j < 4; ++j) {
            int row = wv * 32 + j * 8 + rsub;
            gload_lds16(A  + (m0 + row) * 1024 + k0 + koff, &As[wv * 2048 + j * 512]);
            gload_lds16(Bt + (n0 + row) * 1024 + k0 + koff, &Bs[wv * 2048 + j * 512]);
        }
        __syncthreads();   // compiler drains vmcnt before s_barrier
#pragma unroll
        for (int kk = 0; kk < 64; kk += 32) {
            short8 af[4], bfr[4];
            int ko = kk + (lane >> 4) * 8;
#pragma unroll
            for (int mi = 0; mi < 4; ++mi) af[mi] = *(const short8*)(&As[(wm * 64 + mi * 16 + (lane & 15)) * 64 + ko]);
#pragma unroll
            for (int ni = 0; ni < 4; ++ni) bfr[ni] = *(const short8*)(&Bs[(wn * 64 + ni * 16 + (lane & 15)) * 64 + ko]);
#pragma unroll
            for (int mi = 0; mi < 4; ++mi)
#pragma unroll
                for (int ni = 0; ni < 4; ++ni)
                    acc[mi][ni] = __builtin_amdgcn_mfma_f32_16x16x32_bf16(af[mi], bfr[ni], acc[mi][ni], 0, 0, 0);
        }
        __syncthreads();
    }
    const int g = (int)(n0 >> 10);
    const float* bias = (g == 0) ? pbi : (g == 1) ? pbf : (g == 2) ? pbc : pbo;
#pragma unroll
    for (int ni = 0; ni < 4; ++ni) {
        int col = (int)n0 + wn * 64 + ni * 16 + (lane & 15);
        float bv = bias[col & 1023];
#pragma unroll
        for (int mi = 0; mi < 4; ++mi) {
            int row0 = (int)m0 + wm * 64 + mi * 16 + ((lane >> 4) << 2);
#pragma unroll
            for (int r = 0; r < 4; ++r)
                __builtin_nontemporal_store(f2bf(acc[mi][ni][r] + bv),
                                            &gates[(size_t)(row0 + r) * GCOLS + col]);
        }
    }
}

// ---------------- persistent scan: 128 WGs (64 colgroups x 2 batch-halves) x 256 thr ----
// BARRIER-FREE dataflow with TAGGED-BF16 h: each published bf16's LSB carries one bit
// of the 2-bit step tag (even col -> tag bit0, odd col -> tag bit1). A dword is valid
// iff (dword & 0x00010001) == P(t). Byte-granular stores cannot tear. h volume is
// half of the f32 scheme and the loaded dwords ARE the MFMA A-fragments (no cvt).
// h layout per buffer: [kchunk(128)][batch(32)][8 bf16 cols] = 64KB.
__global__ __launch_bounds__(256, 1) void k_scan(
    const ushort_t* __restrict__ gates, const ushort_t* __restrict__ VT,
    ushort_t* hbuf, float* __restrict__ out) {
    __shared__ float red[2][4 * 1024];                         // 2 x 16KB
    const int tid = threadIdx.x, w = blockIdx.x;
    const int lane = tid & 63, wv = tid >> 6;
    const int q = lane >> 4;          // k-sub selector
    const int arow = lane & 15;       // batch row within half / V row within n-tile
    const int cg = w >> 1;            // col-group 0..63 (16 hidden cols)
    const int bh = w & 1;             // batch half

    // ---- V fragments: 4 gates x 8 k-steps, pinned in 128 VGPRs ----
    short8 bv[4][8];
#pragma unroll
    for (int g = 0; g < 4; ++g) {
        const ushort_t* vrow = VT + ((size_t)(g * 1024 + cg * 16 + arow)) * 1024 + wv * 256 + q * 8;
#pragma unroll
        for (int ks = 0; ks < 8; ++ks)
            bv[g][ks] = *(const short8*)(vrow + ks * 32);
    }

    const int bl = tid >> 4, hcl = tid & 15;          // thread's (batch_local, col_local)
    const int batch_g = bh * 16 + bl;
    const int col_g = cg * 16 + hcl;
    // publish slot (ushort index) in blocked layout [kchunk][batch][8 cols]
    const int pub_idx = ((col_g >> 3) * 32 + batch_g) * 8 + (col_g & 7);
    // this thread's tag bit position: even col carries bit0, odd col carries bit1
    const int tag_sel = col_g & 1;

    // prefetch gates t=0 (nontemporal)
    float cur[4];
    {
        size_t r0 = (size_t)batch_g * GCOLS + col_g;
#pragma unroll
        for (int g = 0; g < 4; ++g) cur[g] = bf2f(__builtin_nontemporal_load(&gates[r0 + g * 1024]));
    }

    float c_reg = 0.f;
    for (int t = 0; t < SEQ; ++t) {
        // re-pin V each iteration: forces residency
#pragma unroll
        for (int g = 0; g < 4; ++g)
#pragma unroll
            for (int ks = 0; ks < 8; ++ks)
                asm volatile("" : "+v"(*(i32x4*)&bv[g][ks]));

        const ushort_t* hc = hbuf + (t & 1) * 32768;

        f32x4 acc[4] = {};
        i32x4 hb[8];
        if (t > 0) {
            // ---- poll-load h: 8 x 16B blocks; dword valid iff (d & M) == P ----
            const unsigned P = (unsigned)((t & 1) | (((t >> 1) & 1) << 16));
            const unsigned M = 0x00010001u;
            const ushort_t* hbase = hc + ((wv * 32 + q) * 32 + bh * 16 + arow) * 8;
            unsigned stale = 0xFFu;
            for (;;) {
#pragma unroll
                for (int bx = 0; bx < 8; ++bx)
                    if (stale & (1u << bx))
                        ld_h16(&hb[bx], hbase + bx * 1024);   // kchunk stride 4: 4*32*8 ushorts
                asm volatile("s_waitcnt vmcnt(0)" ::: "memory");
                unsigned ns = 0;
#pragma unroll
                for (int bx = 0; bx < 8; ++bx)
                    if (stale & (1u << bx)) {
                        unsigned m = ((((unsigned)hb[bx][0]) ^ P) | (((unsigned)hb[bx][1]) ^ P) |
                                      (((unsigned)hb[bx][2]) ^ P) | (((unsigned)hb[bx][3]) ^ P)) & M;
                        if (m) ns |= 1u << bx;
                    }
                stale = ns;
                if (__all(stale == 0)) break;
            }
            __builtin_amdgcn_sched_barrier(0);
        }

        // ---- prefetch gates for t+1: AFTER detection; waitcnt lands at use next step ----
        ushort_t pf[4];
        {
            int tn = (t + 1 < SEQ) ? t + 1 : 0;
            size_t r0 = (size_t)(tn * 32 + batch_g) * GCOLS + col_g;
#pragma unroll
            for (int g = 0; g < 4; ++g) pf[g] = __builtin_nontemporal_load(&gates[r0 + g * 1024]);
        }

        if (t > 0) {
            // ---- MFMA: loaded dwords are the A-fragments directly (bf16, tag noise ~1ulp) ----
#pragma unroll
            for (int ks = 0; ks < 8; ++ks) {
                short8 A = __builtin_bit_cast(short8, hb[ks]);
                acc[0] = __builtin_amdgcn_mfma_f32_16x16x32_bf16(A, bv[0][ks], acc[0], 0, 0, 0);
                acc[1] = __builtin_amdgcn_mfma_f32_16x16x32_bf16(A, bv[1][ks], acc[1], 0, 0, 0);
                acc[2] = __builtin_amdgcn_mfma_f32_16x16x32_bf16(A, bv[2][ks], acc[2], 0, 0, 0);
                acc[3] = __builtin_amdgcn_mfma_f32_16x16x32_bf16(A, bv[3][ks], acc[3], 0, 0, 0);
            }
        }

        // ---- red stores into buffer t&1, rotated cols (2-way aliasing = free) ----
        {
            float* rp = &red[t & 1][wv * 1024];
#pragma unroll
            for (int g = 0; g < 4; ++g)
#pragma unroll
                for (int r = 0; r < 4; ++r) {
                    int bb = q * 4 + r;
                    int colrot = (g * 16 + arow + 16 * q) & 63;
                    rp[bb * 64 + colrot] = acc[g][r];
                }
        }
        __syncthreads();   // the ONLY sync per step

        // ---- gather own 4 gate sums + elementwise + per-thread tagged publish ----
        {
            const float* rb = &red[t & 1][0];
            float s[4];
            int rotbase = 16 * (bl >> 2);
#pragma unroll
            for (int g = 0; g < 4; ++g) {
                int o = bl * 64 + ((g * 16 + hcl + rotbase) & 63);
                s[g] = rb[o] + rb[1024 + o] + rb[2048 + o] + rb[3072 + o] + cur[g];
            }
            c_reg = sigmoidf_(s[1]) * c_reg + sigmoidf_(s[0]) * tanhs_(s[2]);
            float h = sigmoidf_(s[3]) * tanhs_(c_reg);
            __builtin_nontemporal_store(h, &out[(size_t)t * 32768 + batch_g * 1024 + col_g]);
            if (t == SEQ - 1) {
                out[HSEQ_ELEMS + batch_g * 1024 + col_g] = h;
                out[HSEQ_ELEMS + 32768 + batch_g * 1024 + col_g] = c_reg;
                break;
            }
            // tagged-bf16 publish: LSB = my tag bit of step tag (t+1)&3
            unsigned tg = (unsigned)(t + 1);
            unsigned bit = tag_sel ? ((tg >> 1) & 1u) : (tg & 1u);
            unsigned hv = ((unsigned)f2bf(h) & ~1u) | bit;
            ushort_t* hn = hbuf + (((t & 1) ^ 1) * 32768);
            st_h2(hn + pub_idx, hv);
        }
#pragma unroll
        for (int g = 0; g < 4; ++g) cur[g] = bf2f(pf[g]);
    }
}

extern "C" void kernel_launch(void* const* d_in, const int* in_sizes, int n_in,
                              void* d_out, int out_size, void* d_ws, size_t ws_size,
                              hipStream_t stream) {
    const float* x  = (const float*)d_in[0];
    const float* Ui = (const float*)d_in[1];
    const float* Vi = (const float*)d_in[2];
    const float* bi = (const float*)d_in[3];
    const float* Uf = (const float*)d_in[4];
    const float* Vf = (const float*)d_in[5];
    const float* bfp= (const float*)d_in[6];
    const float* Uc = (const float*)d_in[7];
    const float* Vc = (const float*)d_in[8];
    const float* bc = (const float*)d_in[9];
    const float* Uo = (const float*)d_in[10];
    const float* Vo = (const float*)d_in[11];
    const float* bo = (const float*)d_in[12];

    char* ws = (char*)d_ws;
    ushort_t* hbufB = (ushort_t*)(ws + 4096);                 // 131072 B (2 x blocked 32x1024 bf16)
    ushort_t* xbf   = (ushort_t*)(ws + 266240);               // 33554432 B
    ushort_t* UT    = (ushort_t*)(ws + 33820672);             // 8388608 B
    ushort_t* VT    = (ushort_t*)(ws + 42209280);             // 8388608 B
    ushort_t* gates = (ushort_t*)(ws + 50597888);             // 134217728 B

    // poison: buf0 (even steps, tags {0,2}: bit0=0) -> memset 0x01 sets every bf16 LSB=1 (invalid).
    //         buf1 (odd steps, tags {1,3}: bit0=1) -> memset 0x00 sets LSB=0 (invalid).
    hipMemsetAsync(ws + 4096, 0x01, 65536, stream);
    hipMemsetAsync(ws + 4096 + 65536, 0x00, 65536, stream);
    hipLaunchKernelGGL(k_convert_x, dim3(8192), dim3(256), 0, stream, x, xbf);
    hipLaunchKernelGGL(k_transpose8, dim3(8192), dim3(256), 0, stream,
                       Ui, Uf, Uc, Uo, Vi, Vf, Vc, Vo, UT, VT);
    hipLaunchKernelGGL(k_gemm, dim3(4096), dim3(256), 0, stream,
                       xbf, UT, bi, bfp, bc, bo, gates);
    hipLaunchKernelGGL(k_scan, dim3(NWG), dim3(256), 0, stream,
                       gates, VT, hbufB, (float*)d_out);
}

// Round 13
// 1395.141 us; speedup vs baseline: 6.7902x; 1.2854x over previous
//
#include <hip/hip_runtime.h>

typedef unsigned short ushort_t;
typedef unsigned long long u64;
typedef __attribute__((ext_vector_type(8))) short short8;
typedef __attribute__((ext_vector_type(4))) float f32x4;
typedef __attribute__((ext_vector_type(4))) int i32x4;

#define SEQ 512
#define HID 1024
#define GCOLS 4096           // 4*HID
#define HSEQ_ELEMS 16777216  // SEQ*BATCH*HID
#define NWG 128              // 64 col-groups x 2 batch-halves

__device__ __forceinline__ ushort_t f2bf(float f) {
    unsigned u = __float_as_uint(f);
    unsigned r = (u + 0x7FFFu + ((u >> 16) & 1u)) >> 16;
    return (ushort_t)r;
}
__device__ __forceinline__ float bf2f(ushort_t u) {
    return __uint_as_float(((unsigned)u) << 16);
}
__device__ __forceinline__ float sigmoidf_(float x) { return 1.f / (1.f + __expf(-x)); }
__device__ __forceinline__ float tanhs_(float x) {
    float ax = fabsf(x);
    float e  = __expf(-2.f * ax);
    float t  = (1.f - e) / (1.f + e);
    return copysignf(t, x);
}

// 16B coherent (device-scope) load at the L3 coherence point.
__device__ __forceinline__ void ld_h16(i32x4* dst, const ushort_t* p) {
    asm volatile("global_load_dwordx4 %0, %1, off sc0 sc1"
                 : "=&v"(*dst) : "v"(p) : "memory");
}
// 2B coherent tagged publish store (byte-enable merge at L3; no tearing across threads)
__device__ __forceinline__ void st_h2(ushort_t* p, unsigned v) {
    asm volatile("global_store_short %0, %1, off sc0 sc1"
                 :: "v"(p), "v"(v) : "memory");
}

// async global->LDS, 16B per lane (dest = wave-uniform base + lane*16)
__device__ __forceinline__ void gload_lds16(const ushort_t* g, ushort_t* l) {
    __builtin_amdgcn_global_load_lds(
        (const __attribute__((address_space(1))) unsigned*)g,
        (__attribute__((address_space(3))) unsigned*)l, 16, 0, 0);
}

// ---------------- convert x (fp32 -> bf16) ----------------
__global__ __launch_bounds__(256) void k_convert_x(const float* __restrict__ x, ushort_t* __restrict__ xbf) {
    size_t i = ((size_t)blockIdx.x * 256 + threadIdx.x) * 8;
    float4 a = *(const float4*)(x + i);
    float4 b = *(const float4*)(x + i + 4);
    short8 v;
    v[0] = (short)f2bf(a.x); v[1] = (short)f2bf(a.y); v[2] = (short)f2bf(a.z); v[3] = (short)f2bf(a.w);
    v[4] = (short)f2bf(b.x); v[5] = (short)f2bf(b.y); v[6] = (short)f2bf(b.z); v[7] = (short)f2bf(b.w);
    *(short8*)(xbf + i) = v;
}

// ---------------- transpose-convert 8 square matrices ----------------
__global__ __launch_bounds__(256) void k_transpose8(
    const float* __restrict__ u0, const float* __restrict__ u1, const float* __restrict__ u2, const float* __restrict__ u3,
    const float* __restrict__ v0, const float* __restrict__ v1, const float* __restrict__ v2, const float* __restrict__ v3,
    ushort_t* __restrict__ UT, ushort_t* __restrict__ VT) {
    __shared__ float tile[32][33];
    int m  = blockIdx.x >> 10;    // matrix 0..7
    int tl = blockIdx.x & 1023;
    int tr = tl >> 5, tc = tl & 31;
    const float* src = (m == 0) ? u0 : (m == 1) ? u1 : (m == 2) ? u2 : (m == 3) ? u3
                      : (m == 4) ? v0 : (m == 5) ? v1 : (m == 6) ? v2 : v3;
    int r = threadIdx.x >> 5, c = threadIdx.x & 31;
    int k0 = tr * 32, n0 = tc * 32;
#pragma unroll
    for (int i = 0; i < 4; ++i)
        tile[r + 8 * i][c] = src[(size_t)(k0 + r + 8 * i) * HID + n0 + c];
    __syncthreads();
    ushort_t* dst = (m < 4) ? (UT + (size_t)m * HID * HID) : (VT + (size_t)(m - 4) * HID * HID);
#pragma unroll
    for (int i = 0; i < 4; ++i) {
        int row = r + 8 * i;
        dst[(size_t)(n0 + row) * HID + k0 + c] = f2bf(tile[c][row]);
    }
}

// ---------------- phase-1 GEMM: gates_pre = x_bf @ U + bias ----------------
// m97 structure: global_load_lds width=16 staging, 128x128 tile, BK=64, 2-barrier loop.
// Gates stored with PLAIN stores -> L3-resident for the scan (134MB < 256MB L3).
__global__ __launch_bounds__(256) void k_gemm(
    const ushort_t* __restrict__ A, const ushort_t* __restrict__ Bt,
    const float* __restrict__ pbi, const float* __restrict__ pbf,
    const float* __restrict__ pbc, const float* __restrict__ pbo,
    ushort_t* __restrict__ gates) {
    __shared__ ushort_t As[128 * 64];
    __shared__ ushort_t Bs[128 * 64];
    const int tid = threadIdx.x, lane = tid & 63, wv = tid >> 6;
    const int bm = blockIdx.x & 127, bn = blockIdx.x >> 7;
    const size_t m0 = (size_t)bm * 128;
    const size_t n0 = (size_t)bn * 128;
    const int wm = wv >> 1, wn = wv & 1;
    f32x4 acc[4][4] = {};
    const int rsub = lane >> 3;        // 0..7 row within 8-row chunk
    const int koff = (lane & 7) * 8;   // k element offset

    for (int kt = 0; kt < 16; ++kt) {
        int k0 = kt * 64;
#pragma unroll
        for (int j = 0; j < 4; ++j) {
            int row = wv * 32 + j * 8 + rsub;
            gload_lds16(A  + (m0 + row) * 1024 + k0 + koff, &As[wv * 2048 + j * 512]);
            gload_lds16(Bt + (n0 + row) * 1024 + k0 + koff, &Bs[wv * 2048 + j * 512]);
        }
        __syncthreads();   // compiler drains vmcnt before s_barrier
#pragma unroll
        for (int kk = 0; kk < 64; kk += 32) {
            short8 af[4], bfr[4];
            int ko = kk + (lane >> 4) * 8;
#pragma unroll
            for (int mi = 0; mi < 4; ++mi) af[mi] = *(const short8*)(&As[(wm * 64 + mi * 16 + (lane & 15)) * 64 + ko]);
#pragma unroll
            for (int ni = 0; ni < 4; ++ni) bfr[ni] = *(const short8*)(&Bs[(wn * 64 + ni * 16 + (lane & 15)) * 64 + ko]);
#pragma unroll
            for (int mi = 0; mi < 4; ++mi)
#pragma unroll
                for (int ni = 0; ni < 4; ++ni)
                    acc[mi][ni] = __builtin_amdgcn_mfma_f32_16x16x32_bf16(af[mi], bfr[ni], acc[mi][ni], 0, 0, 0);
        }
        __syncthreads();
    }
    const int g = (int)(n0 >> 10);
    const float* bias = (g == 0) ? pbi : (g == 1) ? pbf : (g == 2) ? pbc : pbo;
#pragma unroll
    for (int ni = 0; ni < 4; ++ni) {
        int col = (int)n0 + wn * 64 + ni * 16 + (lane & 15);
        float bv = bias[col & 1023];
#pragma unroll
        for (int mi = 0; mi < 4; ++mi) {
            int row0 = (int)m0 + wm * 64 + mi * 16 + ((lane >> 4) << 2);
#pragma unroll
            for (int r = 0; r < 4; ++r)
                gates[(size_t)(row0 + r) * GCOLS + col] = f2bf(acc[mi][ni][r] + bv);
        }
    }
}

// ---------------- persistent scan: 128 WGs (64 colgroups x 2 batch-halves) x 256 thr ----
// BARRIER-FREE dataflow with TAGGED-BF16 h (R12). Changes this round:
// (1) sched_barrier(0) after the poll's vmcnt(0): stops the compiler hoisting the tag
//     validation above the waitcnt (rule #18) -> no spurious-stale retry rounds.
// (2) gates read with plain cached loads (L3-resident now) -> rotation stall gone.
__global__ __launch_bounds__(256, 1) void k_scan(
    const ushort_t* __restrict__ gates, const ushort_t* __restrict__ VT,
    ushort_t* hbuf, float* __restrict__ out) {
    __shared__ float red[2][4 * 1024];                         // 2 x 16KB
    const int tid = threadIdx.x, w = blockIdx.x;
    const int lane = tid & 63, wv = tid >> 6;
    const int q = lane >> 4;          // k-sub selector
    const int arow = lane & 15;       // batch row within half / V row within n-tile
    const int cg = w >> 1;            // col-group 0..63 (16 hidden cols)
    const int bh = w & 1;             // batch half

    // ---- V fragments: 4 gates x 8 k-steps, pinned in 128 VGPRs ----
    short8 bv[4][8];
#pragma unroll
    for (int g = 0; g < 4; ++g) {
        const ushort_t* vrow = VT + ((size_t)(g * 1024 + cg * 16 + arow)) * 1024 + wv * 256 + q * 8;
#pragma unroll
        for (int ks = 0; ks < 8; ++ks)
            bv[g][ks] = *(const short8*)(vrow + ks * 32);
    }

    const int bl = tid >> 4, hcl = tid & 15;          // thread's (batch_local, col_local)
    const int batch_g = bh * 16 + bl;
    const int col_g = cg * 16 + hcl;
    // publish slot (ushort index) in blocked layout [kchunk][batch][8 cols]
    const int pub_idx = ((col_g >> 3) * 32 + batch_g) * 8 + (col_g & 7);
    // this thread's tag bit position: even col carries bit0, odd col carries bit1
    const int tag_sel = col_g & 1;

    // prefetch gates t=0 (plain cached loads; gates are L3-resident)
    float cur[4];
    {
        size_t r0 = (size_t)batch_g * GCOLS + col_g;
#pragma unroll
        for (int g = 0; g < 4; ++g) cur[g] = bf2f(gates[r0 + g * 1024]);
    }

    float c_reg = 0.f;
    for (int t = 0; t < SEQ; ++t) {
        // re-pin V each iteration: forces residency
#pragma unroll
        for (int g = 0; g < 4; ++g)
#pragma unroll
            for (int ks = 0; ks < 8; ++ks)
                asm volatile("" : "+v"(*(i32x4*)&bv[g][ks]));

        const ushort_t* hc = hbuf + (t & 1) * 32768;

        f32x4 acc[4] = {};
        i32x4 hb[8];
        if (t > 0) {
            // ---- poll-load h: 8 x 16B blocks; dword valid iff (d & M) == P ----
            const unsigned P = (unsigned)((t & 1) | (((t >> 1) & 1) << 16));
            const unsigned M = 0x00010001u;
            const ushort_t* hbase = hc + ((wv * 32 + q) * 32 + bh * 16 + arow) * 8;
            unsigned stale = 0xFFu;
            for (;;) {
#pragma unroll
                for (int bx = 0; bx < 8; ++bx)
                    if (stale & (1u << bx))
                        ld_h16(&hb[bx], hbase + bx * 1024);   // kchunk stride 4
                asm volatile("s_waitcnt vmcnt(0)" ::: "memory");
                __builtin_amdgcn_sched_barrier(0);   // rule #18: pin validation AFTER waitcnt
                unsigned ns = 0;
#pragma unroll
                for (int bx = 0; bx < 8; ++bx)
                    if (stale & (1u << bx)) {
                        unsigned m = ((((unsigned)hb[bx][0]) ^ P) | (((unsigned)hb[bx][1]) ^ P) |
                                      (((unsigned)hb[bx][2]) ^ P) | (((unsigned)hb[bx][3]) ^ P)) & M;
                        if (m) ns |= 1u << bx;
                    }
                stale = ns;
                if (__all(stale == 0)) break;
            }
            __builtin_amdgcn_sched_barrier(0);
        }

        // ---- prefetch gates for t+1: AFTER detection; L3-resident plain loads ----
        ushort_t pf[4];
        {
            int tn = (t + 1 < SEQ) ? t + 1 : 0;
            size_t r0 = (size_t)(tn * 32 + batch_g) * GCOLS + col_g;
#pragma unroll
            for (int g = 0; g < 4; ++g) pf[g] = gates[r0 + g * 1024];
        }

        if (t > 0) {
            // ---- MFMA: loaded dwords are the A-fragments directly ----
#pragma unroll
            for (int ks = 0; ks < 8; ++ks) {
                short8 A = __builtin_bit_cast(short8, hb[ks]);
                acc[0] = __builtin_amdgcn_mfma_f32_16x16x32_bf16(A, bv[0][ks], acc[0], 0, 0, 0);
                acc[1] = __builtin_amdgcn_mfma_f32_16x16x32_bf16(A, bv[1][ks], acc[1], 0, 0, 0);
                acc[2] = __builtin_amdgcn_mfma_f32_16x16x32_bf16(A, bv[2][ks], acc[2], 0, 0, 0);
                acc[3] = __builtin_amdgcn_mfma_f32_16x16x32_bf16(A, bv[3][ks], acc[3], 0, 0, 0);
            }
        }

        // ---- red stores into buffer t&1, rotated cols (2-way aliasing = free) ----
        {
            float* rp = &red[t & 1][wv * 1024];
#pragma unroll
            for (int g = 0; g < 4; ++g)
#pragma unroll
                for (int r = 0; r < 4; ++r) {
                    int bb = q * 4 + r;
                    int colrot = (g * 16 + arow + 16 * q) & 63;
                    rp[bb * 64 + colrot] = acc[g][r];
                }
        }
        __syncthreads();   // the ONLY sync per step

        // ---- gather own 4 gate sums + elementwise + per-thread tagged publish ----
        {
            const float* rb = &red[t & 1][0];
            float s[4];
            int rotbase = 16 * (bl >> 2);
#pragma unroll
            for (int g = 0; g < 4; ++g) {
                int o = bl * 64 + ((g * 16 + hcl + rotbase) & 63);
                s[g] = rb[o] + rb[1024 + o] + rb[2048 + o] + rb[3072 + o] + cur[g];
            }
            c_reg = sigmoidf_(s[1]) * c_reg + sigmoidf_(s[0]) * tanhs_(s[2]);
            float h = sigmoidf_(s[3]) * tanhs_(c_reg);
            __builtin_nontemporal_store(h, &out[(size_t)t * 32768 + batch_g * 1024 + col_g]);
            if (t == SEQ - 1) {
                out[HSEQ_ELEMS + batch_g * 1024 + col_g] = h;
                out[HSEQ_ELEMS + 32768 + batch_g * 1024 + col_g] = c_reg;
                break;
            }
            // tagged-bf16 publish: LSB = my tag bit of step tag (t+1)&3
            unsigned tg = (unsigned)(t + 1);
            unsigned bit = tag_sel ? ((tg >> 1) & 1u) : (tg & 1u);
            unsigned hv = ((unsigned)f2bf(h) & ~1u) | bit;
            ushort_t* hn = hbuf + (((t & 1) ^ 1) * 32768);
            st_h2(hn + pub_idx, hv);
        }
#pragma unroll
        for (int g = 0; g < 4; ++g) cur[g] = bf2f(pf[g]);
    }
}

extern "C" void kernel_launch(void* const* d_in, const int* in_sizes, int n_in,
                              void* d_out, int out_size, void* d_ws, size_t ws_size,
                              hipStream_t stream) {
    const float* x  = (const float*)d_in[0];
    const float* Ui = (const float*)d_in[1];
    const float* Vi = (const float*)d_in[2];
    const float* bi = (const float*)d_in[3];
    const float* Uf = (const float*)d_in[4];
    const float* Vf = (const float*)d_in[5];
    const float* bfp= (const float*)d_in[6];
    const float* Uc = (const float*)d_in[7];
    const float* Vc = (const float*)d_in[8];
    const float* bc = (const float*)d_in[9];
    const float* Uo = (const float*)d_in[10];
    const float* Vo = (const float*)d_in[11];
    const float* bo = (const float*)d_in[12];

    char* ws = (char*)d_ws;
    ushort_t* hbufB = (ushort_t*)(ws + 4096);                 // 131072 B (2 x blocked 32x1024 bf16)
    ushort_t* xbf   = (ushort_t*)(ws + 266240);               // 33554432 B
    ushort_t* UT    = (ushort_t*)(ws + 33820672);             // 8388608 B
    ushort_t* VT    = (ushort_t*)(ws + 42209280);             // 8388608 B
    ushort_t* gates = (ushort_t*)(ws + 50597888);             // 134217728 B

    // poison: buf0 (even steps, tags {0,2}: bit0=0) -> memset 0x01 sets every bf16 LSB=1 (invalid).
    //         buf1 (odd steps, tags {1,3}: bit0=1) -> memset 0x00 sets LSB=0 (invalid).
    hipMemsetAsync(ws + 4096, 0x01, 65536, stream);
    hipMemsetAsync(ws + 4096 + 65536, 0x00, 65536, stream);
    hipLaunchKernelGGL(k_convert_x, dim3(8192), dim3(256), 0, stream, x, xbf);
    hipLaunchKernelGGL(k_transpose8, dim3(8192), dim3(256), 0, stream,
                       Ui, Uf, Uc, Uo, Vi, Vf, Vc, Vo, UT, VT);
    hipLaunchKernelGGL(k_gemm, dim3(4096), dim3(256), 0, stream,
                       xbf, UT, bi, bfp, bc, bo, gates);
    hipLaunchKernelGGL(k_scan, dim3(NWG), dim3(256), 0, stream,
                       gates, VT, hbufB, (float*)d_out);
}

// Round 14
// 1273.514 us; speedup vs baseline: 7.4387x; 1.0955x over previous
//
#include <hip/hip_runtime.h>

typedef unsigned short ushort_t;
typedef unsigned long long u64;
typedef __attribute__((ext_vector_type(8))) short short8;
typedef __attribute__((ext_vector_type(4))) float f32x4;
typedef __attribute__((ext_vector_type(4))) int i32x4;

#define SEQ 512
#define HID 1024
#define GCOLS 4096           // 4*HID
#define HSEQ_ELEMS 16777216  // SEQ*BATCH*HID
#define NWG 128              // 64 col-groups x 2 batch-halves

__device__ __forceinline__ ushort_t f2bf(float f) {
    unsigned u = __float_as_uint(f);
    unsigned r = (u + 0x7FFFu + ((u >> 16) & 1u)) >> 16;
    return (ushort_t)r;
}
__device__ __forceinline__ float bf2f(ushort_t u) {
    return __uint_as_float(((unsigned)u) << 16);
}
__device__ __forceinline__ float sigmoidf_(float x) { return 1.f / (1.f + __expf(-x)); }
__device__ __forceinline__ float tanhs_(float x) {
    float ax = fabsf(x);
    float e  = __expf(-2.f * ax);
    float t  = (1.f - e) / (1.f + e);
    return copysignf(t, x);
}

// 16B coherent (device-scope) load at the L3 coherence point.
__device__ __forceinline__ void ld_h16(i32x4* dst, const ushort_t* p) {
    asm volatile("global_load_dwordx4 %0, %1, off sc0 sc1"
                 : "=&v"(*dst) : "v"(p) : "memory");
}
// 2B coherent tagged publish store (byte-enable merge at L3; no tearing across threads)
__device__ __forceinline__ void st_h2(ushort_t* p, unsigned v) {
    asm volatile("global_store_short %0, %1, off sc0 sc1"
                 :: "v"(p), "v"(v) : "memory");
}

// async global->LDS, 16B per lane (dest = wave-uniform base + lane*16)
__device__ __forceinline__ void gload_lds16(const ushort_t* g, ushort_t* l) {
    __builtin_amdgcn_global_load_lds(
        (const __attribute__((address_space(1))) unsigned*)g,
        (__attribute__((address_space(3))) unsigned*)l, 16, 0, 0);
}

// ---------------- convert x (fp32 -> bf16) ----------------
__global__ __launch_bounds__(256) void k_convert_x(const float* __restrict__ x, ushort_t* __restrict__ xbf) {
    size_t i = ((size_t)blockIdx.x * 256 + threadIdx.x) * 8;
    float4 a = *(const float4*)(x + i);
    float4 b = *(const float4*)(x + i + 4);
    short8 v;
    v[0] = (short)f2bf(a.x); v[1] = (short)f2bf(a.y); v[2] = (short)f2bf(a.z); v[3] = (short)f2bf(a.w);
    v[4] = (short)f2bf(b.x); v[5] = (short)f2bf(b.y); v[6] = (short)f2bf(b.z); v[7] = (short)f2bf(b.w);
    *(short8*)(xbf + i) = v;
}

// ---------------- transpose-convert 8 square matrices ----------------
__global__ __launch_bounds__(256) void k_transpose8(
    const float* __restrict__ u0, const float* __restrict__ u1, const float* __restrict__ u2, const float* __restrict__ u3,
    const float* __restrict__ v0, const float* __restrict__ v1, const float* __restrict__ v2, const float* __restrict__ v3,
    ushort_t* __restrict__ UT, ushort_t* __restrict__ VT) {
    __shared__ float tile[32][33];
    int m  = blockIdx.x >> 10;    // matrix 0..7
    int tl = blockIdx.x & 1023;
    int tr = tl >> 5, tc = tl & 31;
    const float* src = (m == 0) ? u0 : (m == 1) ? u1 : (m == 2) ? u2 : (m == 3) ? u3
                      : (m == 4) ? v0 : (m == 5) ? v1 : (m == 6) ? v2 : v3;
    int r = threadIdx.x >> 5, c = threadIdx.x & 31;
    int k0 = tr * 32, n0 = tc * 32;
#pragma unroll
    for (int i = 0; i < 4; ++i)
        tile[r + 8 * i][c] = src[(size_t)(k0 + r + 8 * i) * HID + n0 + c];
    __syncthreads();
    ushort_t* dst = (m < 4) ? (UT + (size_t)m * HID * HID) : (VT + (size_t)(m - 4) * HID * HID);
#pragma unroll
    for (int i = 0; i < 4; ++i) {
        int row = r + 8 * i;
        dst[(size_t)(n0 + row) * HID + k0 + c] = f2bf(tile[c][row]);
    }
}

// ---------------- phase-1 GEMM: gates_pre = x_bf @ U + bias ----------------
// m97 structure: global_load_lds width=16 staging, 128x128 tile, BK=64, 2-barrier loop.
// Gates stored with PLAIN stores -> L3-resident for the scan (134MB < 256MB L3).
__global__ __launch_bounds__(256) void k_gemm(
    const ushort_t* __restrict__ A, const ushort_t* __restrict__ Bt,
    const float* __restrict__ pbi, const float* __restrict__ pbf,
    const float* __restrict__ pbc, const float* __restrict__ pbo,
    ushort_t* __restrict__ gates) {
    __shared__ ushort_t As[128 * 64];
    __shared__ ushort_t Bs[128 * 64];
    const int tid = threadIdx.x, lane = tid & 63, wv = tid >> 6;
    const int bm = blockIdx.x & 127, bn = blockIdx.x >> 7;
    const size_t m0 = (size_t)bm * 128;
    const size_t n0 = (size_t)bn * 128;
    const int wm = wv >> 1, wn = wv & 1;
    f32x4 acc[4][4] = {};
    const int rsub = lane >> 3;        // 0..7 row within 8-row chunk
    const int koff = (lane & 7) * 8;   // k element offset

    for (int kt = 0; kt < 16; ++kt) {
        int k0 = kt * 64;
#pragma unroll
        for (int j = 0; j < 4; ++j) {
            int row = wv * 32 + j * 8 + rsub;
            gload_lds16(A  + (m0 + row) * 1024 + k0 + koff, &As[wv * 2048 + j * 512]);
            gload_lds16(Bt + (n0 + row) * 1024 + k0 + koff, &Bs[wv * 2048 + j * 512]);
        }
        __syncthreads();   // compiler drains vmcnt before s_barrier
#pragma unroll
        for (int kk = 0; kk < 64; kk += 32) {
            short8 af[4], bfr[4];
            int ko = kk + (lane >> 4) * 8;
#pragma unroll
            for (int mi = 0; mi < 4; ++mi) af[mi] = *(const short8*)(&As[(wm * 64 + mi * 16 + (lane & 15)) * 64 + ko]);
#pragma unroll
            for (int ni = 0; ni < 4; ++ni) bfr[ni] = *(const short8*)(&Bs[(wn * 64 + ni * 16 + (lane & 15)) * 64 + ko]);
#pragma unroll
            for (int mi = 0; mi < 4; ++mi)
#pragma unroll
                for (int ni = 0; ni < 4; ++ni)
                    acc[mi][ni] = __builtin_amdgcn_mfma_f32_16x16x32_bf16(af[mi], bfr[ni], acc[mi][ni], 0, 0, 0);
        }
        __syncthreads();
    }
    const int g = (int)(n0 >> 10);
    const float* bias = (g == 0) ? pbi : (g == 1) ? pbf : (g == 2) ? pbc : pbo;
#pragma unroll
    for (int ni = 0; ni < 4; ++ni) {
        int col = (int)n0 + wn * 64 + ni * 16 + (lane & 15);
        float bv = bias[col & 1023];
#pragma unroll
        for (int mi = 0; mi < 4; ++mi) {
            int row0 = (int)m0 + wm * 64 + mi * 16 + ((lane >> 4) << 2);
#pragma unroll
            for (int r = 0; r < 4; ++r)
                gates[(size_t)(row0 + r) * GCOLS + col] = f2bf(acc[mi][ni][r] + bv);
        }
    }
}

// ---------------- persistent scan: 128 WGs (64 colgroups x 2 batch-halves) x 256 thr ----
// BARRIER-FREE dataflow with TAGGED-BF16 h (R12/R13). Poll-window hygiene this round:
// (1) gates prefetch issued BEFORE the poll (L3-resident; fully hidden by the poll's
//     own vmcnt round trip) -> nothing left on the post-detect path;
// (2) s_sleep(1) backoff on RETRY rounds only -> less L3 read-storm contention with
//     the straggler's publish stores during the critical window;
// (3) publish store issued before the out NT store.
__global__ __launch_bounds__(256, 1) void k_scan(
    const ushort_t* __restrict__ gates, const ushort_t* __restrict__ VT,
    ushort_t* hbuf, float* __restrict__ out) {
    __shared__ float red[2][4 * 1024];                         // 2 x 16KB
    const int tid = threadIdx.x, w = blockIdx.x;
    const int lane = tid & 63, wv = tid >> 6;
    const int q = lane >> 4;          // k-sub selector
    const int arow = lane & 15;       // batch row within half / V row within n-tile
    const int cg = w >> 1;            // col-group 0..63 (16 hidden cols)
    const int bh = w & 1;             // batch half

    // ---- V fragments: 4 gates x 8 k-steps, pinned in 128 VGPRs ----
    short8 bv[4][8];
#pragma unroll
    for (int g = 0; g < 4; ++g) {
        const ushort_t* vrow = VT + ((size_t)(g * 1024 + cg * 16 + arow)) * 1024 + wv * 256 + q * 8;
#pragma unroll
        for (int ks = 0; ks < 8; ++ks)
            bv[g][ks] = *(const short8*)(vrow + ks * 32);
    }

    const int bl = tid >> 4, hcl = tid & 15;          // thread's (batch_local, col_local)
    const int batch_g = bh * 16 + bl;
    const int col_g = cg * 16 + hcl;
    // publish slot (ushort index) in blocked layout [kchunk][batch][8 cols]
    const int pub_idx = ((col_g >> 3) * 32 + batch_g) * 8 + (col_g & 7);
    // this thread's tag bit position: even col carries bit0, odd col carries bit1
    const int tag_sel = col_g & 1;

    // prefetch gates t=0 (plain cached loads; gates are L3-resident)
    float cur[4];
    {
        size_t r0 = (size_t)batch_g * GCOLS + col_g;
#pragma unroll
        for (int g = 0; g < 4; ++g) cur[g] = bf2f(gates[r0 + g * 1024]);
    }

    float c_reg = 0.f;
    for (int t = 0; t < SEQ; ++t) {
        // re-pin V each iteration: forces residency
#pragma unroll
        for (int g = 0; g < 4; ++g)
#pragma unroll
            for (int ks = 0; ks < 8; ++ks)
                asm volatile("" : "+v"(*(i32x4*)&bv[g][ks]));

        const ushort_t* hc = hbuf + (t & 1) * 32768;

        // ---- prefetch gates for t+1 BEFORE the poll: L3-resident (~300ns), fully
        //      drained by the poll's first vmcnt(0); pinned here by the poll asm's
        //      "memory" clobbers (cannot sink past) ----
        ushort_t pf[4];
        {
            int tn = (t + 1 < SEQ) ? t + 1 : 0;
            size_t r0 = (size_t)(tn * 32 + batch_g) * GCOLS + col_g;
#pragma unroll
            for (int g = 0; g < 4; ++g) pf[g] = gates[r0 + g * 1024];
        }

        f32x4 acc[4] = {};
        i32x4 hb[8];
        if (t > 0) {
            // ---- poll-load h: 8 x 16B blocks; dword valid iff (d & M) == P ----
            const unsigned P = (unsigned)((t & 1) | (((t >> 1) & 1) << 16));
            const unsigned M = 0x00010001u;
            const ushort_t* hbase = hc + ((wv * 32 + q) * 32 + bh * 16 + arow) * 8;
            unsigned stale = 0xFFu;
            bool retry = false;
            for (;;) {
                if (retry) __builtin_amdgcn_s_sleep(1);   // backoff: reduce L3 storm
#pragma unroll
                for (int bx = 0; bx < 8; ++bx)
                    if (stale & (1u << bx))
                        ld_h16(&hb[bx], hbase + bx * 1024);   // kchunk stride 4
                asm volatile("s_waitcnt vmcnt(0)" ::: "memory");
                __builtin_amdgcn_sched_barrier(0);   // rule #18: pin validation AFTER waitcnt
                unsigned ns = 0;
#pragma unroll
                for (int bx = 0; bx < 8; ++bx)
                    if (stale & (1u << bx)) {
                        unsigned m = ((((unsigned)hb[bx][0]) ^ P) | (((unsigned)hb[bx][1]) ^ P) |
                                      (((unsigned)hb[bx][2]) ^ P) | (((unsigned)hb[bx][3]) ^ P)) & M;
                        if (m) ns |= 1u << bx;
                    }
                stale = ns;
                if (__all(stale == 0)) break;
                retry = true;
            }
            __builtin_amdgcn_sched_barrier(0);

            // ---- MFMA: loaded dwords are the A-fragments directly ----
#pragma unroll
            for (int ks = 0; ks < 8; ++ks) {
                short8 A = __builtin_bit_cast(short8, hb[ks]);
                acc[0] = __builtin_amdgcn_mfma_f32_16x16x32_bf16(A, bv[0][ks], acc[0], 0, 0, 0);
                acc[1] = __builtin_amdgcn_mfma_f32_16x16x32_bf16(A, bv[1][ks], acc[1], 0, 0, 0);
                acc[2] = __builtin_amdgcn_mfma_f32_16x16x32_bf16(A, bv[2][ks], acc[2], 0, 0, 0);
                acc[3] = __builtin_amdgcn_mfma_f32_16x16x32_bf16(A, bv[3][ks], acc[3], 0, 0, 0);
            }
        }

        // ---- red stores into buffer t&1, rotated cols (2-way aliasing = free) ----
        {
            float* rp = &red[t & 1][wv * 1024];
#pragma unroll
            for (int g = 0; g < 4; ++g)
#pragma unroll
                for (int r = 0; r < 4; ++r) {
                    int bb = q * 4 + r;
                    int colrot = (g * 16 + arow + 16 * q) & 63;
                    rp[bb * 64 + colrot] = acc[g][r];
                }
        }
        __syncthreads();   // the ONLY sync per step

        // ---- gather own 4 gate sums + elementwise; publish FIRST, then out store ----
        {
            const float* rb = &red[t & 1][0];
            float s[4];
            int rotbase = 16 * (bl >> 2);
#pragma unroll
            for (int g = 0; g < 4; ++g) {
                int o = bl * 64 + ((g * 16 + hcl + rotbase) & 63);
                s[g] = rb[o] + rb[1024 + o] + rb[2048 + o] + rb[3072 + o] + cur[g];
            }
            c_reg = sigmoidf_(s[1]) * c_reg + sigmoidf_(s[0]) * tanhs_(s[2]);
            float h = sigmoidf_(s[3]) * tanhs_(c_reg);
            if (t < SEQ - 1) {
                // tagged-bf16 publish: LSB = my tag bit of step tag (t+1)&3
                unsigned tg = (unsigned)(t + 1);
                unsigned bit = tag_sel ? ((tg >> 1) & 1u) : (tg & 1u);
                unsigned hv = ((unsigned)f2bf(h) & ~1u) | bit;
                ushort_t* hn = hbuf + (((t & 1) ^ 1) * 32768);
                st_h2(hn + pub_idx, hv);
            }
            __builtin_nontemporal_store(h, &out[(size_t)t * 32768 + batch_g * 1024 + col_g]);
            if (t == SEQ - 1) {
                out[HSEQ_ELEMS + batch_g * 1024 + col_g] = h;
                out[HSEQ_ELEMS + 32768 + batch_g * 1024 + col_g] = c_reg;
                break;
            }
        }
#pragma unroll
        for (int g = 0; g < 4; ++g) cur[g] = bf2f(pf[g]);
    }
}

extern "C" void kernel_launch(void* const* d_in, const int* in_sizes, int n_in,
                              void* d_out, int out_size, void* d_ws, size_t ws_size,
                              hipStream_t stream) {
    const float* x  = (const float*)d_in[0];
    const float* Ui = (const float*)d_in[1];
    const float* Vi = (const float*)d_in[2];
    const float* bi = (const float*)d_in[3];
    const float* Uf = (const float*)d_in[4];
    const float* Vf = (const float*)d_in[5];
    const float* bfp= (const float*)d_in[6];
    const float* Uc = (const float*)d_in[7];
    const float* Vc = (const float*)d_in[8];
    const float* bc = (const float*)d_in[9];
    const float* Uo = (const float*)d_in[10];
    const float* Vo = (const float*)d_in[11];
    const float* bo = (const float*)d_in[12];

    char* ws = (char*)d_ws;
    ushort_t* hbufB = (ushort_t*)(ws + 4096);                 // 131072 B (2 x blocked 32x1024 bf16)
    ushort_t* xbf   = (ushort_t*)(ws + 266240);               // 33554432 B
    ushort_t* UT    = (ushort_t*)(ws + 33820672);             // 8388608 B
    ushort_t* VT    = (ushort_t*)(ws + 42209280);             // 8388608 B
    ushort_t* gates = (ushort_t*)(ws + 50597888);             // 134217728 B

    // poison: buf0 (even steps, tags {0,2}: bit0=0) -> memset 0x01 sets every bf16 LSB=1 (invalid).
    //         buf1 (odd steps, tags {1,3}: bit0=1) -> memset 0x00 sets LSB=0 (invalid).
    hipMemsetAsync(ws + 4096, 0x01, 65536, stream);
    hipMemsetAsync(ws + 4096 + 65536, 0x00, 65536, stream);
    hipLaunchKernelGGL(k_convert_x, dim3(8192), dim3(256), 0, stream, x, xbf);
    hipLaunchKernelGGL(k_transpose8, dim3(8192), dim3(256), 0, stream,
                       Ui, Uf, Uc, Uo, Vi, Vf, Vc, Vo, UT, VT);
    hipLaunchKernelGGL(k_gemm, dim3(4096), dim3(256), 0, stream,
                       xbf, UT, bi, bfp, bc, bo, gates);
    hipLaunchKernelGGL(k_scan, dim3(NWG), dim3(256), 0, stream,
                       gates, VT, hbufB, (float*)d_out);
}

// Round 16
// 1270.512 us; speedup vs baseline: 7.4563x; 1.0024x over previous
//
#include <hip/hip_runtime.h>

typedef unsigned short ushort_t;
typedef unsigned long long u64;
typedef __attribute__((ext_vector_type(8))) short short8;
typedef __attribute__((ext_vector_type(4))) float f32x4;
typedef __attribute__((ext_vector_type(4))) int i32x4;

#define SEQ 512
#define HID 1024
#define GCOLS 4096           // 4*HID
#define HSEQ_ELEMS 16777216  // SEQ*BATCH*HID
#define NWG 128              // 64 col-groups x 2 batch-halves

__device__ __forceinline__ ushort_t f2bf(float f) {
    unsigned u = __float_as_uint(f);
    unsigned r = (u + 0x7FFFu + ((u >> 16) & 1u)) >> 16;
    return (ushort_t)r;
}
__device__ __forceinline__ float bf2f(ushort_t u) {
    return __uint_as_float(((unsigned)u) << 16);
}
__device__ __forceinline__ float sigmoidf_(float x) { return 1.f / (1.f + __expf(-x)); }
__device__ __forceinline__ float tanhs_(float x) {
    float ax = fabsf(x);
    float e  = __expf(-2.f * ax);
    float t  = (1.f - e) / (1.f + e);
    return copysignf(t, x);
}

// 16B coherent (device-scope) load at the L3 coherence point.
__device__ __forceinline__ void ld_h16(i32x4* dst, const ushort_t* p) {
    asm volatile("global_load_dwordx4 %0, %1, off sc0 sc1"
                 : "=&v"(*dst) : "v"(p) : "memory");
}
// 2B coherent tagged publish store (byte-enable merge at L3; no tearing across threads)
__device__ __forceinline__ void st_h2(ushort_t* p, unsigned v) {
    asm volatile("global_store_short %0, %1, off sc0 sc1"
                 :: "v"(p), "v"(v) : "memory");
}

// async global->LDS, 16B per lane (dest = wave-uniform base + lane*16)
__device__ __forceinline__ void gload_lds16(const ushort_t* g, ushort_t* l) {
    __builtin_amdgcn_global_load_lds(
        (const __attribute__((address_space(1))) unsigned*)g,
        (__attribute__((address_space(3))) unsigned*)l, 16, 0, 0);
}

// ---------------- fused prep: convert x (blocks 0..8191) + transpose U/V (8192..16383) ----
// The two halves are fully independent (disjoint inputs/outputs, no cross-WG deps,
// no polling/waiting) -> safe fusion, overlaps two memory-bound phases.
__global__ __launch_bounds__(256) void k_prep(
    const float* __restrict__ x, ushort_t* __restrict__ xbf,
    const float* __restrict__ u0, const float* __restrict__ u1, const float* __restrict__ u2, const float* __restrict__ u3,
    const float* __restrict__ v0, const float* __restrict__ v1, const float* __restrict__ v2, const float* __restrict__ v3,
    ushort_t* __restrict__ UT, ushort_t* __restrict__ VT) {
    __shared__ float tile[32][33];
    if (blockIdx.x < 8192) {
        // ---- convert x (fp32 -> bf16), 8 elems/thread ----
        size_t i = ((size_t)blockIdx.x * 256 + threadIdx.x) * 8;
        float4 a = *(const float4*)(x + i);
        float4 b = *(const float4*)(x + i + 4);
        short8 v;
        v[0] = (short)f2bf(a.x); v[1] = (short)f2bf(a.y); v[2] = (short)f2bf(a.z); v[3] = (short)f2bf(a.w);
        v[4] = (short)f2bf(b.x); v[5] = (short)f2bf(b.y); v[6] = (short)f2bf(b.z); v[7] = (short)f2bf(b.w);
        *(short8*)(xbf + i) = v;
        return;
    }
    // ---- transpose-convert 8 square matrices ----
    int bid = blockIdx.x - 8192;
    int m  = bid >> 10;    // matrix 0..7
    int tl = bid & 1023;
    int tr = tl >> 5, tc = tl & 31;
    const float* src = (m == 0) ? u0 : (m == 1) ? u1 : (m == 2) ? u2 : (m == 3) ? u3
                      : (m == 4) ? v0 : (m == 5) ? v1 : (m == 6) ? v2 : v3;
    int r = threadIdx.x >> 5, c = threadIdx.x & 31;
    int k0 = tr * 32, n0 = tc * 32;
#pragma unroll
    for (int i = 0; i < 4; ++i)
        tile[r + 8 * i][c] = src[(size_t)(k0 + r + 8 * i) * HID + n0 + c];
    __syncthreads();
    ushort_t* dst = (m < 4) ? (UT + (size_t)m * HID * HID) : (VT + (size_t)(m - 4) * HID * HID);
#pragma unroll
    for (int i = 0; i < 4; ++i) {
        int row = r + 8 * i;
        dst[(size_t)(n0 + row) * HID + k0 + c] = f2bf(tile[c][row]);
    }
}

// ---------------- phase-1 GEMM: gates_pre = x_bf @ U + bias ----------------
// m97 structure: global_load_lds width=16 staging, 128x128 tile, BK=64, 2-barrier loop.
// Gates stored with PLAIN stores -> L3-resident for the scan (134MB < 256MB L3).
__global__ __launch_bounds__(256) void k_gemm(
    const ushort_t* __restrict__ A, const ushort_t* __restrict__ Bt,
    const float* __restrict__ pbi, const float* __restrict__ pbf,
    const float* __restrict__ pbc, const float* __restrict__ pbo,
    ushort_t* __restrict__ gates) {
    __shared__ ushort_t As[128 * 64];
    __shared__ ushort_t Bs[128 * 64];
    const int tid = threadIdx.x, lane = tid & 63, wv = tid >> 6;
    const int bm = blockIdx.x & 127, bn = blockIdx.x >> 7;
    const size_t m0 = (size_t)bm * 128;
    const size_t n0 = (size_t)bn * 128;
    const int wm = wv >> 1, wn = wv & 1;
    f32x4 acc[4][4] = {};
    const int rsub = lane >> 3;        // 0..7 row within 8-row chunk
    const int koff = (lane & 7) * 8;   // k element offset

    for (int kt = 0; kt < 16; ++kt) {
        int k0 = kt * 64;
#pragma unroll
        for (int j = 0; j < 4; ++j) {
            int row = wv * 32 + j * 8 + rsub;
            gload_lds16(A  + (m0 + row) * 1024 + k0 + koff, &As[wv * 2048 + j * 512]);
            gload_lds16(Bt + (n0 + row) * 1024 + k0 + koff, &Bs[wv * 2048 + j * 512]);
        }
        __syncthreads();   // compiler drains vmcnt before s_barrier
#pragma unroll
        for (int kk = 0; kk < 64; kk += 32) {
            short8 af[4], bfr[4];
            int ko = kk + (lane >> 4) * 8;
#pragma unroll
            for (int mi = 0; mi < 4; ++mi) af[mi] = *(const short8*)(&As[(wm * 64 + mi * 16 + (lane & 15)) * 64 + ko]);
#pragma unroll
            for (int ni = 0; ni < 4; ++ni) bfr[ni] = *(const short8*)(&Bs[(wn * 64 + ni * 16 + (lane & 15)) * 64 + ko]);
#pragma unroll
            for (int mi = 0; mi < 4; ++mi)
#pragma unroll
                for (int ni = 0; ni < 4; ++ni)
                    acc[mi][ni] = __builtin_amdgcn_mfma_f32_16x16x32_bf16(af[mi], bfr[ni], acc[mi][ni], 0, 0, 0);
        }
        __syncthreads();
    }
    const int g = (int)(n0 >> 10);
    const float* bias = (g == 0) ? pbi : (g == 1) ? pbf : (g == 2) ? pbc : pbo;
#pragma unroll
    for (int ni = 0; ni < 4; ++ni) {
        int col = (int)n0 + wn * 64 + ni * 16 + (lane & 15);
        float bv = bias[col & 1023];
#pragma unroll
        for (int mi = 0; mi < 4; ++mi) {
            int row0 = (int)m0 + wm * 64 + mi * 16 + ((lane >> 4) << 2);
#pragma unroll
            for (int r = 0; r < 4; ++r)
                gates[(size_t)(row0 + r) * GCOLS + col] = f2bf(acc[mi][ni][r] + bv);
        }
    }
}

// ---------------- persistent scan: 128 WGs (64 colgroups x 2 batch-halves) x 256 thr ----
// BARRIER-FREE dataflow with TAGGED-BF16 h (R12-R14, unchanged):
// - h published per-thread as bf16 with the 2-bit step tag split across col pairs
//   (even col LSB = tag bit0, odd col LSB = tag bit1); consumers poll the data itself.
// - gates prefetched before the poll (L3-resident, hidden under the poll's vmcnt).
// - s_sleep backoff on retry rounds only; sched_barrier(0) after waitcnt (rule #18).
__global__ __launch_bounds__(256, 1) void k_scan(
    const ushort_t* __restrict__ gates, const ushort_t* __restrict__ VT,
    ushort_t* hbuf, float* __restrict__ out) {
    __shared__ float red[2][4 * 1024];                         // 2 x 16KB
    const int tid = threadIdx.x, w = blockIdx.x;
    const int lane = tid & 63, wv = tid >> 6;
    const int q = lane >> 4;          // k-sub selector
    const int arow = lane & 15;       // batch row within half / V row within n-tile
    const int cg = w >> 1;            // col-group 0..63 (16 hidden cols)
    const int bh = w & 1;             // batch half

    // ---- V fragments: 4 gates x 8 k-steps, pinned in 128 VGPRs ----
    short8 bv[4][8];
#pragma unroll
    for (int g = 0; g < 4; ++g) {
        const ushort_t* vrow = VT + ((size_t)(g * 1024 + cg * 16 + arow)) * 1024 + wv * 256 + q * 8;
#pragma unroll
        for (int ks = 0; ks < 8; ++ks)
            bv[g][ks] = *(const short8*)(vrow + ks * 32);
    }

    const int bl = tid >> 4, hcl = tid & 15;          // thread's (batch_local, col_local)
    const int batch_g = bh * 16 + bl;
    const int col_g = cg * 16 + hcl;
    // publish slot (ushort index) in blocked layout [kchunk][batch][8 cols]
    const int pub_idx = ((col_g >> 3) * 32 + batch_g) * 8 + (col_g & 7);
    // this thread's tag bit position: even col carries bit0, odd col carries bit1
    const int tag_sel = col_g & 1;

    // prefetch gates t=0 (plain cached loads; gates are L3-resident)
    float cur[4];
    {
        size_t r0 = (size_t)batch_g * GCOLS + col_g;
#pragma unroll
        for (int g = 0; g < 4; ++g) cur[g] = bf2f(gates[r0 + g * 1024]);
    }

    float c_reg = 0.f;
    for (int t = 0; t < SEQ; ++t) {
        // re-pin V each iteration: forces residency
#pragma unroll
        for (int g = 0; g < 4; ++g)
#pragma unroll
            for (int ks = 0; ks < 8; ++ks)
                asm volatile("" : "+v"(*(i32x4*)&bv[g][ks]));

        const ushort_t* hc = hbuf + (t & 1) * 32768;

        // ---- prefetch gates for t+1 BEFORE the poll: L3-resident (~300ns), fully
        //      drained by the poll's first vmcnt(0) ----
        ushort_t pf[4];
        {
            int tn = (t + 1 < SEQ) ? t + 1 : 0;
            size_t r0 = (size_t)(tn * 32 + batch_g) * GCOLS + col_g;
#pragma unroll
            for (int g = 0; g < 4; ++g) pf[g] = gates[r0 + g * 1024];
        }

        f32x4 acc[4] = {};
        i32x4 hb[8];
        if (t > 0) {
            // ---- poll-load h: 8 x 16B blocks; dword valid iff (d & M) == P ----
            const unsigned P = (unsigned)((t & 1) | (((t >> 1) & 1) << 16));
            const unsigned M = 0x00010001u;
            const ushort_t* hbase = hc + ((wv * 32 + q) * 32 + bh * 16 + arow) * 8;
            unsigned stale = 0xFFu;
            bool retry = false;
            for (;;) {
                if (retry) __builtin_amdgcn_s_sleep(1);   // backoff: reduce L3 storm
#pragma unroll
                for (int bx = 0; bx < 8; ++bx)
                    if (stale & (1u << bx))
                        ld_h16(&hb[bx], hbase + bx * 1024);   // kchunk stride 4
                asm volatile("s_waitcnt vmcnt(0)" ::: "memory");
                __builtin_amdgcn_sched_barrier(0);   // rule #18: pin validation AFTER waitcnt
                unsigned ns = 0;
#pragma unroll
                for (int bx = 0; bx < 8; ++bx)
                    if (stale & (1u << bx)) {
                        unsigned m = ((((unsigned)hb[bx][0]) ^ P) | (((unsigned)hb[bx][1]) ^ P) |
                                      (((unsigned)hb[bx][2]) ^ P) | (((unsigned)hb[bx][3]) ^ P)) & M;
                        if (m) ns |= 1u << bx;
                    }
                stale = ns;
                if (__all(stale == 0)) break;
                retry = true;
            }
            __builtin_amdgcn_sched_barrier(0);

            // ---- MFMA: loaded dwords are the A-fragments directly ----
#pragma unroll
            for (int ks = 0; ks < 8; ++ks) {
                short8 A = __builtin_bit_cast(short8, hb[ks]);
                acc[0] = __builtin_amdgcn_mfma_f32_16x16x32_bf16(A, bv[0][ks], acc[0], 0, 0, 0);
                acc[1] = __builtin_amdgcn_mfma_f32_16x16x32_bf16(A, bv[1][ks], acc[1], 0, 0, 0);
                acc[2] = __builtin_amdgcn_mfma_f32_16x16x32_bf16(A, bv[2][ks], acc[2], 0, 0, 0);
                acc[3] = __builtin_amdgcn_mfma_f32_16x16x32_bf16(A, bv[3][ks], acc[3], 0, 0, 0);
            }
        }

        // ---- red stores into buffer t&1, rotated cols (2-way aliasing = free) ----
        {
            float* rp = &red[t & 1][wv * 1024];
#pragma unroll
            for (int g = 0; g < 4; ++g)
#pragma unroll
                for (int r = 0; r < 4; ++r) {
                    int bb = q * 4 + r;
                    int colrot = (g * 16 + arow + 16 * q) & 63;
                    rp[bb * 64 + colrot] = acc[g][r];
                }
        }
        __syncthreads();   // the ONLY sync per step

        // ---- gather own 4 gate sums + elementwise; publish FIRST, then out store ----
        {
            const float* rb = &red[t & 1][0];
            float s[4];
            int rotbase = 16 * (bl >> 2);
#pragma unroll
            for (int g = 0; g < 4; ++g) {
                int o = bl * 64 + ((g * 16 + hcl + rotbase) & 63);
                s[g] = rb[o] + rb[1024 + o] + rb[2048 + o] + rb[3072 + o] + cur[g];
            }
            c_reg = sigmoidf_(s[1]) * c_reg + sigmoidf_(s[0]) * tanhs_(s[2]);
            float h = sigmoidf_(s[3]) * tanhs_(c_reg);
            if (t < SEQ - 1) {
                // tagged-bf16 publish: LSB = my tag bit of step tag (t+1)&3
                unsigned tg = (unsigned)(t + 1);
                unsigned bit = tag_sel ? ((tg >> 1) & 1u) : (tg & 1u);
                unsigned hv = ((unsigned)f2bf(h) & ~1u) | bit;
                ushort_t* hn = hbuf + (((t & 1) ^ 1) * 32768);
                st_h2(hn + pub_idx, hv);
            }
            __builtin_nontemporal_store(h, &out[(size_t)t * 32768 + batch_g * 1024 + col_g]);
            if (t == SEQ - 1) {
                out[HSEQ_ELEMS + batch_g * 1024 + col_g] = h;
                out[HSEQ_ELEMS + 32768 + batch_g * 1024 + col_g] = c_reg;
                break;
            }
        }
#pragma unroll
        for (int g = 0; g < 4; ++g) cur[g] = bf2f(pf[g]);
    }
}

extern "C" void kernel_launch(void* const* d_in, const int* in_sizes, int n_in,
                              void* d_out, int out_size, void* d_ws, size_t ws_size,
                              hipStream_t stream) {
    const float* x  = (const float*)d_in[0];
    const float* Ui = (const float*)d_in[1];
    const float* Vi = (const float*)d_in[2];
    const float* bi = (const float*)d_in[3];
    const float* Uf = (const float*)d_in[4];
    const float* Vf = (const float*)d_in[5];
    const float* bfp= (const float*)d_in[6];
    const float* Uc = (const float*)d_in[7];
    const float* Vc = (const float*)d_in[8];
    const float* bc = (const float*)d_in[9];
    const float* Uo = (const float*)d_in[10];
    const float* Vo = (const float*)d_in[11];
    const float* bo = (const float*)d_in[12];

    char* ws = (char*)d_ws;
    ushort_t* hbufB = (ushort_t*)(ws + 4096);                 // 131072 B (2 x blocked 32x1024 bf16)
    ushort_t* xbf   = (ushort_t*)(ws + 266240);               // 33554432 B
    ushort_t* UT    = (ushort_t*)(ws + 33820672);             // 8388608 B
    ushort_t* VT    = (ushort_t*)(ws + 42209280);             // 8388608 B
    ushort_t* gates = (ushort_t*)(ws + 50597888);             // 134217728 B

    // poison: buf0 (even steps, tags {0,2}: bit0=0) -> memset 0x01 sets every bf16 LSB=1 (invalid).
    //         buf1 (odd steps, tags {1,3}: bit0=1) -> memset 0x00 sets LSB=0 (invalid).
    hipMemsetAsync(ws + 4096, 0x01, 65536, stream);
    hipMemsetAsync(ws + 4096 + 65536, 0x00, 65536, stream);
    hipLaunchKernelGGL(k_prep, dim3(16384), dim3(256), 0, stream,
                       x, xbf, Ui, Uf, Uc, Uo, Vi, Vf, Vc, Vo, UT, VT);
    hipLaunchKernelGGL(k_gemm, dim3(4096), dim3(256), 0, stream,
                       xbf, UT, bi, bfp, bc, bo, gates);
    hipLaunchKernelGGL(k_scan, dim3(NWG), dim3(256), 0, stream,
                       gates, VT, hbufB, (float*)d_out);
}